// Round 6
// baseline (457.947 us; speedup 1.0000x reference)
//
#include <hip/hip_runtime.h>

#define EDIM 256
#define KNN 8
#define NB 64
#define NP 512
#define NTOT (NB * NP)

typedef short s16x8 __attribute__((ext_vector_type(8)));
typedef float f32x4 __attribute__((ext_vector_type(4)));
typedef unsigned short ushort;

__device__ __forceinline__ ushort f2b(float f) {
    unsigned u = __float_as_uint(f);
    u = (u + 0x7fffu + ((u >> 16) & 1u)) >> 16;   // RNE
    return (ushort)u;
}
__device__ __forceinline__ float b2f(ushort h) {
    return __uint_as_float(((unsigned)h) << 16);
}
__device__ __forceinline__ void split2(float x, ushort& h, ushort& l) {
    h = f2b(x);
    l = f2b(x - b2f(h));
}
// truncation split (edge hot path): pair error ~2^-16 relative, fewer VALU
__device__ __forceinline__ ushort f2bt(float f) {
    return (ushort)(__float_as_uint(f) >> 16);
}
__device__ __forceinline__ void split2t(float x, ushort& h, ushort& l) {
    h = f2bt(x);
    l = f2bt(x - b2f(h));
}

// async global->LDS, 16B per lane; lds dest is wave-uniform base + lane*16
__device__ __forceinline__ void gload16(const ushort* g, ushort* l) {
    __builtin_amdgcn_global_load_lds(
        (const __attribute__((address_space(1))) void*)g,
        (__attribute__((address_space(3))) void*)l, 16, 0, 0);
}

// ---------------------------------------------------------------------------
// Kernel 0a: weight prep -> transposed bf16 hi/lo pairs.
// ---------------------------------------------------------------------------
__global__ __launch_bounds__(256)
void k_cvt(const float* __restrict__ gW1, const float* __restrict__ gW2,
           const float* __restrict__ g_gamma, const float* __restrict__ g_beta,
           const float* __restrict__ gb2,
           const float* __restrict__ cW2, const float* __restrict__ pW2,
           ushort* __restrict__ Wdh, ushort* __restrict__ Wdl,
           ushort* __restrict__ Wbh, ushort* __restrict__ Wbl,
           ushort* __restrict__ g2h, ushort* __restrict__ g2l,
           float* __restrict__ hb,
           ushort* __restrict__ cW2Th, ushort* __restrict__ cW2Tl,
           ushort* __restrict__ pW2Th, ushort* __restrict__ pW2Tl)
{
    const int gid = blockIdx.x * 256 + threadIdx.x;
    ushort h, l;
    if (gid < 65536) {
        const int n = gid >> 8, k = gid & 255;
        split2(gW1[k * 256 + n] - gW1[(k + 256) * 256 + n], h, l);
        Wdh[gid] = h; Wdl[gid] = l;
    } else if (gid < 131072) {
        const int i = gid - 65536, n = i >> 8, k = i & 255;
        split2(gW1[(k + 256) * 256 + n], h, l);
        Wbh[i] = h; Wbl[i] = l;
    } else if (gid < 196608) {
        const int i = gid - 131072, n = i >> 8, k = i & 255;
        split2(g_gamma[k] * gW2[k * 256 + n], h, l);
        g2h[i] = h; g2l[i] = l;
    } else if (gid < 196864) {
        const int n = gid - 196608;
        float s = gb2[n];
        for (int k = 0; k < 256; ++k) s += g_beta[k] * gW2[k * 256 + n];
        hb[n] = s;
    } else if (gid < 213248) {
        const int i = gid - 196864, n = i >> 6, k = i & 63;
        split2(cW2[k * 256 + n], h, l);
        cW2Th[i] = h; cW2Tl[i] = l;
    } else if (gid < 229632) {
        const int i = gid - 213248, n = i >> 6, k = i & 63;
        split2(pW2[k * 256 + n], h, l);
        pW2Th[i] = h; pW2Tl[i] = l;
    }
}

// ---------------------------------------------------------------------------
// Kernel 0b: fold merge GEMM into the MLP weights (linearity).
// ---------------------------------------------------------------------------
__global__ __launch_bounds__(256)
void k_fold(const float* __restrict__ cW2, const float* __restrict__ pW2,
            const float* __restrict__ cb2, const float* __restrict__ pb2,
            const float* __restrict__ mW,
            ushort* __restrict__ WcTh, ushort* __restrict__ WcTl,
            ushort* __restrict__ WpTh, ushort* __restrict__ WpTl,
            float* __restrict__ cbM, float* __restrict__ pbM)
{
    const int gid = blockIdx.x * 256 + threadIdx.x;
    ushort h, l;
    if (gid < 16384) {
        const int j = gid >> 8, n = gid & 255;
        float s = 0.f;
        for (int k = 0; k < 256; ++k) s += cW2[j * 256 + k] * mW[(256 + k) * 256 + n];
        split2(s, h, l);
        WcTh[n * 64 + j] = h; WcTl[n * 64 + j] = l;
    } else if (gid < 32768) {
        const int i = gid - 16384, j = i >> 8, n = i & 255;
        float s = 0.f;
        for (int k = 0; k < 256; ++k) s += pW2[j * 256 + k] * mW[(512 + k) * 256 + n];
        split2(s, h, l);
        WpTh[n * 64 + j] = h; WpTl[n * 64 + j] = l;
    } else if (gid < 33024) {
        const int n = gid - 32768;
        float s = 0.f;
        for (int k = 0; k < 256; ++k) s += cb2[k] * mW[(256 + k) * 256 + n];
        cbM[n] = s;
    } else if (gid < 33280) {
        const int n = gid - 33024;
        float s = 0.f;
        for (int k = 0; k < 256; ++k) s += pb2[k] * mW[(512 + k) * 256 + n];
        pbM[n] = s;
    }
}

// ---------------------------------------------------------------------------
// Kernel 0c: classMn[c] = (class_table[c] / ||class_table[c]||) @ M0.
// ---------------------------------------------------------------------------
__global__ __launch_bounds__(256)
void k_cls(const float* __restrict__ ct, const float* __restrict__ mW,
           float* __restrict__ classMn)
{
    __shared__ float ctn[256];
    __shared__ float red[4];
    const int c = blockIdx.x, t = threadIdx.x;
    const float v = ct[c * 256 + t];
    float ss = v * v;
    #pragma unroll
    for (int s = 32; s > 0; s >>= 1) ss += __shfl_down(ss, s, 64);
    if ((t & 63) == 0) red[t >> 6] = ss;
    __syncthreads();
    const float tot = red[0] + red[1] + red[2] + red[3];
    const float r = 1.f / fmaxf(sqrtf(tot), 1e-12f);
    ctn[t] = v * r;
    __syncthreads();
    float s = 0.f;
    for (int k = 0; k < 256; ++k) s += ctn[k] * mW[k * 256 + t];
    classMn[c * 256 + t] = s;
}

// ---------------------------------------------------------------------------
// Kernel 1: embeddings via folded GEMMs. 16 obj/block, full problem (2048).
// ---------------------------------------------------------------------------
__global__ __launch_bounds__(256)
void k_embed(const float* __restrict__ classMn,
             const float* __restrict__ cW1, const float* __restrict__ cb1,
             const float* __restrict__ cb2,
             const float* __restrict__ pW1, const float* __restrict__ pb1,
             const float* __restrict__ pb2,
             const float* __restrict__ mb,
             const ushort* __restrict__ cW2Th, const ushort* __restrict__ cW2Tl,
             const ushort* __restrict__ pW2Th, const ushort* __restrict__ pW2Tl,
             const ushort* __restrict__ WcTh, const ushort* __restrict__ WcTl,
             const ushort* __restrict__ WpTh, const ushort* __restrict__ WpTl,
             const float* __restrict__ cbM, const float* __restrict__ pbM,
             const float* __restrict__ positions, const float* __restrict__ colors,
             const int* __restrict__ cls, const int cstride,
             ushort* __restrict__ ehi, ushort* __restrict__ elo,
             float* __restrict__ sqn)
{
    __shared__ __align__(16) ushort Ahc[16 * 72];
    __shared__ __align__(16) ushort Alc[16 * 72];
    __shared__ __align__(16) ushort Ahp[16 * 72];
    __shared__ __align__(16) ushort Alp[16 * 72];
    __shared__ float sqc[16][4], sqp_[16][4], sqe[16][4];

    const int t = threadIdx.x, w = t >> 6, lane = t & 63;
    const int l15 = lane & 15, quad = lane >> 4;
    const int obase = blockIdx.x * 16;

    {
        const int o = lane >> 4;
        const int objl = w * 4 + o;
        const int gobj = obase + objl;
        const float c0 = colors[gobj * 3], c1 = colors[gobj * 3 + 1], c2 = colors[gobj * 3 + 2];
        const float q0 = positions[gobj * 3], q1 = positions[gobj * 3 + 1], q2 = positions[gobj * 3 + 2];
        const int u0 = (lane & 15) * 4;
        #pragma unroll
        for (int uu = 0; uu < 4; ++uu) {
            const int u = u0 + uu;
            const float hc = fmaxf(cb1[u] + c0 * cW1[u] + c1 * cW1[64 + u] + c2 * cW1[128 + u], 0.f);
            const float hp = fmaxf(pb1[u] + q0 * pW1[u] + q1 * pW1[64 + u] + q2 * pW1[128 + u], 0.f);
            ushort h, l;
            split2(hc, h, l); Ahc[objl * 72 + u] = h; Alc[objl * 72 + u] = l;
            split2(hp, h, l); Ahp[objl * 72 + u] = h; Alp[objl * 72 + u] = l;
        }
    }
    __syncthreads();

    f32x4 aco[4], ape[4];
    #pragma unroll
    for (int nt = 0; nt < 4; ++nt) { aco[nt] = (f32x4){0.f,0.f,0.f,0.f}; ape[nt] = (f32x4){0.f,0.f,0.f,0.f}; }

    #pragma unroll
    for (int kt = 0; kt < 2; ++kt) {
        const int ao = l15 * 72 + kt * 32 + quad * 8;
        const s16x8 ahc = *(const s16x8*)&Ahc[ao];
        const s16x8 alc = *(const s16x8*)&Alc[ao];
        const s16x8 ahp = *(const s16x8*)&Ahp[ao];
        const s16x8 alp = *(const s16x8*)&Alp[ao];
        #pragma unroll
        for (int nt = 0; nt < 4; ++nt) {
            const int n = w * 64 + nt * 16 + l15;
            const size_t bo = (size_t)n * 64 + kt * 32 + quad * 8;
            const s16x8 cbh = *(const s16x8*)(cW2Th + bo);
            const s16x8 cbl = *(const s16x8*)(cW2Tl + bo);
            const s16x8 pbh = *(const s16x8*)(pW2Th + bo);
            const s16x8 pbl = *(const s16x8*)(pW2Tl + bo);
            aco[nt] = __builtin_amdgcn_mfma_f32_16x16x32_bf16(ahc, cbh, aco[nt], 0, 0, 0);
            ape[nt] = __builtin_amdgcn_mfma_f32_16x16x32_bf16(ahp, pbh, ape[nt], 0, 0, 0);
            aco[nt] = __builtin_amdgcn_mfma_f32_16x16x32_bf16(alc, cbh, aco[nt], 0, 0, 0);
            ape[nt] = __builtin_amdgcn_mfma_f32_16x16x32_bf16(alp, pbh, ape[nt], 0, 0, 0);
            aco[nt] = __builtin_amdgcn_mfma_f32_16x16x32_bf16(ahc, cbl, aco[nt], 0, 0, 0);
            ape[nt] = __builtin_amdgcn_mfma_f32_16x16x32_bf16(ahp, pbl, ape[nt], 0, 0, 0);
        }
    }

    float sc[4] = {0.f,0.f,0.f,0.f}, sp[4] = {0.f,0.f,0.f,0.f};
    #pragma unroll
    for (int nt = 0; nt < 4; ++nt) {
        const int col = w * 64 + nt * 16 + l15;
        const float cbv = cb2[col], pbv = pb2[col];
        #pragma unroll
        for (int r = 0; r < 4; ++r) {
            const float co = aco[nt][r] + cbv;
            const float pe = ape[nt][r] + pbv;
            sc[r] += co * co;
            sp[r] += pe * pe;
        }
    }
    #pragma unroll
    for (int s = 8; s > 0; s >>= 1) {
        #pragma unroll
        for (int r = 0; r < 4; ++r) {
            sc[r] += __shfl_xor(sc[r], s, 64);
            sp[r] += __shfl_xor(sp[r], s, 64);
        }
    }
    if (l15 == 0) {
        #pragma unroll
        for (int r = 0; r < 4; ++r) { sqc[quad * 4 + r][w] = sc[r]; sqp_[quad * 4 + r][w] = sp[r]; }
    }
    __syncthreads();

    float rco[4], rpe[4];
    #pragma unroll
    for (int r = 0; r < 4; ++r) {
        const int row = quad * 4 + r;
        rco[r] = 1.f / fmaxf(sqrtf(sqc[row][0] + sqc[row][1] + sqc[row][2] + sqc[row][3]), 1e-12f);
        rpe[r] = 1.f / fmaxf(sqrtf(sqp_[row][0] + sqp_[row][1] + sqp_[row][2] + sqp_[row][3]), 1e-12f);
    }

    f32x4 ac[4], ap[4];
    #pragma unroll
    for (int nt = 0; nt < 4; ++nt) { ac[nt] = (f32x4){0.f,0.f,0.f,0.f}; ap[nt] = (f32x4){0.f,0.f,0.f,0.f}; }

    #pragma unroll
    for (int kt = 0; kt < 2; ++kt) {
        const int ao = l15 * 72 + kt * 32 + quad * 8;
        const s16x8 ahc = *(const s16x8*)&Ahc[ao];
        const s16x8 alc = *(const s16x8*)&Alc[ao];
        const s16x8 ahp = *(const s16x8*)&Ahp[ao];
        const s16x8 alp = *(const s16x8*)&Alp[ao];
        #pragma unroll
        for (int nt = 0; nt < 4; ++nt) {
            const int n = w * 64 + nt * 16 + l15;
            const size_t bo = (size_t)n * 64 + kt * 32 + quad * 8;
            const s16x8 cbh = *(const s16x8*)(WcTh + bo);
            const s16x8 cbl = *(const s16x8*)(WcTl + bo);
            const s16x8 pbh = *(const s16x8*)(WpTh + bo);
            const s16x8 pbl = *(const s16x8*)(WpTl + bo);
            ac[nt] = __builtin_amdgcn_mfma_f32_16x16x32_bf16(ahc, cbh, ac[nt], 0, 0, 0);
            ap[nt] = __builtin_amdgcn_mfma_f32_16x16x32_bf16(ahp, pbh, ap[nt], 0, 0, 0);
            ac[nt] = __builtin_amdgcn_mfma_f32_16x16x32_bf16(alc, cbh, ac[nt], 0, 0, 0);
            ap[nt] = __builtin_amdgcn_mfma_f32_16x16x32_bf16(alp, pbh, ap[nt], 0, 0, 0);
            ac[nt] = __builtin_amdgcn_mfma_f32_16x16x32_bf16(ahc, cbl, ac[nt], 0, 0, 0);
            ap[nt] = __builtin_amdgcn_mfma_f32_16x16x32_bf16(ahp, pbl, ap[nt], 0, 0, 0);
        }
    }

    int ci[4];
    #pragma unroll
    for (int r = 0; r < 4; ++r) {
        const int gobj = obase + quad * 4 + r;
        int c = cls[(size_t)gobj * cstride];
        if ((unsigned)c > 30u) c = 0;
        ci[r] = c;
    }

    float rp[4] = {0.f,0.f,0.f,0.f};
    #pragma unroll
    for (int nt = 0; nt < 4; ++nt) {
        const int col = w * 64 + nt * 16 + l15;
        const float mbv = mb[col], cbMv = cbM[col], pbMv = pbM[col];
        #pragma unroll
        for (int r = 0; r < 4; ++r) {
            const int row = quad * 4 + r;
            const float e = classMn[ci[r] * 256 + col]
                          + rco[r] * (ac[nt][r] + cbMv)
                          + rpe[r] * (ap[nt][r] + pbMv) + mbv;
            ushort h, l;
            split2(e, h, l);
            ehi[(size_t)(obase + row) * 256 + col] = h;
            elo[(size_t)(obase + row) * 256 + col] = l;
            rp[r] += e * e;
        }
    }
    #pragma unroll
    for (int s = 8; s > 0; s >>= 1) {
        #pragma unroll
        for (int r = 0; r < 4; ++r) rp[r] += __shfl_xor(rp[r], s, 64);
    }
    if (l15 == 0) {
        #pragma unroll
        for (int r = 0; r < 4; ++r) sqe[quad * 4 + r][w] = rp[r];
    }
    __syncthreads();
    if (t < 16) sqn[obase + t] = sqe[t][0] + sqe[t][1] + sqe[t][2] + sqe[t][3];
}

// ---------------------------------------------------------------------------
// Kernel 2: Gram/distance. m97-style 128x128 tile per block, double-buffered
// LDS staged via global_load_lds (width 16), BK=32/step, XOR chunk-swizzle
// on both sides (rule 21). Diagonal tiles stage A only. Nontemporal dist.
// ---------------------------------------------------------------------------
__global__ __launch_bounds__(256)
void k_gram(const ushort* __restrict__ ehi, const ushort* __restrict__ elo,
            const float* __restrict__ sqn, float* __restrict__ dist)
{
    // [dbuf][Ah,Al,Bh,Bl][128 rows * 32 k], 64 KB total
    __shared__ __align__(16) ushort lds[2][4][4096];

    const int t = threadIdx.x, w = t >> 6, lane = t & 63;
    const int l15 = lane & 15, quad = lane >> 4;
    const int b = blockIdx.x;
    const int xcd = b & 7, rest = b >> 3;        // rest 0..127
    const int cell = xcd * 8 + (rest >> 4);      // 0..63
    const int tile = rest & 15;
    const int p0 = (tile >> 2) * 128, q0 = (tile & 3) * 128;
    const size_t cb = (size_t)cell * NP;
    const int diag = (p0 == q0);
    const int wr = w >> 1, wc = w & 1;           // 2x2 wave grid, 64x64 each

    int srow[2], scol[2];
    #pragma unroll
    for (int i = 0; i < 2; ++i) {
        const int p = (w * 2 + i) * 64 + lane;
        const int row = p >> 2;
        srow[i] = row;
        scol[i] = ((p & 3) ^ ((row >> 1) & 3)) * 8;   // ushort offset of 16B chunk
    }

    #define STAGE(KT, D)                                                         \
    {                                                                            \
        const int kb_ = (KT) * 32;                                               \
        _Pragma("unroll")                                                        \
        for (int i = 0; i < 2; ++i) {                                            \
            const int ls_ = (w * 2 + i) * 512;   /* slot*8 ushorts */            \
            const size_t ga_ = (cb + p0 + srow[i]) * 256 + kb_ + scol[i];        \
            gload16(ehi + ga_, &lds[D][0][ls_]);                                 \
            gload16(elo + ga_, &lds[D][1][ls_]);                                 \
            if (!diag) {                                                         \
                const size_t gq_ = (cb + q0 + srow[i]) * 256 + kb_ + scol[i];    \
                gload16(ehi + gq_, &lds[D][2][ls_]);                             \
                gload16(elo + gq_, &lds[D][3][ls_]);                             \
            }                                                                    \
        }                                                                        \
    }

    f32x4 acc[4][4];
    #pragma unroll
    for (int mt = 0; mt < 4; ++mt)
        #pragma unroll
        for (int nt = 0; nt < 4; ++nt) acc[mt][nt] = (f32x4){0.f, 0.f, 0.f, 0.f};

    const int bB = diag ? 0 : 2;

    STAGE(0, 0);
    __syncthreads();

    for (int kt = 0; kt < 8; ++kt) {
        const int cur = kt & 1;
        if (kt < 7) STAGE(kt + 1, cur ^ 1);      // prefetch next k-slice

        s16x8 ah[4], al[4];
        #pragma unroll
        for (int mt = 0; mt < 4; ++mt) {
            const int r = wr * 64 + mt * 16 + l15;
            const int slot = 4 * r + (quad ^ ((r >> 1) & 3));
            ah[mt] = *(const s16x8*)&lds[cur][0][slot * 8];
            al[mt] = *(const s16x8*)&lds[cur][1][slot * 8];
        }
        #pragma unroll
        for (int nt = 0; nt < 4; ++nt) {
            const int rq = wc * 64 + nt * 16 + l15;
            const int slot = 4 * rq + (quad ^ ((rq >> 1) & 3));
            const s16x8 bh = *(const s16x8*)&lds[cur][bB][slot * 8];
            const s16x8 bl = *(const s16x8*)&lds[cur][bB + 1][slot * 8];
            #pragma unroll
            for (int mt = 0; mt < 4; ++mt) {
                acc[mt][nt] = __builtin_amdgcn_mfma_f32_16x16x32_bf16(ah[mt], bh, acc[mt][nt], 0, 0, 0);
                acc[mt][nt] = __builtin_amdgcn_mfma_f32_16x16x32_bf16(al[mt], bh, acc[mt][nt], 0, 0, 0);
                acc[mt][nt] = __builtin_amdgcn_mfma_f32_16x16x32_bf16(ah[mt], bl, acc[mt][nt], 0, 0, 0);
            }
        }
        __syncthreads();                          // drains vmcnt(0) -> buf ready
    }
    #undef STAGE

    float sqp[4][4];
    #pragma unroll
    for (int mt = 0; mt < 4; ++mt)
        #pragma unroll
        for (int r = 0; r < 4; ++r)
            sqp[mt][r] = sqn[cb + p0 + wr * 64 + mt * 16 + quad * 4 + r];

    #pragma unroll
    for (int nt = 0; nt < 4; ++nt) {
        const int colq = q0 + wc * 64 + nt * 16 + l15;
        const float sq_q = sqn[cb + colq];
        #pragma unroll
        for (int mt = 0; mt < 4; ++mt) {
            #pragma unroll
            for (int r = 0; r < 4; ++r) {
                const int rowp = p0 + wr * 64 + mt * 16 + quad * 4 + r;
                __builtin_nontemporal_store((sqp[mt][r] + sq_q) - 2.f * acc[mt][nt][r],
                                            &dist[(cb + rowp) * NP + colq]);
            }
        }
    }
}

// ---------------------------------------------------------------------------
// Kernel 3: top-8 smallest per point (ties -> lowest index). One wave/point.
// ---------------------------------------------------------------------------
__global__ __launch_bounds__(256)
void k_select(const float* __restrict__ dist, int* __restrict__ nidx)
{
    const int wv = threadIdx.x >> 6, lane = threadIdx.x & 63;
    const int xcd = blockIdx.x & 7, rest = blockIdx.x >> 3;   // rest 0..1023
    const int cell = xcd * 8 + (rest >> 7);                   // 0..63
    const int p = cell * NP + (rest & 127) * 4 + wv;          // global point
    const float* row = dist + (size_t)p * NP;

    float d[8];
    {
        const float4 va = *(const float4*)(row + lane * 8);
        const float4 vb = *(const float4*)(row + lane * 8 + 4);
        d[0] = va.x; d[1] = va.y; d[2] = va.z; d[3] = va.w;
        d[4] = vb.x; d[5] = vb.y; d[6] = vb.z; d[7] = vb.w;
    }

    for (int r = 0; r < KNN; ++r) {
        float bd = d[0]; int bi = 0;
        #pragma unroll
        for (int i = 1; i < 8; ++i)
            if (d[i] < bd) { bd = d[i]; bi = i; }   // strict < keeps lowest i on tie
        int bq = lane * 8 + bi;
        #pragma unroll
        for (int s = 32; s > 0; s >>= 1) {
            const float od = __shfl_down(bd, s, 64);
            const int oq = __shfl_down(bq, s, 64);
            if (od < bd || (od == bd && oq < bq)) { bd = od; bq = oq; }
        }
        const int win = __shfl(bq, 0, 64);
        if (lane == 0) nidx[(size_t)p * KNN + r] = ((p >> 9) << 9) | win;
        if ((win >> 3) == lane) {
            const int wi = win & 7;
            #pragma unroll
            for (int i = 0; i < 8; ++i) if (wi == i) d[i] = 3.4e38f;
        }
    }
}

// ---------------------------------------------------------------------------
// Kernel 4: u = x@Wd+gb1, v = x@Wb via 2-pass split MFMA (A hi+lo, B hi only).
// 64 points/block: wave = 2 m-frags x 128 cols.
// ---------------------------------------------------------------------------
__global__ __launch_bounds__(256)
void k_uv(const ushort* __restrict__ ehi, const ushort* __restrict__ elo,
          const ushort* __restrict__ Wdh, const ushort* __restrict__ Wbh,
          const float* __restrict__ gb1,
          float* __restrict__ u, float* __restrict__ v)
{
    const int t = threadIdx.x, w = t >> 6, lane = t & 63;
    const int l15 = lane & 15, quad = lane >> 4;
    const int isV = blockIdx.x >> 9;           // 1024 blocks total
    const int m0 = (blockIdx.x & 511) * 64;
    const ushort* Wh = isV ? Wbh : Wdh;
    float* out = isV ? v : u;
    const int mh = w & 1, ch = w >> 1;

    const size_t arow0 = (size_t)(m0 + mh * 32 + l15) * 256 + quad * 8;
    const size_t arow1 = arow0 + 16 * 256;

    f32x4 acc[2][8];
    #pragma unroll
    for (int mt = 0; mt < 2; ++mt)
        #pragma unroll
        for (int nt = 0; nt < 8; ++nt) acc[mt][nt] = (f32x4){0.f, 0.f, 0.f, 0.f};

    #pragma unroll
    for (int s = 0; s < 8; ++s) {
        const s16x8 ah0 = *(const s16x8*)(ehi + arow0 + s * 32);
        const s16x8 al0 = *(const s16x8*)(elo + arow0 + s * 32);
        const s16x8 ah1 = *(const s16x8*)(ehi + arow1 + s * 32);
        const s16x8 al1 = *(const s16x8*)(elo + arow1 + s * 32);
        #pragma unroll
        for (int nt = 0; nt < 8; ++nt) {
            const int n = ch * 128 + nt * 16 + l15;
            const size_t bo = (size_t)n * 256 + s * 32 + quad * 8;
            const s16x8 bh = *(const s16x8*)(Wh + bo);
            acc[0][nt] = __builtin_amdgcn_mfma_f32_16x16x32_bf16(ah0, bh, acc[0][nt], 0, 0, 0);
            acc[0][nt] = __builtin_amdgcn_mfma_f32_16x16x32_bf16(al0, bh, acc[0][nt], 0, 0, 0);
            acc[1][nt] = __builtin_amdgcn_mfma_f32_16x16x32_bf16(ah1, bh, acc[1][nt], 0, 0, 0);
            acc[1][nt] = __builtin_amdgcn_mfma_f32_16x16x32_bf16(al1, bh, acc[1][nt], 0, 0, 0);
        }
    }

    #pragma unroll
    for (int mt = 0; mt < 2; ++mt) {
        #pragma unroll
        for (int nt = 0; nt < 8; ++nt) {
            const int col = ch * 128 + nt * 16 + l15;
            const float bias = isV ? 0.f : gb1[col];
            #pragma unroll
            for (int r = 0; r < 4; ++r) {
                const int row = mh * 32 + mt * 16 + quad * 4 + r;
                out[(size_t)(m0 + row) * 256 + col] = acc[mt][nt][r] + bias;
            }
        }
    }
}

// ---------------------------------------------------------------------------
// Kernel 5: edge GEMM + max aggregation. Block = 8 points (64 edges), 4 waves;
// wave w = all 64 edges x cols w*64..+63. 2-pass split (A trunc-split hi+lo,
// B hi only). KEY CHANGE (T4): the inner-loop barrier is a raw
// `s_waitcnt lgkmcnt(0)` + `s_barrier` instead of __syncthreads(), so the
// compiler's `vmcnt(0)` drain is gone -- v-gathers and B loads stay in
// flight across barriers. LDS dbuf protocol is still correct: lgkmcnt(0)
// before the barrier completes all ds_writes/ds_reads issued before it.
// ---------------------------------------------------------------------------
__global__ __launch_bounds__(256)
void k_edge(const float* __restrict__ u, const float* __restrict__ v,
            const int* __restrict__ nidx,
            const ushort* __restrict__ g2h,
            const float* __restrict__ hb,
            float* __restrict__ part)
{
    __shared__ ushort Abuf[2][2][2304];   // [dbuf][hi/lo][edge*36+k], 18.4 KB
    __shared__ float ustage[2048];        // 8 pts x 256 k, 8 KB

    const int t = threadIdx.x, w = t >> 6, lane = t & 63;
    const int l15 = lane & 15, quad = lane >> 4;

    const int b = blockIdx.x;
    const int xcd = b & 7, rest = b >> 3;        // rest 0..511
    const int cell = xcd * 8 + (rest >> 6);      // 0..63
    const int pl0 = cell * NP + (rest & 63) * 8;

    // stage u rows once (coalesced, 8 floats per thread)
    {
        const int pt = t >> 5, kk = (t & 31) * 8;
        const float4 a = *(const float4*)(u + (size_t)(pl0 + pt) * 256 + kk);
        const float4 bq = *(const float4*)(u + (size_t)(pl0 + pt) * 256 + kk + 4);
        *(float4*)&ustage[pt * 256 + kk] = a;
        *(float4*)&ustage[pt * 256 + kk + 4] = bq;
    }

    const int se = t >> 2, kq = t & 3;
    const int upt = se >> 3;                     // point within block
    int svrow = nidx[(size_t)(pl0 + upt) * KNN + (se & 7)];
    if ((unsigned)svrow >= (unsigned)NTOT) svrow = 0;

    __syncthreads();                             // ustage visible (one-time)

    float4 vr[2][2];                             // 2-set v pipeline

    #define VLOAD(S)                                                             \
    {                                                                            \
        const int k0 = (S) * 32 + kq * 8;                                        \
        vr[(S) & 1][0] = *(const float4*)(v + (size_t)svrow * 256 + k0);         \
        vr[(S) & 1][1] = *(const float4*)(v + (size_t)svrow * 256 + k0 + 4);     \
    }
    #define SPLITW(S, BUF)                                                       \
    {                                                                            \
        const int k0u = (S) * 32 + kq * 8;                                       \
        const float4 ua = *(const float4*)&ustage[upt * 256 + k0u];              \
        const float4 ub = *(const float4*)&ustage[upt * 256 + k0u + 4];          \
        const float4 va = vr[(S) & 1][0], vb = vr[(S) & 1][1];                   \
        const float sv[8] = {                                                    \
            fmaxf(ua.x + va.x, 0.f), fmaxf(ua.y + va.y, 0.f),                    \
            fmaxf(ua.z + va.z, 0.f), fmaxf(ua.w + va.w, 0.f),                    \
            fmaxf(ub.x + vb.x, 0.f), fmaxf(ub.y + vb.y, 0.f),                    \
            fmaxf(ub.z + vb.z, 0.f), fmaxf(ub.w + vb.w, 0.f)};                   \
        union { uint2 q[2]; ushort us[8]; } th, tl;                              \
        _Pragma("unroll")                                                        \
        for (int j = 0; j < 8; ++j) { split2t(sv[j], th.us[j], tl.us[j]); }      \
        *(uint2*)&Abuf[BUF][0][se * 36 + kq * 8]     = th.q[0];                  \
        *(uint2*)&Abuf[BUF][0][se * 36 + kq * 8 + 4] = th.q[1];                  \
        *(uint2*)&Abuf[BUF][1][se * 36 + kq * 8]     = tl.q[0];                  \
        *(uint2*)&Abuf[BUF][1][se * 36 + kq * 8 + 4] = tl.q[1];                  \
    }

    // LDS-only barrier: completes all DS ops issued before it, leaves
    // global loads (vmcnt) in flight across the barrier.
    #define LDS_BARRIER()                                                        \
    {                                                                            \
        asm volatile("s_waitcnt lgkmcnt(0)" ::: "memory");                       \
        __builtin_amdgcn_s_barrier();                                            \
    }

    f32x4 acc[4][4];
    #pragma unroll
    for (int mt = 0; mt < 4; ++mt)
        #pragma unroll
        for (int nt = 0; nt < 4; ++nt) acc[mt][nt] = (f32x4){0.f, 0.f, 0.f, 0.f};

    VLOAD(0); VLOAD(1);
    SPLITW(0, 0);

    #pragma unroll
    for (int s = 0; s < 8; ++s) {
        LDS_BARRIER();                        // buf[s&1] visible; buf[(s+1)&1] readers done
        if (s < 7) {
            SPLITW(s + 1, (s + 1) & 1);       // u from LDS, v register-resident
            if (s < 6) VLOAD(s + 2);          // stays in flight across barriers now
        }

        const int k0 = s * 32 + quad * 8;
        s16x8 ah[4], al[4];
        #pragma unroll
        for (int mt = 0; mt < 4; ++mt) {
            const int ao = (mt * 16 + l15) * 36 + quad * 8;
            union { uint2 q[2]; s16x8 v8; } Th, Tl;
            Th.q[0] = *(const uint2*)&Abuf[s & 1][0][ao];
            Th.q[1] = *(const uint2*)&Abuf[s & 1][0][ao + 4];
            Tl.q[0] = *(const uint2*)&Abuf[s & 1][1][ao];
            Tl.q[1] = *(const uint2*)&Abuf[s & 1][1][ao + 4];
            ah[mt] = Th.v8; al[mt] = Tl.v8;
        }
        #pragma unroll
        for (int nt = 0; nt < 4; ++nt) {
            const int n = w * 64 + nt * 16 + l15;
            const s16x8 bh = *(const s16x8*)(g2h + (size_t)n * 256 + k0);
            #pragma unroll
            for (int mt = 0; mt < 4; ++mt) {
                acc[mt][nt] = __builtin_amdgcn_mfma_f32_16x16x32_bf16(ah[mt], bh, acc[mt][nt], 0, 0, 0);
                acc[mt][nt] = __builtin_amdgcn_mfma_f32_16x16x32_bf16(al[mt], bh, acc[mt][nt], 0, 0, 0);
            }
        }
    }
    #undef VLOAD
    #undef SPLITW
    #undef LDS_BARRIER

    const int slot = rest & 63;
    #pragma unroll
    for (int nt = 0; nt < 4; ++nt) {
        float rm = -3.4e38f;
        #pragma unroll
        for (int mt = 0; mt < 4; ++mt)
            rm = fmaxf(rm, fmaxf(fmaxf(acc[mt][nt][0], acc[mt][nt][1]),
                                 fmaxf(acc[mt][nt][2], acc[mt][nt][3])));
        rm = fmaxf(rm, __shfl_xor(rm, 16, 64));
        rm = fmaxf(rm, __shfl_xor(rm, 32, 64));
        if (quad == 0) {
            const int col = w * 64 + nt * 16 + l15;
            part[((size_t)cell * 64 + slot) * 256 + col] = rm + hb[col];
        }
    }
}

// ---------------------------------------------------------------------------
// Kernel 6: reduce 64 partial maxes per cell, final MLP (f32), L2 normalize.
// ---------------------------------------------------------------------------
__global__ __launch_bounds__(256)
void k_final(const float* __restrict__ part,
             const float* __restrict__ lW1, const float* __restrict__ lb1,
             const float* __restrict__ lW2, const float* __restrict__ lb2,
             float* __restrict__ out)
{
    __shared__ float pooled[256];
    __shared__ float hid[256];
    __shared__ float red[4];

    const int b = blockIdx.x;
    const int t = threadIdx.x;

    float m = -3.4e38f;
    for (int s = 0; s < 64; ++s)
        m = fmaxf(m, part[((size_t)b * 64 + s) * 256 + t]);
    pooled[t] = m;
    __syncthreads();

    float h = lb1[t];
    for (int k = 0; k < 256; k += 4) {
        #pragma unroll
        for (int kk = 0; kk < 4; ++kk)
            h += pooled[k + kk] * lW1[(k + kk) * 256 + t];
    }
    hid[t] = fmaxf(h, 0.f);
    __syncthreads();

    float o = lb2[t];
    for (int k = 0; k < 256; k += 4) {
        #pragma unroll
        for (int kk = 0; kk < 4; ++kk)
            o += hid[k + kk] * lW2[(k + kk) * 256 + t];
    }

    float ss = o * o;
    #pragma unroll
    for (int s = 32; s > 0; s >>= 1) ss += __shfl_down(ss, s, 64);
    if ((t & 63) == 0) red[t >> 6] = ss;
    __syncthreads();
    const float tot = red[0] + red[1] + red[2] + red[3];
    const float rn = 1.f / fmaxf(sqrtf(tot), 1e-12f);
    out[b * 256 + t] = o * rn;
}

// ---------------------------------------------------------------------------
extern "C" void kernel_launch(void* const* d_in, const int* in_sizes, int n_in,
                              void* d_out, int out_size, void* d_ws, size_t ws_size,
                              hipStream_t stream)
{
    (void)n_in; (void)out_size; (void)ws_size;

    const float* class_table = (const float*)d_in[0];
    const float* cW1 = (const float*)d_in[1];
    const float* cb1 = (const float*)d_in[2];
    const float* cW2 = (const float*)d_in[3];
    const float* cb2 = (const float*)d_in[4];
    const float* pW1 = (const float*)d_in[5];
    const float* pb1 = (const float*)d_in[6];
    const float* pW2 = (const float*)d_in[7];
    const float* pb2 = (const float*)d_in[8];
    const float* mW  = (const float*)d_in[9];
    const float* mb  = (const float*)d_in[10];
    const float* gW1 = (const float*)d_in[11];
    const float* gb1 = (const float*)d_in[12];
    const float* g_gamma = (const float*)d_in[13];
    const float* g_beta  = (const float*)d_in[14];
    const float* gW2 = (const float*)d_in[15];
    const float* gb2 = (const float*)d_in[16];
    const float* lW1 = (const float*)d_in[17];
    const float* lb1 = (const float*)d_in[18];
    const float* lW2 = (const float*)d_in[19];
    const float* lb2 = (const float*)d_in[20];
    const float* positions = (const float*)d_in[21];
    const float* colors    = (const float*)d_in[22];
    const int*  cls        = (const int*)d_in[23];

    const int cstride = (in_sizes[23] == 2 * NTOT) ? 2 : 1;

    // workspace layout (bytes), total ~174 MB (ws_size ~268 MB).
    char* base = (char*)d_ws;
    float*   part   = (float*)(base + 0);               //   4,194,304
    ushort*  Wdh    = (ushort*)(base + 4194304);
    ushort*  Wdl    = (ushort*)(base + 4325376);
    ushort*  Wbh    = (ushort*)(base + 4456448);
    ushort*  Wbl    = (ushort*)(base + 4587520);
    ushort*  g2h    = (ushort*)(base + 4718592);
    ushort*  g2l    = (ushort*)(base + 4849664);
    float*   hb     = (float*)(base + 4980736);
    ushort*  cW2Th  = (ushort*)(base + 4981760);
    ushort*  cW2Tl  = (ushort*)(base + 5014528);
    ushort*  pW2Th  = (ushort*)(base + 5047296);
    ushort*  pW2Tl  = (ushort*)(base + 5080064);
    ushort*  WcTh   = (ushort*)(base + 5112832);
    ushort*  WcTl   = (ushort*)(base + 5145600);
    ushort*  WpTh   = (ushort*)(base + 5178368);
    ushort*  WpTl   = (ushort*)(base + 5211136);
    float*   classMn= (float*)(base + 5243904);
    float*   cbM    = (float*)(base + 5275648);
    float*   pbM    = (float*)(base + 5276672);
    int*     nidx   = (int*)(base + 5277696);           //   1,048,576
    float*   sqn    = (float*)(base + 6326272);         //     131,072
    ushort*  ehi    = (ushort*)(base + 6457344);        //  16,777,216
    ushort*  elo    = (ushort*)(base + 23234560);       //  16,777,216
    float*   dist   = (float*)(base + 40011776);        //  67,108,864
    float*   v      = (float*)(base + 107120640);       //  33,554,432
    float*   u      = (float*)(base + 140675072);       //  33,554,432
    float* out = (float*)d_out;

    k_cvt<<<897, 256, 0, stream>>>(gW1, gW2, g_gamma, g_beta, gb2, cW2, pW2,
                                   Wdh, Wdl, Wbh, Wbl, g2h, g2l, hb,
                                   cW2Th, cW2Tl, pW2Th, pW2Tl);
    k_fold<<<130, 256, 0, stream>>>(cW2, pW2, cb2, pb2, mW,
                                    WcTh, WcTl, WpTh, WpTl, cbM, pbM);
    k_cls<<<31, 256, 0, stream>>>(class_table, mW, classMn);

    k_embed<<<NTOT / 16, 256, 0, stream>>>(classMn, cW1, cb1, cb2, pW1, pb1, pb2,
                                           mb, cW2Th, cW2Tl, pW2Th, pW2Tl,
                                           WcTh, WcTl, WpTh, WpTl, cbM, pbM,
                                           positions, colors, cls, cstride,
                                           ehi, elo, sqn);
    k_gram<<<NB * 16, 256, 0, stream>>>(ehi, elo, sqn, dist);
    k_select<<<NTOT / 4, 256, 0, stream>>>(dist, nidx);
    k_uv<<<2 * NTOT / 64, 256, 0, stream>>>(ehi, elo, Wdh, Wbh, gb1, u, v);
    k_edge<<<NTOT / 8, 256, 0, stream>>>(u, v, nidx, g2h, hb, part);
    k_final<<<NB, 256, 0, stream>>>(part, lW1, lb1, lW2, lb2, out);
}

// Round 7
// 441.791 us; speedup vs baseline: 1.0366x; 1.0366x over previous
//
#include <hip/hip_runtime.h>

#define EDIM 256
#define KNN 8
#define NB 64
#define NP 512
#define NTOT (NB * NP)

typedef short s16x8 __attribute__((ext_vector_type(8)));
typedef float f32x4 __attribute__((ext_vector_type(4)));
typedef unsigned short ushort;

__device__ __forceinline__ ushort f2b(float f) {
    unsigned u = __float_as_uint(f);
    u = (u + 0x7fffu + ((u >> 16) & 1u)) >> 16;   // RNE
    return (ushort)u;
}
__device__ __forceinline__ float b2f(ushort h) {
    return __uint_as_float(((unsigned)h) << 16);
}
__device__ __forceinline__ void split2(float x, ushort& h, ushort& l) {
    h = f2b(x);
    l = f2b(x - b2f(h));
}
// truncation split (edge hot path): pair error ~2^-16 relative, fewer VALU
__device__ __forceinline__ ushort f2bt(float f) {
    return (ushort)(__float_as_uint(f) >> 16);
}
__device__ __forceinline__ void split2t(float x, ushort& h, ushort& l) {
    h = f2bt(x);
    l = f2bt(x - b2f(h));
}

// async global->LDS, 16B per lane; lds dest is wave-uniform base + lane*16
__device__ __forceinline__ void gload16(const ushort* g, ushort* l) {
    __builtin_amdgcn_global_load_lds(
        (const __attribute__((address_space(1))) void*)g,
        (__attribute__((address_space(3))) void*)l, 16, 0, 0);
}

// ---------------------------------------------------------------------------
// Kernel 0a: weight prep -> transposed bf16 hi/lo pairs.
// ---------------------------------------------------------------------------
__global__ __launch_bounds__(256)
void k_cvt(const float* __restrict__ gW1, const float* __restrict__ gW2,
           const float* __restrict__ g_gamma, const float* __restrict__ g_beta,
           const float* __restrict__ gb2,
           const float* __restrict__ cW2, const float* __restrict__ pW2,
           ushort* __restrict__ Wdh, ushort* __restrict__ Wdl,
           ushort* __restrict__ Wbh, ushort* __restrict__ Wbl,
           ushort* __restrict__ g2h, ushort* __restrict__ g2l,
           float* __restrict__ hb,
           ushort* __restrict__ cW2Th, ushort* __restrict__ cW2Tl,
           ushort* __restrict__ pW2Th, ushort* __restrict__ pW2Tl)
{
    const int gid = blockIdx.x * 256 + threadIdx.x;
    ushort h, l;
    if (gid < 65536) {
        const int n = gid >> 8, k = gid & 255;
        split2(gW1[k * 256 + n] - gW1[(k + 256) * 256 + n], h, l);
        Wdh[gid] = h; Wdl[gid] = l;
    } else if (gid < 131072) {
        const int i = gid - 65536, n = i >> 8, k = i & 255;
        split2(gW1[(k + 256) * 256 + n], h, l);
        Wbh[i] = h; Wbl[i] = l;
    } else if (gid < 196608) {
        const int i = gid - 131072, n = i >> 8, k = i & 255;
        split2(g_gamma[k] * gW2[k * 256 + n], h, l);
        g2h[i] = h; g2l[i] = l;
    } else if (gid < 196864) {
        const int n = gid - 196608;
        float s = gb2[n];
        for (int k = 0; k < 256; ++k) s += g_beta[k] * gW2[k * 256 + n];
        hb[n] = s;
    } else if (gid < 213248) {
        const int i = gid - 196864, n = i >> 6, k = i & 63;
        split2(cW2[k * 256 + n], h, l);
        cW2Th[i] = h; cW2Tl[i] = l;
    } else if (gid < 229632) {
        const int i = gid - 213248, n = i >> 6, k = i & 63;
        split2(pW2[k * 256 + n], h, l);
        pW2Th[i] = h; pW2Tl[i] = l;
    }
}

// ---------------------------------------------------------------------------
// Kernel 0b: fold merge GEMM into the MLP weights (linearity).
// ---------------------------------------------------------------------------
__global__ __launch_bounds__(256)
void k_fold(const float* __restrict__ cW2, const float* __restrict__ pW2,
            const float* __restrict__ cb2, const float* __restrict__ pb2,
            const float* __restrict__ mW,
            ushort* __restrict__ WcTh, ushort* __restrict__ WcTl,
            ushort* __restrict__ WpTh, ushort* __restrict__ WpTl,
            float* __restrict__ cbM, float* __restrict__ pbM)
{
    const int gid = blockIdx.x * 256 + threadIdx.x;
    ushort h, l;
    if (gid < 16384) {
        const int j = gid >> 8, n = gid & 255;
        float s = 0.f;
        for (int k = 0; k < 256; ++k) s += cW2[j * 256 + k] * mW[(256 + k) * 256 + n];
        split2(s, h, l);
        WcTh[n * 64 + j] = h; WcTl[n * 64 + j] = l;
    } else if (gid < 32768) {
        const int i = gid - 16384, j = i >> 8, n = i & 255;
        float s = 0.f;
        for (int k = 0; k < 256; ++k) s += pW2[j * 256 + k] * mW[(512 + k) * 256 + n];
        split2(s, h, l);
        WpTh[n * 64 + j] = h; WpTl[n * 64 + j] = l;
    } else if (gid < 33024) {
        const int n = gid - 32768;
        float s = 0.f;
        for (int k = 0; k < 256; ++k) s += cb2[k] * mW[(256 + k) * 256 + n];
        cbM[n] = s;
    } else if (gid < 33280) {
        const int n = gid - 33024;
        float s = 0.f;
        for (int k = 0; k < 256; ++k) s += pb2[k] * mW[(512 + k) * 256 + n];
        pbM[n] = s;
    }
}

// ---------------------------------------------------------------------------
// Kernel 0c: classMn[c] = (class_table[c] / ||class_table[c]||) @ M0.
// ---------------------------------------------------------------------------
__global__ __launch_bounds__(256)
void k_cls(const float* __restrict__ ct, const float* __restrict__ mW,
           float* __restrict__ classMn)
{
    __shared__ float ctn[256];
    __shared__ float red[4];
    const int c = blockIdx.x, t = threadIdx.x;
    const float v = ct[c * 256 + t];
    float ss = v * v;
    #pragma unroll
    for (int s = 32; s > 0; s >>= 1) ss += __shfl_down(ss, s, 64);
    if ((t & 63) == 0) red[t >> 6] = ss;
    __syncthreads();
    const float tot = red[0] + red[1] + red[2] + red[3];
    const float r = 1.f / fmaxf(sqrtf(tot), 1e-12f);
    ctn[t] = v * r;
    __syncthreads();
    float s = 0.f;
    for (int k = 0; k < 256; ++k) s += ctn[k] * mW[k * 256 + t];
    classMn[c * 256 + t] = s;
}

// ---------------------------------------------------------------------------
// Kernel 1: embeddings via folded GEMMs. 16 obj/block, full problem (2048).
// ---------------------------------------------------------------------------
__global__ __launch_bounds__(256)
void k_embed(const float* __restrict__ classMn,
             const float* __restrict__ cW1, const float* __restrict__ cb1,
             const float* __restrict__ cb2,
             const float* __restrict__ pW1, const float* __restrict__ pb1,
             const float* __restrict__ pb2,
             const float* __restrict__ mb,
             const ushort* __restrict__ cW2Th, const ushort* __restrict__ cW2Tl,
             const ushort* __restrict__ pW2Th, const ushort* __restrict__ pW2Tl,
             const ushort* __restrict__ WcTh, const ushort* __restrict__ WcTl,
             const ushort* __restrict__ WpTh, const ushort* __restrict__ WpTl,
             const float* __restrict__ cbM, const float* __restrict__ pbM,
             const float* __restrict__ positions, const float* __restrict__ colors,
             const int* __restrict__ cls, const int cstride,
             ushort* __restrict__ ehi, ushort* __restrict__ elo,
             float* __restrict__ sqn)
{
    __shared__ __align__(16) ushort Ahc[16 * 72];
    __shared__ __align__(16) ushort Alc[16 * 72];
    __shared__ __align__(16) ushort Ahp[16 * 72];
    __shared__ __align__(16) ushort Alp[16 * 72];
    __shared__ float sqc[16][4], sqp_[16][4], sqe[16][4];

    const int t = threadIdx.x, w = t >> 6, lane = t & 63;
    const int l15 = lane & 15, quad = lane >> 4;
    const int obase = blockIdx.x * 16;

    {
        const int o = lane >> 4;
        const int objl = w * 4 + o;
        const int gobj = obase + objl;
        const float c0 = colors[gobj * 3], c1 = colors[gobj * 3 + 1], c2 = colors[gobj * 3 + 2];
        const float q0 = positions[gobj * 3], q1 = positions[gobj * 3 + 1], q2 = positions[gobj * 3 + 2];
        const int u0 = (lane & 15) * 4;
        #pragma unroll
        for (int uu = 0; uu < 4; ++uu) {
            const int u = u0 + uu;
            const float hc = fmaxf(cb1[u] + c0 * cW1[u] + c1 * cW1[64 + u] + c2 * cW1[128 + u], 0.f);
            const float hp = fmaxf(pb1[u] + q0 * pW1[u] + q1 * pW1[64 + u] + q2 * pW1[128 + u], 0.f);
            ushort h, l;
            split2(hc, h, l); Ahc[objl * 72 + u] = h; Alc[objl * 72 + u] = l;
            split2(hp, h, l); Ahp[objl * 72 + u] = h; Alp[objl * 72 + u] = l;
        }
    }
    __syncthreads();

    f32x4 aco[4], ape[4];
    #pragma unroll
    for (int nt = 0; nt < 4; ++nt) { aco[nt] = (f32x4){0.f,0.f,0.f,0.f}; ape[nt] = (f32x4){0.f,0.f,0.f,0.f}; }

    #pragma unroll
    for (int kt = 0; kt < 2; ++kt) {
        const int ao = l15 * 72 + kt * 32 + quad * 8;
        const s16x8 ahc = *(const s16x8*)&Ahc[ao];
        const s16x8 alc = *(const s16x8*)&Alc[ao];
        const s16x8 ahp = *(const s16x8*)&Ahp[ao];
        const s16x8 alp = *(const s16x8*)&Alp[ao];
        #pragma unroll
        for (int nt = 0; nt < 4; ++nt) {
            const int n = w * 64 + nt * 16 + l15;
            const size_t bo = (size_t)n * 64 + kt * 32 + quad * 8;
            const s16x8 cbh = *(const s16x8*)(cW2Th + bo);
            const s16x8 cbl = *(const s16x8*)(cW2Tl + bo);
            const s16x8 pbh = *(const s16x8*)(pW2Th + bo);
            const s16x8 pbl = *(const s16x8*)(pW2Tl + bo);
            aco[nt] = __builtin_amdgcn_mfma_f32_16x16x32_bf16(ahc, cbh, aco[nt], 0, 0, 0);
            ape[nt] = __builtin_amdgcn_mfma_f32_16x16x32_bf16(ahp, pbh, ape[nt], 0, 0, 0);
            aco[nt] = __builtin_amdgcn_mfma_f32_16x16x32_bf16(alc, cbh, aco[nt], 0, 0, 0);
            ape[nt] = __builtin_amdgcn_mfma_f32_16x16x32_bf16(alp, pbh, ape[nt], 0, 0, 0);
            aco[nt] = __builtin_amdgcn_mfma_f32_16x16x32_bf16(ahc, cbl, aco[nt], 0, 0, 0);
            ape[nt] = __builtin_amdgcn_mfma_f32_16x16x32_bf16(ahp, pbl, ape[nt], 0, 0, 0);
        }
    }

    float sc[4] = {0.f,0.f,0.f,0.f}, sp[4] = {0.f,0.f,0.f,0.f};
    #pragma unroll
    for (int nt = 0; nt < 4; ++nt) {
        const int col = w * 64 + nt * 16 + l15;
        const float cbv = cb2[col], pbv = pb2[col];
        #pragma unroll
        for (int r = 0; r < 4; ++r) {
            const float co = aco[nt][r] + cbv;
            const float pe = ape[nt][r] + pbv;
            sc[r] += co * co;
            sp[r] += pe * pe;
        }
    }
    #pragma unroll
    for (int s = 8; s > 0; s >>= 1) {
        #pragma unroll
        for (int r = 0; r < 4; ++r) {
            sc[r] += __shfl_xor(sc[r], s, 64);
            sp[r] += __shfl_xor(sp[r], s, 64);
        }
    }
    if (l15 == 0) {
        #pragma unroll
        for (int r = 0; r < 4; ++r) { sqc[quad * 4 + r][w] = sc[r]; sqp_[quad * 4 + r][w] = sp[r]; }
    }
    __syncthreads();

    float rco[4], rpe[4];
    #pragma unroll
    for (int r = 0; r < 4; ++r) {
        const int row = quad * 4 + r;
        rco[r] = 1.f / fmaxf(sqrtf(sqc[row][0] + sqc[row][1] + sqc[row][2] + sqc[row][3]), 1e-12f);
        rpe[r] = 1.f / fmaxf(sqrtf(sqp_[row][0] + sqp_[row][1] + sqp_[row][2] + sqp_[row][3]), 1e-12f);
    }

    f32x4 ac[4], ap[4];
    #pragma unroll
    for (int nt = 0; nt < 4; ++nt) { ac[nt] = (f32x4){0.f,0.f,0.f,0.f}; ap[nt] = (f32x4){0.f,0.f,0.f,0.f}; }

    #pragma unroll
    for (int kt = 0; kt < 2; ++kt) {
        const int ao = l15 * 72 + kt * 32 + quad * 8;
        const s16x8 ahc = *(const s16x8*)&Ahc[ao];
        const s16x8 alc = *(const s16x8*)&Alc[ao];
        const s16x8 ahp = *(const s16x8*)&Ahp[ao];
        const s16x8 alp = *(const s16x8*)&Alp[ao];
        #pragma unroll
        for (int nt = 0; nt < 4; ++nt) {
            const int n = w * 64 + nt * 16 + l15;
            const size_t bo = (size_t)n * 64 + kt * 32 + quad * 8;
            const s16x8 cbh = *(const s16x8*)(WcTh + bo);
            const s16x8 cbl = *(const s16x8*)(WcTl + bo);
            const s16x8 pbh = *(const s16x8*)(WpTh + bo);
            const s16x8 pbl = *(const s16x8*)(WpTl + bo);
            ac[nt] = __builtin_amdgcn_mfma_f32_16x16x32_bf16(ahc, cbh, ac[nt], 0, 0, 0);
            ap[nt] = __builtin_amdgcn_mfma_f32_16x16x32_bf16(ahp, pbh, ap[nt], 0, 0, 0);
            ac[nt] = __builtin_amdgcn_mfma_f32_16x16x32_bf16(alc, cbh, ac[nt], 0, 0, 0);
            ap[nt] = __builtin_amdgcn_mfma_f32_16x16x32_bf16(alp, pbh, ap[nt], 0, 0, 0);
            ac[nt] = __builtin_amdgcn_mfma_f32_16x16x32_bf16(ahc, cbl, ac[nt], 0, 0, 0);
            ap[nt] = __builtin_amdgcn_mfma_f32_16x16x32_bf16(ahp, pbl, ap[nt], 0, 0, 0);
        }
    }

    int ci[4];
    #pragma unroll
    for (int r = 0; r < 4; ++r) {
        const int gobj = obase + quad * 4 + r;
        int c = cls[(size_t)gobj * cstride];
        if ((unsigned)c > 30u) c = 0;
        ci[r] = c;
    }

    float rp[4] = {0.f,0.f,0.f,0.f};
    #pragma unroll
    for (int nt = 0; nt < 4; ++nt) {
        const int col = w * 64 + nt * 16 + l15;
        const float mbv = mb[col], cbMv = cbM[col], pbMv = pbM[col];
        #pragma unroll
        for (int r = 0; r < 4; ++r) {
            const int row = quad * 4 + r;
            const float e = classMn[ci[r] * 256 + col]
                          + rco[r] * (ac[nt][r] + cbMv)
                          + rpe[r] * (ap[nt][r] + pbMv) + mbv;
            ushort h, l;
            split2(e, h, l);
            ehi[(size_t)(obase + row) * 256 + col] = h;
            elo[(size_t)(obase + row) * 256 + col] = l;
            rp[r] += e * e;
        }
    }
    #pragma unroll
    for (int s = 8; s > 0; s >>= 1) {
        #pragma unroll
        for (int r = 0; r < 4; ++r) rp[r] += __shfl_xor(rp[r], s, 64);
    }
    if (l15 == 0) {
        #pragma unroll
        for (int r = 0; r < 4; ++r) sqe[quad * 4 + r][w] = rp[r];
    }
    __syncthreads();
    if (t < 16) sqn[obase + t] = sqe[t][0] + sqe[t][1] + sqe[t][2] + sqe[t][3];
}

// ---------------------------------------------------------------------------
// Kernel 2: Gram/distance. m97-style 128x128 tile per block, double-buffered
// LDS staged via global_load_lds (width 16), BK=32/step, XOR chunk-swizzle
// on both sides (rule 21). Diagonal tiles stage A only. Nontemporal dist.
// ---------------------------------------------------------------------------
__global__ __launch_bounds__(256)
void k_gram(const ushort* __restrict__ ehi, const ushort* __restrict__ elo,
            const float* __restrict__ sqn, float* __restrict__ dist)
{
    // [dbuf][Ah,Al,Bh,Bl][128 rows * 32 k], 64 KB total
    __shared__ __align__(16) ushort lds[2][4][4096];

    const int t = threadIdx.x, w = t >> 6, lane = t & 63;
    const int l15 = lane & 15, quad = lane >> 4;
    const int b = blockIdx.x;
    const int xcd = b & 7, rest = b >> 3;        // rest 0..127
    const int cell = xcd * 8 + (rest >> 4);      // 0..63
    const int tile = rest & 15;
    const int p0 = (tile >> 2) * 128, q0 = (tile & 3) * 128;
    const size_t cb = (size_t)cell * NP;
    const int diag = (p0 == q0);
    const int wr = w >> 1, wc = w & 1;           // 2x2 wave grid, 64x64 each

    int srow[2], scol[2];
    #pragma unroll
    for (int i = 0; i < 2; ++i) {
        const int p = (w * 2 + i) * 64 + lane;
        const int row = p >> 2;
        srow[i] = row;
        scol[i] = ((p & 3) ^ ((row >> 1) & 3)) * 8;   // ushort offset of 16B chunk
    }

    #define STAGE(KT, D)                                                         \
    {                                                                            \
        const int kb_ = (KT) * 32;                                               \
        _Pragma("unroll")                                                        \
        for (int i = 0; i < 2; ++i) {                                            \
            const int ls_ = (w * 2 + i) * 512;   /* slot*8 ushorts */            \
            const size_t ga_ = (cb + p0 + srow[i]) * 256 + kb_ + scol[i];        \
            gload16(ehi + ga_, &lds[D][0][ls_]);                                 \
            gload16(elo + ga_, &lds[D][1][ls_]);                                 \
            if (!diag) {                                                         \
                const size_t gq_ = (cb + q0 + srow[i]) * 256 + kb_ + scol[i];    \
                gload16(ehi + gq_, &lds[D][2][ls_]);                             \
                gload16(elo + gq_, &lds[D][3][ls_]);                             \
            }                                                                    \
        }                                                                        \
    }

    f32x4 acc[4][4];
    #pragma unroll
    for (int mt = 0; mt < 4; ++mt)
        #pragma unroll
        for (int nt = 0; nt < 4; ++nt) acc[mt][nt] = (f32x4){0.f, 0.f, 0.f, 0.f};

    const int bB = diag ? 0 : 2;

    STAGE(0, 0);
    __syncthreads();

    for (int kt = 0; kt < 8; ++kt) {
        const int cur = kt & 1;
        if (kt < 7) STAGE(kt + 1, cur ^ 1);      // prefetch next k-slice

        s16x8 ah[4], al[4];
        #pragma unroll
        for (int mt = 0; mt < 4; ++mt) {
            const int r = wr * 64 + mt * 16 + l15;
            const int slot = 4 * r + (quad ^ ((r >> 1) & 3));
            ah[mt] = *(const s16x8*)&lds[cur][0][slot * 8];
            al[mt] = *(const s16x8*)&lds[cur][1][slot * 8];
        }
        #pragma unroll
        for (int nt = 0; nt < 4; ++nt) {
            const int rq = wc * 64 + nt * 16 + l15;
            const int slot = 4 * rq + (quad ^ ((rq >> 1) & 3));
            const s16x8 bh = *(const s16x8*)&lds[cur][bB][slot * 8];
            const s16x8 bl = *(const s16x8*)&lds[cur][bB + 1][slot * 8];
            #pragma unroll
            for (int mt = 0; mt < 4; ++mt) {
                acc[mt][nt] = __builtin_amdgcn_mfma_f32_16x16x32_bf16(ah[mt], bh, acc[mt][nt], 0, 0, 0);
                acc[mt][nt] = __builtin_amdgcn_mfma_f32_16x16x32_bf16(al[mt], bh, acc[mt][nt], 0, 0, 0);
                acc[mt][nt] = __builtin_amdgcn_mfma_f32_16x16x32_bf16(ah[mt], bl, acc[mt][nt], 0, 0, 0);
            }
        }
        __syncthreads();                          // drains vmcnt(0) -> buf ready
    }
    #undef STAGE

    float sqp[4][4];
    #pragma unroll
    for (int mt = 0; mt < 4; ++mt)
        #pragma unroll
        for (int r = 0; r < 4; ++r)
            sqp[mt][r] = sqn[cb + p0 + wr * 64 + mt * 16 + quad * 4 + r];

    #pragma unroll
    for (int nt = 0; nt < 4; ++nt) {
        const int colq = q0 + wc * 64 + nt * 16 + l15;
        const float sq_q = sqn[cb + colq];
        #pragma unroll
        for (int mt = 0; mt < 4; ++mt) {
            #pragma unroll
            for (int r = 0; r < 4; ++r) {
                const int rowp = p0 + wr * 64 + mt * 16 + quad * 4 + r;
                __builtin_nontemporal_store((sqp[mt][r] + sq_q) - 2.f * acc[mt][nt][r],
                                            &dist[(cb + rowp) * NP + colq]);
            }
        }
    }
}

// ---------------------------------------------------------------------------
// Kernel 3: top-8 smallest per point (ties -> lowest index). One wave/point.
// ---------------------------------------------------------------------------
__global__ __launch_bounds__(256)
void k_select(const float* __restrict__ dist, int* __restrict__ nidx)
{
    const int wv = threadIdx.x >> 6, lane = threadIdx.x & 63;
    const int xcd = blockIdx.x & 7, rest = blockIdx.x >> 3;   // rest 0..1023
    const int cell = xcd * 8 + (rest >> 7);                   // 0..63
    const int p = cell * NP + (rest & 127) * 4 + wv;          // global point
    const float* row = dist + (size_t)p * NP;

    float d[8];
    {
        const float4 va = *(const float4*)(row + lane * 8);
        const float4 vb = *(const float4*)(row + lane * 8 + 4);
        d[0] = va.x; d[1] = va.y; d[2] = va.z; d[3] = va.w;
        d[4] = vb.x; d[5] = vb.y; d[6] = vb.z; d[7] = vb.w;
    }

    for (int r = 0; r < KNN; ++r) {
        float bd = d[0]; int bi = 0;
        #pragma unroll
        for (int i = 1; i < 8; ++i)
            if (d[i] < bd) { bd = d[i]; bi = i; }   // strict < keeps lowest i on tie
        int bq = lane * 8 + bi;
        #pragma unroll
        for (int s = 32; s > 0; s >>= 1) {
            const float od = __shfl_down(bd, s, 64);
            const int oq = __shfl_down(bq, s, 64);
            if (od < bd || (od == bd && oq < bq)) { bd = od; bq = oq; }
        }
        const int win = __shfl(bq, 0, 64);
        if (lane == 0) nidx[(size_t)p * KNN + r] = ((p >> 9) << 9) | win;
        if ((win >> 3) == lane) {
            const int wi = win & 7;
            #pragma unroll
            for (int i = 0; i < 8; ++i) if (wi == i) d[i] = 3.4e38f;
        }
    }
}

// ---------------------------------------------------------------------------
// Kernel 4: u = x@Wd+gb1, v = x@Wb via 2-pass split MFMA (A hi+lo, B hi only).
// 64 points/block: wave = 2 m-frags x 128 cols. REWORKED: A (ehi/elo) is now
// staged per k-step through double-buffered LDS via global_load_lds width-16
// with the k_gram XOR chunk-swizzle (both sides, rule 21) -- replaces the
// per-lane 512B-strided global A reads that left this kernel latency-bound.
// B (Wh, 128 KB, L2-hot) stays direct. Same MFMA order/operands -> u,v
// bit-identical.
// ---------------------------------------------------------------------------
__global__ __launch_bounds__(256)
void k_uv(const ushort* __restrict__ ehi, const ushort* __restrict__ elo,
          const ushort* __restrict__ Wdh, const ushort* __restrict__ Wbh,
          const float* __restrict__ gb1,
          float* __restrict__ u, float* __restrict__ v)
{
    __shared__ __align__(16) ushort lds[2][2][2048];   // [dbuf][hi/lo][slot*8], 16 KB

    const int t = threadIdx.x, w = t >> 6, lane = t & 63;
    const int l15 = lane & 15, quad = lane >> 4;
    const int isV = blockIdx.x >> 9;           // 1024 blocks total
    const int m0 = (blockIdx.x & 511) * 64;
    const ushort* Wh = isV ? Wbh : Wdh;
    float* out = isV ? v : u;
    const int mh = w & 1, ch = w >> 1;

    // staging: 256 slots of 16B per array (64 rows x 4 chunks); wave w covers
    // slots [w*64, w*64+64). slot p holds (row = p>>2, chunk = (p&3)^((row>>1)&3)).
    const int sp = w * 64 + lane;
    const int srow = sp >> 2;
    const int scol = ((sp & 3) ^ ((srow >> 1) & 3)) * 8;   // ushort offset

    #define STAGE_UV(S, D)                                                       \
    {                                                                            \
        const size_t ga_ = (size_t)(m0 + srow) * 256 + (S) * 32 + scol;          \
        gload16(ehi + ga_, &lds[D][0][sp * 8]);                                  \
        gload16(elo + ga_, &lds[D][1][sp * 8]);                                  \
    }

    // read-side slots for this wave's two A-row fragments
    const int r0 = mh * 32 + l15, r1 = r0 + 16;
    const int slot0 = 4 * r0 + (quad ^ ((r0 >> 1) & 3));
    const int slot1 = 4 * r1 + (quad ^ ((r1 >> 1) & 3));

    f32x4 acc[2][8];
    #pragma unroll
    for (int mt = 0; mt < 2; ++mt)
        #pragma unroll
        for (int nt = 0; nt < 8; ++nt) acc[mt][nt] = (f32x4){0.f, 0.f, 0.f, 0.f};

    STAGE_UV(0, 0);
    __syncthreads();

    for (int s = 0; s < 8; ++s) {
        const int cur = s & 1;
        if (s < 7) STAGE_UV(s + 1, cur ^ 1);   // prefetch next k-slice

        const s16x8 ah0 = *(const s16x8*)&lds[cur][0][slot0 * 8];
        const s16x8 al0 = *(const s16x8*)&lds[cur][1][slot0 * 8];
        const s16x8 ah1 = *(const s16x8*)&lds[cur][0][slot1 * 8];
        const s16x8 al1 = *(const s16x8*)&lds[cur][1][slot1 * 8];
        #pragma unroll
        for (int nt = 0; nt < 8; ++nt) {
            const int n = ch * 128 + nt * 16 + l15;
            const size_t bo = (size_t)n * 256 + s * 32 + quad * 8;
            const s16x8 bh = *(const s16x8*)(Wh + bo);
            acc[0][nt] = __builtin_amdgcn_mfma_f32_16x16x32_bf16(ah0, bh, acc[0][nt], 0, 0, 0);
            acc[0][nt] = __builtin_amdgcn_mfma_f32_16x16x32_bf16(al0, bh, acc[0][nt], 0, 0, 0);
            acc[1][nt] = __builtin_amdgcn_mfma_f32_16x16x32_bf16(ah1, bh, acc[1][nt], 0, 0, 0);
            acc[1][nt] = __builtin_amdgcn_mfma_f32_16x16x32_bf16(al1, bh, acc[1][nt], 0, 0, 0);
        }
        __syncthreads();                        // drains vmcnt(0) -> buf ready
    }
    #undef STAGE_UV

    #pragma unroll
    for (int mt = 0; mt < 2; ++mt) {
        #pragma unroll
        for (int nt = 0; nt < 8; ++nt) {
            const int col = ch * 128 + nt * 16 + l15;
            const float bias = isV ? 0.f : gb1[col];
            #pragma unroll
            for (int r = 0; r < 4; ++r) {
                const int row = mh * 32 + mt * 16 + quad * 4 + r;
                out[(size_t)(m0 + row) * 256 + col] = acc[mt][nt][r] + bias;
            }
        }
    }
}

// ---------------------------------------------------------------------------
// Kernel 5: edge GEMM + max aggregation. Block = 8 points (64 edges), 4 waves;
// wave w = all 64 edges x cols w*64..+63. 2-pass split (A trunc-split hi+lo,
// B hi only). LDS-only inner barrier (lgkmcnt(0)+s_barrier) keeps v/B global
// loads in flight across barriers.
// ---------------------------------------------------------------------------
__global__ __launch_bounds__(256)
void k_edge(const float* __restrict__ u, const float* __restrict__ v,
            const int* __restrict__ nidx,
            const ushort* __restrict__ g2h,
            const float* __restrict__ hb,
            float* __restrict__ part)
{
    __shared__ ushort Abuf[2][2][2304];   // [dbuf][hi/lo][edge*36+k], 18.4 KB
    __shared__ float ustage[2048];        // 8 pts x 256 k, 8 KB

    const int t = threadIdx.x, w = t >> 6, lane = t & 63;
    const int l15 = lane & 15, quad = lane >> 4;

    const int b = blockIdx.x;
    const int xcd = b & 7, rest = b >> 3;        // rest 0..511
    const int cell = xcd * 8 + (rest >> 6);      // 0..63
    const int pl0 = cell * NP + (rest & 63) * 8;

    // stage u rows once (coalesced, 8 floats per thread)
    {
        const int pt = t >> 5, kk = (t & 31) * 8;
        const float4 a = *(const float4*)(u + (size_t)(pl0 + pt) * 256 + kk);
        const float4 bq = *(const float4*)(u + (size_t)(pl0 + pt) * 256 + kk + 4);
        *(float4*)&ustage[pt * 256 + kk] = a;
        *(float4*)&ustage[pt * 256 + kk + 4] = bq;
    }

    const int se = t >> 2, kq = t & 3;
    const int upt = se >> 3;                     // point within block
    int svrow = nidx[(size_t)(pl0 + upt) * KNN + (se & 7)];
    if ((unsigned)svrow >= (unsigned)NTOT) svrow = 0;

    __syncthreads();                             // ustage visible (one-time)

    float4 vr[2][2];                             // 2-set v pipeline

    #define VLOAD(S)                                                             \
    {                                                                            \
        const int k0 = (S) * 32 + kq * 8;                                        \
        vr[(S) & 1][0] = *(const float4*)(v + (size_t)svrow * 256 + k0);         \
        vr[(S) & 1][1] = *(const float4*)(v + (size_t)svrow * 256 + k0 + 4);     \
    }
    #define SPLITW(S, BUF)                                                       \
    {                                                                            \
        const int k0u = (S) * 32 + kq * 8;                                       \
        const float4 ua = *(const float4*)&ustage[upt * 256 + k0u];              \
        const float4 ub = *(const float4*)&ustage[upt * 256 + k0u + 4];          \
        const float4 va = vr[(S) & 1][0], vb = vr[(S) & 1][1];                   \
        const float sv[8] = {                                                    \
            fmaxf(ua.x + va.x, 0.f), fmaxf(ua.y + va.y, 0.f),                    \
            fmaxf(ua.z + va.z, 0.f), fmaxf(ua.w + va.w, 0.f),                    \
            fmaxf(ub.x + vb.x, 0.f), fmaxf(ub.y + vb.y, 0.f),                    \
            fmaxf(ub.z + vb.z, 0.f), fmaxf(ub.w + vb.w, 0.f)};                   \
        union { uint2 q[2]; ushort us[8]; } th, tl;                              \
        _Pragma("unroll")                                                        \
        for (int j = 0; j < 8; ++j) { split2t(sv[j], th.us[j], tl.us[j]); }      \
        *(uint2*)&Abuf[BUF][0][se * 36 + kq * 8]     = th.q[0];                  \
        *(uint2*)&Abuf[BUF][0][se * 36 + kq * 8 + 4] = th.q[1];                  \
        *(uint2*)&Abuf[BUF][1][se * 36 + kq * 8]     = tl.q[0];                  \
        *(uint2*)&Abuf[BUF][1][se * 36 + kq * 8 + 4] = tl.q[1];                  \
    }

    // LDS-only barrier: completes all DS ops issued before it, leaves
    // global loads (vmcnt) in flight across the barrier.
    #define LDS_BARRIER()                                                        \
    {                                                                            \
        asm volatile("s_waitcnt lgkmcnt(0)" ::: "memory");                       \
        __builtin_amdgcn_s_barrier();                                            \
    }

    f32x4 acc[4][4];
    #pragma unroll
    for (int mt = 0; mt < 4; ++mt)
        #pragma unroll
        for (int nt = 0; nt < 4; ++nt) acc[mt][nt] = (f32x4){0.f, 0.f, 0.f, 0.f};

    VLOAD(0); VLOAD(1);
    SPLITW(0, 0);

    #pragma unroll
    for (int s = 0; s < 8; ++s) {
        LDS_BARRIER();                        // buf[s&1] visible; buf[(s+1)&1] readers done
        if (s < 7) {
            SPLITW(s + 1, (s + 1) & 1);       // u from LDS, v register-resident
            if (s < 6) VLOAD(s + 2);          // stays in flight across barriers
        }

        const int k0 = s * 32 + quad * 8;
        s16x8 ah[4], al[4];
        #pragma unroll
        for (int mt = 0; mt < 4; ++mt) {
            const int ao = (mt * 16 + l15) * 36 + quad * 8;
            union { uint2 q[2]; s16x8 v8; } Th, Tl;
            Th.q[0] = *(const uint2*)&Abuf[s & 1][0][ao];
            Th.q[1] = *(const uint2*)&Abuf[s & 1][0][ao + 4];
            Tl.q[0] = *(const uint2*)&Abuf[s & 1][1][ao];
            Tl.q[1] = *(const uint2*)&Abuf[s & 1][1][ao + 4];
            ah[mt] = Th.v8; al[mt] = Tl.v8;
        }
        #pragma unroll
        for (int nt = 0; nt < 4; ++nt) {
            const int n = w * 64 + nt * 16 + l15;
            const s16x8 bh = *(const s16x8*)(g2h + (size_t)n * 256 + k0);
            #pragma unroll
            for (int mt = 0; mt < 4; ++mt) {
                acc[mt][nt] = __builtin_amdgcn_mfma_f32_16x16x32_bf16(ah[mt], bh, acc[mt][nt], 0, 0, 0);
                acc[mt][nt] = __builtin_amdgcn_mfma_f32_16x16x32_bf16(al[mt], bh, acc[mt][nt], 0, 0, 0);
            }
        }
    }
    #undef VLOAD
    #undef SPLITW
    #undef LDS_BARRIER

    const int slot = rest & 63;
    #pragma unroll
    for (int nt = 0; nt < 4; ++nt) {
        float rm = -3.4e38f;
        #pragma unroll
        for (int mt = 0; mt < 4; ++mt)
            rm = fmaxf(rm, fmaxf(fmaxf(acc[mt][nt][0], acc[mt][nt][1]),
                                 fmaxf(acc[mt][nt][2], acc[mt][nt][3])));
        rm = fmaxf(rm, __shfl_xor(rm, 16, 64));
        rm = fmaxf(rm, __shfl_xor(rm, 32, 64));
        if (quad == 0) {
            const int col = w * 64 + nt * 16 + l15;
            part[((size_t)cell * 64 + slot) * 256 + col] = rm + hb[col];
        }
    }
}

// ---------------------------------------------------------------------------
// Kernel 6: reduce 64 partial maxes per cell, final MLP (f32), L2 normalize.
// ---------------------------------------------------------------------------
__global__ __launch_bounds__(256)
void k_final(const float* __restrict__ part,
             const float* __restrict__ lW1, const float* __restrict__ lb1,
             const float* __restrict__ lW2, const float* __restrict__ lb2,
             float* __restrict__ out)
{
    __shared__ float pooled[256];
    __shared__ float hid[256];
    __shared__ float red[4];

    const int b = blockIdx.x;
    const int t = threadIdx.x;

    float m = -3.4e38f;
    for (int s = 0; s < 64; ++s)
        m = fmaxf(m, part[((size_t)b * 64 + s) * 256 + t]);
    pooled[t] = m;
    __syncthreads();

    float h = lb1[t];
    for (int k = 0; k < 256; k += 4) {
        #pragma unroll
        for (int kk = 0; kk < 4; ++kk)
            h += pooled[k + kk] * lW1[(k + kk) * 256 + t];
    }
    hid[t] = fmaxf(h, 0.f);
    __syncthreads();

    float o = lb2[t];
    for (int k = 0; k < 256; k += 4) {
        #pragma unroll
        for (int kk = 0; kk < 4; ++kk)
            o += hid[k + kk] * lW2[(k + kk) * 256 + t];
    }

    float ss = o * o;
    #pragma unroll
    for (int s = 32; s > 0; s >>= 1) ss += __shfl_down(ss, s, 64);
    if ((t & 63) == 0) red[t >> 6] = ss;
    __syncthreads();
    const float tot = red[0] + red[1] + red[2] + red[3];
    const float rn = 1.f / fmaxf(sqrtf(tot), 1e-12f);
    out[b * 256 + t] = o * rn;
}

// ---------------------------------------------------------------------------
extern "C" void kernel_launch(void* const* d_in, const int* in_sizes, int n_in,
                              void* d_out, int out_size, void* d_ws, size_t ws_size,
                              hipStream_t stream)
{
    (void)n_in; (void)out_size; (void)ws_size;

    const float* class_table = (const float*)d_in[0];
    const float* cW1 = (const float*)d_in[1];
    const float* cb1 = (const float*)d_in[2];
    const float* cW2 = (const float*)d_in[3];
    const float* cb2 = (const float*)d_in[4];
    const float* pW1 = (const float*)d_in[5];
    const float* pb1 = (const float*)d_in[6];
    const float* pW2 = (const float*)d_in[7];
    const float* pb2 = (const float*)d_in[8];
    const float* mW  = (const float*)d_in[9];
    const float* mb  = (const float*)d_in[10];
    const float* gW1 = (const float*)d_in[11];
    const float* gb1 = (const float*)d_in[12];
    const float* g_gamma = (const float*)d_in[13];
    const float* g_beta  = (const float*)d_in[14];
    const float* gW2 = (const float*)d_in[15];
    const float* gb2 = (const float*)d_in[16];
    const float* lW1 = (const float*)d_in[17];
    const float* lb1 = (const float*)d_in[18];
    const float* lW2 = (const float*)d_in[19];
    const float* lb2 = (const float*)d_in[20];
    const float* positions = (const float*)d_in[21];
    const float* colors    = (const float*)d_in[22];
    const int*  cls        = (const int*)d_in[23];

    const int cstride = (in_sizes[23] == 2 * NTOT) ? 2 : 1;

    // workspace layout (bytes), total ~174 MB (ws_size ~268 MB).
    char* base = (char*)d_ws;
    float*   part   = (float*)(base + 0);               //   4,194,304
    ushort*  Wdh    = (ushort*)(base + 4194304);
    ushort*  Wdl    = (ushort*)(base + 4325376);
    ushort*  Wbh    = (ushort*)(base + 4456448);
    ushort*  Wbl    = (ushort*)(base + 4587520);
    ushort*  g2h    = (ushort*)(base + 4718592);
    ushort*  g2l    = (ushort*)(base + 4849664);
    float*   hb     = (float*)(base + 4980736);
    ushort*  cW2Th  = (ushort*)(base + 4981760);
    ushort*  cW2Tl  = (ushort*)(base + 5014528);
    ushort*  pW2Th  = (ushort*)(base + 5047296);
    ushort*  pW2Tl  = (ushort*)(base + 5080064);
    ushort*  WcTh   = (ushort*)(base + 5112832);
    ushort*  WcTl   = (ushort*)(base + 5145600);
    ushort*  WpTh   = (ushort*)(base + 5178368);
    ushort*  WpTl   = (ushort*)(base + 5211136);
    float*   classMn= (float*)(base + 5243904);
    float*   cbM    = (float*)(base + 5275648);
    float*   pbM    = (float*)(base + 5276672);
    int*     nidx   = (int*)(base + 5277696);           //   1,048,576
    float*   sqn    = (float*)(base + 6326272);         //     131,072
    ushort*  ehi    = (ushort*)(base + 6457344);        //  16,777,216
    ushort*  elo    = (ushort*)(base + 23234560);       //  16,777,216
    float*   dist   = (float*)(base + 40011776);        //  67,108,864
    float*   v      = (float*)(base + 107120640);       //  33,554,432
    float*   u      = (float*)(base + 140675072);       //  33,554,432
    float* out = (float*)d_out;

    k_cvt<<<897, 256, 0, stream>>>(gW1, gW2, g_gamma, g_beta, gb2, cW2, pW2,
                                   Wdh, Wdl, Wbh, Wbl, g2h, g2l, hb,
                                   cW2Th, cW2Tl, pW2Th, pW2Tl);
    k_fold<<<130, 256, 0, stream>>>(cW2, pW2, cb2, pb2, mW,
                                    WcTh, WcTl, WpTh, WpTl, cbM, pbM);
    k_cls<<<31, 256, 0, stream>>>(class_table, mW, classMn);

    k_embed<<<NTOT / 16, 256, 0, stream>>>(classMn, cW1, cb1, cb2, pW1, pb1, pb2,
                                           mb, cW2Th, cW2Tl, pW2Th, pW2Tl,
                                           WcTh, WcTl, WpTh, WpTl, cbM, pbM,
                                           positions, colors, cls, cstride,
                                           ehi, elo, sqn);
    k_gram<<<NB * 16, 256, 0, stream>>>(ehi, elo, sqn, dist);
    k_select<<<NTOT / 4, 256, 0, stream>>>(dist, nidx);
    k_uv<<<2 * NTOT / 64, 256, 0, stream>>>(ehi, elo, Wdh, Wbh, gb1, u, v);
    k_edge<<<NTOT / 8, 256, 0, stream>>>(u, v, nidx, g2h, hb, part);
    k_final<<<NB, 256, 0, stream>>>(part, lW1, lb1, lW2, lb2, out);
}

// Round 8
// 437.651 us; speedup vs baseline: 1.0464x; 1.0095x over previous
//
#include <hip/hip_runtime.h>

#define EDIM 256
#define KNN 8
#define NB 64
#define NP 512
#define NTOT (NB * NP)

typedef short s16x8 __attribute__((ext_vector_type(8)));
typedef float f32x4 __attribute__((ext_vector_type(4)));
typedef float f32x16 __attribute__((ext_vector_type(16)));
typedef unsigned short ushort;

__device__ __forceinline__ ushort f2b(float f) {
    unsigned u = __float_as_uint(f);
    u = (u + 0x7fffu + ((u >> 16) & 1u)) >> 16;   // RNE
    return (ushort)u;
}
__device__ __forceinline__ float b2f(ushort h) {
    return __uint_as_float(((unsigned)h) << 16);
}
__device__ __forceinline__ void split2(float x, ushort& h, ushort& l) {
    h = f2b(x);
    l = f2b(x - b2f(h));
}
// truncation split (edge hot path): pair error ~2^-16 relative, fewer VALU
__device__ __forceinline__ ushort f2bt(float f) {
    return (ushort)(__float_as_uint(f) >> 16);
}
__device__ __forceinline__ void split2t(float x, ushort& h, ushort& l) {
    h = f2bt(x);
    l = f2bt(x - b2f(h));
}

// async global->LDS, 16B per lane; lds dest is wave-uniform base + lane*16
__device__ __forceinline__ void gload16(const ushort* g, ushort* l) {
    __builtin_amdgcn_global_load_lds(
        (const __attribute__((address_space(1))) void*)g,
        (__attribute__((address_space(3))) void*)l, 16, 0, 0);
}

// ---------------------------------------------------------------------------
// Kernel 0a: weight prep -> transposed bf16 hi/lo pairs.
// ---------------------------------------------------------------------------
__global__ __launch_bounds__(256)
void k_cvt(const float* __restrict__ gW1, const float* __restrict__ gW2,
           const float* __restrict__ g_gamma, const float* __restrict__ g_beta,
           const float* __restrict__ gb2,
           const float* __restrict__ cW2, const float* __restrict__ pW2,
           ushort* __restrict__ Wdh, ushort* __restrict__ Wdl,
           ushort* __restrict__ Wbh, ushort* __restrict__ Wbl,
           ushort* __restrict__ g2h, ushort* __restrict__ g2l,
           float* __restrict__ hb,
           ushort* __restrict__ cW2Th, ushort* __restrict__ cW2Tl,
           ushort* __restrict__ pW2Th, ushort* __restrict__ pW2Tl)
{
    const int gid = blockIdx.x * 256 + threadIdx.x;
    ushort h, l;
    if (gid < 65536) {
        const int n = gid >> 8, k = gid & 255;
        split2(gW1[k * 256 + n] - gW1[(k + 256) * 256 + n], h, l);
        Wdh[gid] = h; Wdl[gid] = l;
    } else if (gid < 131072) {
        const int i = gid - 65536, n = i >> 8, k = i & 255;
        split2(gW1[(k + 256) * 256 + n], h, l);
        Wbh[i] = h; Wbl[i] = l;
    } else if (gid < 196608) {
        const int i = gid - 131072, n = i >> 8, k = i & 255;
        split2(g_gamma[k] * gW2[k * 256 + n], h, l);
        g2h[i] = h; g2l[i] = l;
    } else if (gid < 196864) {
        const int n = gid - 196608;
        float s = gb2[n];
        for (int k = 0; k < 256; ++k) s += g_beta[k] * gW2[k * 256 + n];
        hb[n] = s;
    } else if (gid < 213248) {
        const int i = gid - 196864, n = i >> 6, k = i & 63;
        split2(cW2[k * 256 + n], h, l);
        cW2Th[i] = h; cW2Tl[i] = l;
    } else if (gid < 229632) {
        const int i = gid - 213248, n = i >> 6, k = i & 63;
        split2(pW2[k * 256 + n], h, l);
        pW2Th[i] = h; pW2Tl[i] = l;
    }
}

// ---------------------------------------------------------------------------
// Kernel 0b: fold merge GEMM into the MLP weights (linearity).
// ---------------------------------------------------------------------------
__global__ __launch_bounds__(256)
void k_fold(const float* __restrict__ cW2, const float* __restrict__ pW2,
            const float* __restrict__ cb2, const float* __restrict__ pb2,
            const float* __restrict__ mW,
            ushort* __restrict__ WcTh, ushort* __restrict__ WcTl,
            ushort* __restrict__ WpTh, ushort* __restrict__ WpTl,
            float* __restrict__ cbM, float* __restrict__ pbM)
{
    const int gid = blockIdx.x * 256 + threadIdx.x;
    ushort h, l;
    if (gid < 16384) {
        const int j = gid >> 8, n = gid & 255;
        float s = 0.f;
        for (int k = 0; k < 256; ++k) s += cW2[j * 256 + k] * mW[(256 + k) * 256 + n];
        split2(s, h, l);
        WcTh[n * 64 + j] = h; WcTl[n * 64 + j] = l;
    } else if (gid < 32768) {
        const int i = gid - 16384, j = i >> 8, n = i & 255;
        float s = 0.f;
        for (int k = 0; k < 256; ++k) s += pW2[j * 256 + k] * mW[(512 + k) * 256 + n];
        split2(s, h, l);
        WpTh[n * 64 + j] = h; WpTl[n * 64 + j] = l;
    } else if (gid < 33024) {
        const int n = gid - 32768;
        float s = 0.f;
        for (int k = 0; k < 256; ++k) s += cb2[k] * mW[(256 + k) * 256 + n];
        cbM[n] = s;
    } else if (gid < 33280) {
        const int n = gid - 33024;
        float s = 0.f;
        for (int k = 0; k < 256; ++k) s += pb2[k] * mW[(512 + k) * 256 + n];
        pbM[n] = s;
    }
}

// ---------------------------------------------------------------------------
// Kernel 0c: classMn[c] = (class_table[c] / ||class_table[c]||) @ M0.
// ---------------------------------------------------------------------------
__global__ __launch_bounds__(256)
void k_cls(const float* __restrict__ ct, const float* __restrict__ mW,
           float* __restrict__ classMn)
{
    __shared__ float ctn[256];
    __shared__ float red[4];
    const int c = blockIdx.x, t = threadIdx.x;
    const float v = ct[c * 256 + t];
    float ss = v * v;
    #pragma unroll
    for (int s = 32; s > 0; s >>= 1) ss += __shfl_down(ss, s, 64);
    if ((t & 63) == 0) red[t >> 6] = ss;
    __syncthreads();
    const float tot = red[0] + red[1] + red[2] + red[3];
    const float r = 1.f / fmaxf(sqrtf(tot), 1e-12f);
    ctn[t] = v * r;
    __syncthreads();
    float s = 0.f;
    for (int k = 0; k < 256; ++k) s += ctn[k] * mW[k * 256 + t];
    classMn[c * 256 + t] = s;
}

// ---------------------------------------------------------------------------
// Kernel 1: embeddings via folded GEMMs. 16 obj/block, full problem (2048).
// ---------------------------------------------------------------------------
__global__ __launch_bounds__(256)
void k_embed(const float* __restrict__ classMn,
             const float* __restrict__ cW1, const float* __restrict__ cb1,
             const float* __restrict__ cb2,
             const float* __restrict__ pW1, const float* __restrict__ pb1,
             const float* __restrict__ pb2,
             const float* __restrict__ mb,
             const ushort* __restrict__ cW2Th, const ushort* __restrict__ cW2Tl,
             const ushort* __restrict__ pW2Th, const ushort* __restrict__ pW2Tl,
             const ushort* __restrict__ WcTh, const ushort* __restrict__ WcTl,
             const ushort* __restrict__ WpTh, const ushort* __restrict__ WpTl,
             const float* __restrict__ cbM, const float* __restrict__ pbM,
             const float* __restrict__ positions, const float* __restrict__ colors,
             const int* __restrict__ cls, const int cstride,
             ushort* __restrict__ ehi, ushort* __restrict__ elo,
             float* __restrict__ sqn)
{
    __shared__ __align__(16) ushort Ahc[16 * 72];
    __shared__ __align__(16) ushort Alc[16 * 72];
    __shared__ __align__(16) ushort Ahp[16 * 72];
    __shared__ __align__(16) ushort Alp[16 * 72];
    __shared__ float sqc[16][4], sqp_[16][4], sqe[16][4];

    const int t = threadIdx.x, w = t >> 6, lane = t & 63;
    const int l15 = lane & 15, quad = lane >> 4;
    const int obase = blockIdx.x * 16;

    {
        const int o = lane >> 4;
        const int objl = w * 4 + o;
        const int gobj = obase + objl;
        const float c0 = colors[gobj * 3], c1 = colors[gobj * 3 + 1], c2 = colors[gobj * 3 + 2];
        const float q0 = positions[gobj * 3], q1 = positions[gobj * 3 + 1], q2 = positions[gobj * 3 + 2];
        const int u0 = (lane & 15) * 4;
        #pragma unroll
        for (int uu = 0; uu < 4; ++uu) {
            const int u = u0 + uu;
            const float hc = fmaxf(cb1[u] + c0 * cW1[u] + c1 * cW1[64 + u] + c2 * cW1[128 + u], 0.f);
            const float hp = fmaxf(pb1[u] + q0 * pW1[u] + q1 * pW1[64 + u] + q2 * pW1[128 + u], 0.f);
            ushort h, l;
            split2(hc, h, l); Ahc[objl * 72 + u] = h; Alc[objl * 72 + u] = l;
            split2(hp, h, l); Ahp[objl * 72 + u] = h; Alp[objl * 72 + u] = l;
        }
    }
    __syncthreads();

    f32x4 aco[4], ape[4];
    #pragma unroll
    for (int nt = 0; nt < 4; ++nt) { aco[nt] = (f32x4){0.f,0.f,0.f,0.f}; ape[nt] = (f32x4){0.f,0.f,0.f,0.f}; }

    #pragma unroll
    for (int kt = 0; kt < 2; ++kt) {
        const int ao = l15 * 72 + kt * 32 + quad * 8;
        const s16x8 ahc = *(const s16x8*)&Ahc[ao];
        const s16x8 alc = *(const s16x8*)&Alc[ao];
        const s16x8 ahp = *(const s16x8*)&Ahp[ao];
        const s16x8 alp = *(const s16x8*)&Alp[ao];
        #pragma unroll
        for (int nt = 0; nt < 4; ++nt) {
            const int n = w * 64 + nt * 16 + l15;
            const size_t bo = (size_t)n * 64 + kt * 32 + quad * 8;
            const s16x8 cbh = *(const s16x8*)(cW2Th + bo);
            const s16x8 cbl = *(const s16x8*)(cW2Tl + bo);
            const s16x8 pbh = *(const s16x8*)(pW2Th + bo);
            const s16x8 pbl = *(const s16x8*)(pW2Tl + bo);
            aco[nt] = __builtin_amdgcn_mfma_f32_16x16x32_bf16(ahc, cbh, aco[nt], 0, 0, 0);
            ape[nt] = __builtin_amdgcn_mfma_f32_16x16x32_bf16(ahp, pbh, ape[nt], 0, 0, 0);
            aco[nt] = __builtin_amdgcn_mfma_f32_16x16x32_bf16(alc, cbh, aco[nt], 0, 0, 0);
            ape[nt] = __builtin_amdgcn_mfma_f32_16x16x32_bf16(alp, pbh, ape[nt], 0, 0, 0);
            aco[nt] = __builtin_amdgcn_mfma_f32_16x16x32_bf16(ahc, cbl, aco[nt], 0, 0, 0);
            ape[nt] = __builtin_amdgcn_mfma_f32_16x16x32_bf16(ahp, pbl, ape[nt], 0, 0, 0);
        }
    }

    float sc[4] = {0.f,0.f,0.f,0.f}, sp[4] = {0.f,0.f,0.f,0.f};
    #pragma unroll
    for (int nt = 0; nt < 4; ++nt) {
        const int col = w * 64 + nt * 16 + l15;
        const float cbv = cb2[col], pbv = pb2[col];
        #pragma unroll
        for (int r = 0; r < 4; ++r) {
            const float co = aco[nt][r] + cbv;
            const float pe = ape[nt][r] + pbv;
            sc[r] += co * co;
            sp[r] += pe * pe;
        }
    }
    #pragma unroll
    for (int s = 8; s > 0; s >>= 1) {
        #pragma unroll
        for (int r = 0; r < 4; ++r) {
            sc[r] += __shfl_xor(sc[r], s, 64);
            sp[r] += __shfl_xor(sp[r], s, 64);
        }
    }
    if (l15 == 0) {
        #pragma unroll
        for (int r = 0; r < 4; ++r) { sqc[quad * 4 + r][w] = sc[r]; sqp_[quad * 4 + r][w] = sp[r]; }
    }
    __syncthreads();

    float rco[4], rpe[4];
    #pragma unroll
    for (int r = 0; r < 4; ++r) {
        const int row = quad * 4 + r;
        rco[r] = 1.f / fmaxf(sqrtf(sqc[row][0] + sqc[row][1] + sqc[row][2] + sqc[row][3]), 1e-12f);
        rpe[r] = 1.f / fmaxf(sqrtf(sqp_[row][0] + sqp_[row][1] + sqp_[row][2] + sqp_[row][3]), 1e-12f);
    }

    f32x4 ac[4], ap[4];
    #pragma unroll
    for (int nt = 0; nt < 4; ++nt) { ac[nt] = (f32x4){0.f,0.f,0.f,0.f}; ap[nt] = (f32x4){0.f,0.f,0.f,0.f}; }

    #pragma unroll
    for (int kt = 0; kt < 2; ++kt) {
        const int ao = l15 * 72 + kt * 32 + quad * 8;
        const s16x8 ahc = *(const s16x8*)&Ahc[ao];
        const s16x8 alc = *(const s16x8*)&Alc[ao];
        const s16x8 ahp = *(const s16x8*)&Ahp[ao];
        const s16x8 alp = *(const s16x8*)&Alp[ao];
        #pragma unroll
        for (int nt = 0; nt < 4; ++nt) {
            const int n = w * 64 + nt * 16 + l15;
            const size_t bo = (size_t)n * 64 + kt * 32 + quad * 8;
            const s16x8 cbh = *(const s16x8*)(WcTh + bo);
            const s16x8 cbl = *(const s16x8*)(WcTl + bo);
            const s16x8 pbh = *(const s16x8*)(WpTh + bo);
            const s16x8 pbl = *(const s16x8*)(WpTl + bo);
            ac[nt] = __builtin_amdgcn_mfma_f32_16x16x32_bf16(ahc, cbh, ac[nt], 0, 0, 0);
            ap[nt] = __builtin_amdgcn_mfma_f32_16x16x32_bf16(ahp, pbh, ap[nt], 0, 0, 0);
            ac[nt] = __builtin_amdgcn_mfma_f32_16x16x32_bf16(alc, cbh, ac[nt], 0, 0, 0);
            ap[nt] = __builtin_amdgcn_mfma_f32_16x16x32_bf16(alp, pbh, ap[nt], 0, 0, 0);
            ac[nt] = __builtin_amdgcn_mfma_f32_16x16x32_bf16(ahc, cbl, ac[nt], 0, 0, 0);
            ap[nt] = __builtin_amdgcn_mfma_f32_16x16x32_bf16(ahp, pbl, ap[nt], 0, 0, 0);
        }
    }

    int ci[4];
    #pragma unroll
    for (int r = 0; r < 4; ++r) {
        const int gobj = obase + quad * 4 + r;
        int c = cls[(size_t)gobj * cstride];
        if ((unsigned)c > 30u) c = 0;
        ci[r] = c;
    }

    float rp[4] = {0.f,0.f,0.f,0.f};
    #pragma unroll
    for (int nt = 0; nt < 4; ++nt) {
        const int col = w * 64 + nt * 16 + l15;
        const float mbv = mb[col], cbMv = cbM[col], pbMv = pbM[col];
        #pragma unroll
        for (int r = 0; r < 4; ++r) {
            const int row = quad * 4 + r;
            const float e = classMn[ci[r] * 256 + col]
                          + rco[r] * (ac[nt][r] + cbMv)
                          + rpe[r] * (ap[nt][r] + pbMv) + mbv;
            ushort h, l;
            split2(e, h, l);
            ehi[(size_t)(obase + row) * 256 + col] = h;
            elo[(size_t)(obase + row) * 256 + col] = l;
            rp[r] += e * e;
        }
    }
    #pragma unroll
    for (int s = 8; s > 0; s >>= 1) {
        #pragma unroll
        for (int r = 0; r < 4; ++r) rp[r] += __shfl_xor(rp[r], s, 64);
    }
    if (l15 == 0) {
        #pragma unroll
        for (int r = 0; r < 4; ++r) sqe[quad * 4 + r][w] = rp[r];
    }
    __syncthreads();
    if (t < 16) sqn[obase + t] = sqe[t][0] + sqe[t][1] + sqe[t][2] + sqe[t][3];
}

// ---------------------------------------------------------------------------
// Kernel 2: Gram/distance. m97-style 128x128 tile per block, double-buffered
// LDS staged via global_load_lds (width 16), BK=32/step, XOR chunk-swizzle
// on both sides (rule 21). Diagonal tiles stage A only. Nontemporal dist.
// BYTE-IDENTICAL to the passing R7 version (protects kNN bit-stability).
// ---------------------------------------------------------------------------
__global__ __launch_bounds__(256)
void k_gram(const ushort* __restrict__ ehi, const ushort* __restrict__ elo,
            const float* __restrict__ sqn, float* __restrict__ dist)
{
    // [dbuf][Ah,Al,Bh,Bl][128 rows * 32 k], 64 KB total
    __shared__ __align__(16) ushort lds[2][4][4096];

    const int t = threadIdx.x, w = t >> 6, lane = t & 63;
    const int l15 = lane & 15, quad = lane >> 4;
    const int b = blockIdx.x;
    const int xcd = b & 7, rest = b >> 3;        // rest 0..127
    const int cell = xcd * 8 + (rest >> 4);      // 0..63
    const int tile = rest & 15;
    const int p0 = (tile >> 2) * 128, q0 = (tile & 3) * 128;
    const size_t cb = (size_t)cell * NP;
    const int diag = (p0 == q0);
    const int wr = w >> 1, wc = w & 1;           // 2x2 wave grid, 64x64 each

    int srow[2], scol[2];
    #pragma unroll
    for (int i = 0; i < 2; ++i) {
        const int p = (w * 2 + i) * 64 + lane;
        const int row = p >> 2;
        srow[i] = row;
        scol[i] = ((p & 3) ^ ((row >> 1) & 3)) * 8;   // ushort offset of 16B chunk
    }

    #define STAGE(KT, D)                                                         \
    {                                                                            \
        const int kb_ = (KT) * 32;                                               \
        _Pragma("unroll")                                                        \
        for (int i = 0; i < 2; ++i) {                                            \
            const int ls_ = (w * 2 + i) * 512;   /* slot*8 ushorts */            \
            const size_t ga_ = (cb + p0 + srow[i]) * 256 + kb_ + scol[i];        \
            gload16(ehi + ga_, &lds[D][0][ls_]);                                 \
            gload16(elo + ga_, &lds[D][1][ls_]);                                 \
            if (!diag) {                                                         \
                const size_t gq_ = (cb + q0 + srow[i]) * 256 + kb_ + scol[i];    \
                gload16(ehi + gq_, &lds[D][2][ls_]);                             \
                gload16(elo + gq_, &lds[D][3][ls_]);                             \
            }                                                                    \
        }                                                                        \
    }

    f32x4 acc[4][4];
    #pragma unroll
    for (int mt = 0; mt < 4; ++mt)
        #pragma unroll
        for (int nt = 0; nt < 4; ++nt) acc[mt][nt] = (f32x4){0.f, 0.f, 0.f, 0.f};

    const int bB = diag ? 0 : 2;

    STAGE(0, 0);
    __syncthreads();

    for (int kt = 0; kt < 8; ++kt) {
        const int cur = kt & 1;
        if (kt < 7) STAGE(kt + 1, cur ^ 1);      // prefetch next k-slice

        s16x8 ah[4], al[4];
        #pragma unroll
        for (int mt = 0; mt < 4; ++mt) {
            const int r = wr * 64 + mt * 16 + l15;
            const int slot = 4 * r + (quad ^ ((r >> 1) & 3));
            ah[mt] = *(const s16x8*)&lds[cur][0][slot * 8];
            al[mt] = *(const s16x8*)&lds[cur][1][slot * 8];
        }
        #pragma unroll
        for (int nt = 0; nt < 4; ++nt) {
            const int rq = wc * 64 + nt * 16 + l15;
            const int slot = 4 * rq + (quad ^ ((rq >> 1) & 3));
            const s16x8 bh = *(const s16x8*)&lds[cur][bB][slot * 8];
            const s16x8 bl = *(const s16x8*)&lds[cur][bB + 1][slot * 8];
            #pragma unroll
            for (int mt = 0; mt < 4; ++mt) {
                acc[mt][nt] = __builtin_amdgcn_mfma_f32_16x16x32_bf16(ah[mt], bh, acc[mt][nt], 0, 0, 0);
                acc[mt][nt] = __builtin_amdgcn_mfma_f32_16x16x32_bf16(al[mt], bh, acc[mt][nt], 0, 0, 0);
                acc[mt][nt] = __builtin_amdgcn_mfma_f32_16x16x32_bf16(ah[mt], bl, acc[mt][nt], 0, 0, 0);
            }
        }
        __syncthreads();                          // drains vmcnt(0) -> buf ready
    }
    #undef STAGE

    float sqp[4][4];
    #pragma unroll
    for (int mt = 0; mt < 4; ++mt)
        #pragma unroll
        for (int r = 0; r < 4; ++r)
            sqp[mt][r] = sqn[cb + p0 + wr * 64 + mt * 16 + quad * 4 + r];

    #pragma unroll
    for (int nt = 0; nt < 4; ++nt) {
        const int colq = q0 + wc * 64 + nt * 16 + l15;
        const float sq_q = sqn[cb + colq];
        #pragma unroll
        for (int mt = 0; mt < 4; ++mt) {
            #pragma unroll
            for (int r = 0; r < 4; ++r) {
                const int rowp = p0 + wr * 64 + mt * 16 + quad * 4 + r;
                __builtin_nontemporal_store((sqp[mt][r] + sq_q) - 2.f * acc[mt][nt][r],
                                            &dist[(cb + rowp) * NP + colq]);
            }
        }
    }
}

// ---------------------------------------------------------------------------
// Kernel 3: top-8 smallest per point (ties -> lowest index). One wave/point.
// ---------------------------------------------------------------------------
__global__ __launch_bounds__(256)
void k_select(const float* __restrict__ dist, int* __restrict__ nidx)
{
    const int wv = threadIdx.x >> 6, lane = threadIdx.x & 63;
    const int xcd = blockIdx.x & 7, rest = blockIdx.x >> 3;   // rest 0..1023
    const int cell = xcd * 8 + (rest >> 7);                   // 0..63
    const int p = cell * NP + (rest & 127) * 4 + wv;          // global point
    const float* row = dist + (size_t)p * NP;

    float d[8];
    {
        const float4 va = *(const float4*)(row + lane * 8);
        const float4 vb = *(const float4*)(row + lane * 8 + 4);
        d[0] = va.x; d[1] = va.y; d[2] = va.z; d[3] = va.w;
        d[4] = vb.x; d[5] = vb.y; d[6] = vb.z; d[7] = vb.w;
    }

    for (int r = 0; r < KNN; ++r) {
        float bd = d[0]; int bi = 0;
        #pragma unroll
        for (int i = 1; i < 8; ++i)
            if (d[i] < bd) { bd = d[i]; bi = i; }   // strict < keeps lowest i on tie
        int bq = lane * 8 + bi;
        #pragma unroll
        for (int s = 32; s > 0; s >>= 1) {
            const float od = __shfl_down(bd, s, 64);
            const int oq = __shfl_down(bq, s, 64);
            if (od < bd || (od == bd && oq < bq)) { bd = od; bq = oq; }
        }
        const int win = __shfl(bq, 0, 64);
        if (lane == 0) nidx[(size_t)p * KNN + r] = ((p >> 9) << 9) | win;
        if ((win >> 3) == lane) {
            const int wi = win & 7;
            #pragma unroll
            for (int i = 0; i < 8; ++i) if (wi == i) d[i] = 3.4e38f;
        }
    }
}

// ---------------------------------------------------------------------------
// Kernel 4: u = x@Wd+gb1, v = x@Wb via 2-pass split MFMA (A hi+lo, B hi only).
// 64 points/block; A staged per k-step through double-buffered LDS via
// global_load_lds width-16 with XOR chunk-swizzle (both sides, rule 21).
// ---------------------------------------------------------------------------
__global__ __launch_bounds__(256)
void k_uv(const ushort* __restrict__ ehi, const ushort* __restrict__ elo,
          const ushort* __restrict__ Wdh, const ushort* __restrict__ Wbh,
          const float* __restrict__ gb1,
          float* __restrict__ u, float* __restrict__ v)
{
    __shared__ __align__(16) ushort lds[2][2][2048];   // [dbuf][hi/lo][slot*8], 16 KB

    const int t = threadIdx.x, w = t >> 6, lane = t & 63;
    const int l15 = lane & 15, quad = lane >> 4;
    const int isV = blockIdx.x >> 9;           // 1024 blocks total
    const int m0 = (blockIdx.x & 511) * 64;
    const ushort* Wh = isV ? Wbh : Wdh;
    float* out = isV ? v : u;
    const int mh = w & 1, ch = w >> 1;

    // staging: 256 slots of 16B per array (64 rows x 4 chunks); wave w covers
    // slots [w*64, w*64+64). slot p holds (row = p>>2, chunk = (p&3)^((row>>1)&3)).
    const int sp = w * 64 + lane;
    const int srow = sp >> 2;
    const int scol = ((sp & 3) ^ ((srow >> 1) & 3)) * 8;   // ushort offset

    #define STAGE_UV(S, D)                                                       \
    {                                                                            \
        const size_t ga_ = (size_t)(m0 + srow) * 256 + (S) * 32 + scol;          \
        gload16(ehi + ga_, &lds[D][0][sp * 8]);                                  \
        gload16(elo + ga_, &lds[D][1][sp * 8]);                                  \
    }

    // read-side slots for this wave's two A-row fragments
    const int r0 = mh * 32 + l15, r1 = r0 + 16;
    const int slot0 = 4 * r0 + (quad ^ ((r0 >> 1) & 3));
    const int slot1 = 4 * r1 + (quad ^ ((r1 >> 1) & 3));

    f32x4 acc[2][8];
    #pragma unroll
    for (int mt = 0; mt < 2; ++mt)
        #pragma unroll
        for (int nt = 0; nt < 8; ++nt) acc[mt][nt] = (f32x4){0.f, 0.f, 0.f, 0.f};

    STAGE_UV(0, 0);
    __syncthreads();

    for (int s = 0; s < 8; ++s) {
        const int cur = s & 1;
        if (s < 7) STAGE_UV(s + 1, cur ^ 1);   // prefetch next k-slice

        const s16x8 ah0 = *(const s16x8*)&lds[cur][0][slot0 * 8];
        const s16x8 al0 = *(const s16x8*)&lds[cur][1][slot0 * 8];
        const s16x8 ah1 = *(const s16x8*)&lds[cur][0][slot1 * 8];
        const s16x8 al1 = *(const s16x8*)&lds[cur][1][slot1 * 8];
        #pragma unroll
        for (int nt = 0; nt < 8; ++nt) {
            const int n = ch * 128 + nt * 16 + l15;
            const size_t bo = (size_t)n * 256 + s * 32 + quad * 8;
            const s16x8 bh = *(const s16x8*)(Wh + bo);
            acc[0][nt] = __builtin_amdgcn_mfma_f32_16x16x32_bf16(ah0, bh, acc[0][nt], 0, 0, 0);
            acc[0][nt] = __builtin_amdgcn_mfma_f32_16x16x32_bf16(al0, bh, acc[0][nt], 0, 0, 0);
            acc[1][nt] = __builtin_amdgcn_mfma_f32_16x16x32_bf16(ah1, bh, acc[1][nt], 0, 0, 0);
            acc[1][nt] = __builtin_amdgcn_mfma_f32_16x16x32_bf16(al1, bh, acc[1][nt], 0, 0, 0);
        }
        __syncthreads();                        // drains vmcnt(0) -> buf ready
    }
    #undef STAGE_UV

    #pragma unroll
    for (int mt = 0; mt < 2; ++mt) {
        #pragma unroll
        for (int nt = 0; nt < 8; ++nt) {
            const int col = ch * 128 + nt * 16 + l15;
            const float bias = isV ? 0.f : gb1[col];
            #pragma unroll
            for (int r = 0; r < 4; ++r) {
                const int row = mh * 32 + mt * 16 + quad * 4 + r;
                out[(size_t)(m0 + row) * 256 + col] = acc[mt][nt][r] + bias;
            }
        }
    }
}

// ---------------------------------------------------------------------------
// Kernel 5: edge GEMM + max aggregation. Block = 8 points (64 edges), 4 waves.
// REWORKED to 32x32x16 MFMA: per step 16 mfma_32x32x16 instead of 32
// mfma_16x16x32 -- same FLOP, half the MFMA issue slots (the kernel is
// issue-port-bound: MFMA 30% + VALU 26% + DS/VMEM issue at ~2.3 waves/SIMD).
// Fragment layouts by analogy with the verified 16x16 family:
//   A: row = lane&31, k = (lane>>5)*8+e (K=16/chunk); B: col = lane&31, same k;
//   C: col = lane&31, row = (reg&3)+8*(reg>>2)+4*(lane>>5)  [m74/m101].
// Max-aggregation: max over 16 regs x 2 m-tiles, then shfl_xor 32 merges
// row-halves. Accumulation order changes (threshold-checked; k_gram which
// feeds top-k selection stays byte-identical).
// ---------------------------------------------------------------------------
__global__ __launch_bounds__(256)
void k_edge(const float* __restrict__ u, const float* __restrict__ v,
            const int* __restrict__ nidx,
            const ushort* __restrict__ g2h,
            const float* __restrict__ hb,
            float* __restrict__ part)
{
    __shared__ ushort Abuf[2][2][2304];   // [dbuf][hi/lo][edge*36+k], 18.4 KB
    __shared__ float ustage[2048];        // 8 pts x 256 k, 8 KB

    const int t = threadIdx.x, w = t >> 6, lane = t & 63;
    const int l31 = lane & 31, kh = lane >> 5;

    const int b = blockIdx.x;
    const int xcd = b & 7, rest = b >> 3;        // rest 0..511
    const int cell = xcd * 8 + (rest >> 6);      // 0..63
    const int pl0 = cell * NP + (rest & 63) * 8;

    // stage u rows once (coalesced, 8 floats per thread)
    {
        const int pt = t >> 5, kk = (t & 31) * 8;
        const float4 a = *(const float4*)(u + (size_t)(pl0 + pt) * 256 + kk);
        const float4 bq = *(const float4*)(u + (size_t)(pl0 + pt) * 256 + kk + 4);
        *(float4*)&ustage[pt * 256 + kk] = a;
        *(float4*)&ustage[pt * 256 + kk + 4] = bq;
    }

    const int se = t >> 2, kq = t & 3;
    const int upt = se >> 3;                     // point within block
    int svrow = nidx[(size_t)(pl0 + upt) * KNN + (se & 7)];
    if ((unsigned)svrow >= (unsigned)NTOT) svrow = 0;

    __syncthreads();                             // ustage visible (one-time)

    float4 vr[2][2];                             // 2-set v pipeline

    #define VLOAD(S)                                                             \
    {                                                                            \
        const int k0 = (S) * 32 + kq * 8;                                        \
        vr[(S) & 1][0] = *(const float4*)(v + (size_t)svrow * 256 + k0);         \
        vr[(S) & 1][1] = *(const float4*)(v + (size_t)svrow * 256 + k0 + 4);     \
    }
    #define SPLITW(S, BUF)                                                       \
    {                                                                            \
        const int k0u = (S) * 32 + kq * 8;                                       \
        const float4 ua = *(const float4*)&ustage[upt * 256 + k0u];              \
        const float4 ub = *(const float4*)&ustage[upt * 256 + k0u + 4];          \
        const float4 va = vr[(S) & 1][0], vb = vr[(S) & 1][1];                   \
        const float sv[8] = {                                                    \
            fmaxf(ua.x + va.x, 0.f), fmaxf(ua.y + va.y, 0.f),                    \
            fmaxf(ua.z + va.z, 0.f), fmaxf(ua.w + va.w, 0.f),                    \
            fmaxf(ub.x + vb.x, 0.f), fmaxf(ub.y + vb.y, 0.f),                    \
            fmaxf(ub.z + vb.z, 0.f), fmaxf(ub.w + vb.w, 0.f)};                   \
        union { uint2 q[2]; ushort us[8]; } th, tl;                              \
        _Pragma("unroll")                                                        \
        for (int j = 0; j < 8; ++j) { split2t(sv[j], th.us[j], tl.us[j]); }      \
        *(uint2*)&Abuf[BUF][0][se * 36 + kq * 8]     = th.q[0];                  \
        *(uint2*)&Abuf[BUF][0][se * 36 + kq * 8 + 4] = th.q[1];                  \
        *(uint2*)&Abuf[BUF][1][se * 36 + kq * 8]     = tl.q[0];                  \
        *(uint2*)&Abuf[BUF][1][se * 36 + kq * 8 + 4] = tl.q[1];                  \
    }

    // LDS-only barrier: completes all DS ops issued before it, leaves
    // global loads (vmcnt) in flight across the barrier.
    #define LDS_BARRIER()                                                        \
    {                                                                            \
        asm volatile("s_waitcnt lgkmcnt(0)" ::: "memory");                       \
        __builtin_amdgcn_s_barrier();                                            \
    }

    f32x16 acc[2][2];
    #pragma unroll
    for (int mt = 0; mt < 2; ++mt)
        #pragma unroll
        for (int nt = 0; nt < 2; ++nt) acc[mt][nt] = (f32x16)(0.0f);

    VLOAD(0); VLOAD(1);
    SPLITW(0, 0);

    #pragma unroll
    for (int s = 0; s < 8; ++s) {
        LDS_BARRIER();                        // buf[s&1] visible; buf[(s+1)&1] readers done
        if (s < 7) {
            SPLITW(s + 1, (s + 1) & 1);       // u from LDS, v register-resident
            if (s < 6) VLOAD(s + 2);          // stays in flight across barriers
        }

        // A fragments: [m-tile][k-chunk]; row = mt*32 + l31, k = kc*16 + kh*8
        s16x8 ah[2][2], al[2][2];
        #pragma unroll
        for (int mt = 0; mt < 2; ++mt) {
            #pragma unroll
            for (int kc = 0; kc < 2; ++kc) {
                const int ao = (mt * 32 + l31) * 36 + kc * 16 + kh * 8;
                union { uint2 q[2]; s16x8 v8; } Th, Tl;
                Th.q[0] = *(const uint2*)&Abuf[s & 1][0][ao];
                Th.q[1] = *(const uint2*)&Abuf[s & 1][0][ao + 4];
                Tl.q[0] = *(const uint2*)&Abuf[s & 1][1][ao];
                Tl.q[1] = *(const uint2*)&Abuf[s & 1][1][ao + 4];
                ah[mt][kc] = Th.v8; al[mt][kc] = Tl.v8;
            }
        }

        #pragma unroll
        for (int kc = 0; kc < 2; ++kc) {
            #pragma unroll
            for (int nt = 0; nt < 2; ++nt) {
                const int n = w * 64 + nt * 32 + l31;
                const s16x8 bh = *(const s16x8*)(g2h + (size_t)n * 256 + s * 32 + kc * 16 + kh * 8);
                acc[0][nt] = __builtin_amdgcn_mfma_f32_32x32x16_bf16(ah[0][kc], bh, acc[0][nt], 0, 0, 0);
                acc[1][nt] = __builtin_amdgcn_mfma_f32_32x32x16_bf16(ah[1][kc], bh, acc[1][nt], 0, 0, 0);
                acc[0][nt] = __builtin_amdgcn_mfma_f32_32x32x16_bf16(al[0][kc], bh, acc[0][nt], 0, 0, 0);
                acc[1][nt] = __builtin_amdgcn_mfma_f32_32x32x16_bf16(al[1][kc], bh, acc[1][nt], 0, 0, 0);
            }
        }
    }
    #undef VLOAD
    #undef SPLITW
    #undef LDS_BARRIER

    const int slot = rest & 63;
    #pragma unroll
    for (int nt = 0; nt < 2; ++nt) {
        float rm = -3.4e38f;
        #pragma unroll
        for (int r = 0; r < 16; ++r)
            rm = fmaxf(rm, fmaxf(acc[0][nt][r], acc[1][nt][r]));
        rm = fmaxf(rm, __shfl_xor(rm, 32, 64));   // merge row-halves (lane>>5)
        if (kh == 0) {
            const int col = w * 64 + nt * 32 + l31;
            part[((size_t)cell * 64 + slot) * 256 + col] = rm + hb[col];
        }
    }
}

// ---------------------------------------------------------------------------
// Kernel 6: reduce 64 partial maxes per cell, final MLP (f32), L2 normalize.
// ---------------------------------------------------------------------------
__global__ __launch_bounds__(256)
void k_final(const float* __restrict__ part,
             const float* __restrict__ lW1, const float* __restrict__ lb1,
             const float* __restrict__ lW2, const float* __restrict__ lb2,
             float* __restrict__ out)
{
    __shared__ float pooled[256];
    __shared__ float hid[256];
    __shared__ float red[4];

    const int b = blockIdx.x;
    const int t = threadIdx.x;

    float m = -3.4e38f;
    for (int s = 0; s < 64; ++s)
        m = fmaxf(m, part[((size_t)b * 64 + s) * 256 + t]);
    pooled[t] = m;
    __syncthreads();

    float h = lb1[t];
    for (int k = 0; k < 256; k += 4) {
        #pragma unroll
        for (int kk = 0; kk < 4; ++kk)
            h += pooled[k + kk] * lW1[(k + kk) * 256 + t];
    }
    hid[t] = fmaxf(h, 0.f);
    __syncthreads();

    float o = lb2[t];
    for (int k = 0; k < 256; k += 4) {
        #pragma unroll
        for (int kk = 0; kk < 4; ++kk)
            o += hid[k + kk] * lW2[(k + kk) * 256 + t];
    }

    float ss = o * o;
    #pragma unroll
    for (int s = 32; s > 0; s >>= 1) ss += __shfl_down(ss, s, 64);
    if ((t & 63) == 0) red[t >> 6] = ss;
    __syncthreads();
    const float tot = red[0] + red[1] + red[2] + red[3];
    const float rn = 1.f / fmaxf(sqrtf(tot), 1e-12f);
    out[b * 256 + t] = o * rn;
}

// ---------------------------------------------------------------------------
extern "C" void kernel_launch(void* const* d_in, const int* in_sizes, int n_in,
                              void* d_out, int out_size, void* d_ws, size_t ws_size,
                              hipStream_t stream)
{
    (void)n_in; (void)out_size; (void)ws_size;

    const float* class_table = (const float*)d_in[0];
    const float* cW1 = (const float*)d_in[1];
    const float* cb1 = (const float*)d_in[2];
    const float* cW2 = (const float*)d_in[3];
    const float* cb2 = (const float*)d_in[4];
    const float* pW1 = (const float*)d_in[5];
    const float* pb1 = (const float*)d_in[6];
    const float* pW2 = (const float*)d_in[7];
    const float* pb2 = (const float*)d_in[8];
    const float* mW  = (const float*)d_in[9];
    const float* mb  = (const float*)d_in[10];
    const float* gW1 = (const float*)d_in[11];
    const float* gb1 = (const float*)d_in[12];
    const float* g_gamma = (const float*)d_in[13];
    const float* g_beta  = (const float*)d_in[14];
    const float* gW2 = (const float*)d_in[15];
    const float* gb2 = (const float*)d_in[16];
    const float* lW1 = (const float*)d_in[17];
    const float* lb1 = (const float*)d_in[18];
    const float* lW2 = (const float*)d_in[19];
    const float* lb2 = (const float*)d_in[20];
    const float* positions = (const float*)d_in[21];
    const float* colors    = (const float*)d_in[22];
    const int*  cls        = (const int*)d_in[23];

    const int cstride = (in_sizes[23] == 2 * NTOT) ? 2 : 1;

    // workspace layout (bytes), total ~174 MB (ws_size ~268 MB).
    char* base = (char*)d_ws;
    float*   part   = (float*)(base + 0);               //   4,194,304
    ushort*  Wdh    = (ushort*)(base + 4194304);
    ushort*  Wdl    = (ushort*)(base + 4325376);
    ushort*  Wbh    = (ushort*)(base + 4456448);
    ushort*  Wbl    = (ushort*)(base + 4587520);
    ushort*  g2h    = (ushort*)(base + 4718592);
    ushort*  g2l    = (ushort*)(base + 4849664);
    float*   hb     = (float*)(base + 4980736);
    ushort*  cW2Th  = (ushort*)(base + 4981760);
    ushort*  cW2Tl  = (ushort*)(base + 5014528);
    ushort*  pW2Th  = (ushort*)(base + 5047296);
    ushort*  pW2Tl  = (ushort*)(base + 5080064);
    ushort*  WcTh   = (ushort*)(base + 5112832);
    ushort*  WcTl   = (ushort*)(base + 5145600);
    ushort*  WpTh   = (ushort*)(base + 5178368);
    ushort*  WpTl   = (ushort*)(base + 5211136);
    float*   classMn= (float*)(base + 5243904);
    float*   cbM    = (float*)(base + 5275648);
    float*   pbM    = (float*)(base + 5276672);
    int*     nidx   = (int*)(base + 5277696);           //   1,048,576
    float*   sqn    = (float*)(base + 6326272);         //     131,072
    ushort*  ehi    = (ushort*)(base + 6457344);        //  16,777,216
    ushort*  elo    = (ushort*)(base + 23234560);       //  16,777,216
    float*   dist   = (float*)(base + 40011776);        //  67,108,864
    float*   v      = (float*)(base + 107120640);       //  33,554,432
    float*   u      = (float*)(base + 140675072);       //  33,554,432
    float* out = (float*)d_out;

    k_cvt<<<897, 256, 0, stream>>>(gW1, gW2, g_gamma, g_beta, gb2, cW2, pW2,
                                   Wdh, Wdl, Wbh, Wbl, g2h, g2l, hb,
                                   cW2Th, cW2Tl, pW2Th, pW2Tl);
    k_fold<<<130, 256, 0, stream>>>(cW2, pW2, cb2, pb2, mW,
                                    WcTh, WcTl, WpTh, WpTl, cbM, pbM);
    k_cls<<<31, 256, 0, stream>>>(class_table, mW, classMn);

    k_embed<<<NTOT / 16, 256, 0, stream>>>(classMn, cW1, cb1, cb2, pW1, pb1, pb2,
                                           mb, cW2Th, cW2Tl, pW2Th, pW2Tl,
                                           WcTh, WcTl, WpTh, WpTl, cbM, pbM,
                                           positions, colors, cls, cstride,
                                           ehi, elo, sqn);
    k_gram<<<NB * 16, 256, 0, stream>>>(ehi, elo, sqn, dist);
    k_select<<<NTOT / 4, 256, 0, stream>>>(dist, nidx);
    k_uv<<<2 * NTOT / 64, 256, 0, stream>>>(ehi, elo, Wdh, Wbh, gb1, u, v);
    k_edge<<<NTOT / 8, 256, 0, stream>>>(u, v, nidx, g2h, hb, part);
    k_final<<<NB, 256, 0, stream>>>(part, lW1, lb1, lW2, lb2, out);
}

// Round 9
// 428.549 us; speedup vs baseline: 1.0686x; 1.0212x over previous
//
#include <hip/hip_runtime.h>

#define EDIM 256
#define KNN 8
#define NB 64
#define NP 512
#define NTOT (NB * NP)

typedef short s16x8 __attribute__((ext_vector_type(8)));
typedef float f32x4 __attribute__((ext_vector_type(4)));
typedef float f32x16 __attribute__((ext_vector_type(16)));
typedef unsigned short ushort;

__device__ __forceinline__ ushort f2b(float f) {
    unsigned u = __float_as_uint(f);
    u = (u + 0x7fffu + ((u >> 16) & 1u)) >> 16;   // RNE
    return (ushort)u;
}
__device__ __forceinline__ float b2f(ushort h) {
    return __uint_as_float(((unsigned)h) << 16);
}
__device__ __forceinline__ void split2(float x, ushort& h, ushort& l) {
    h = f2b(x);
    l = f2b(x - b2f(h));
}
// truncation split (edge hot path): pair error ~2^-16 relative, fewer VALU
__device__ __forceinline__ ushort f2bt(float f) {
    return (ushort)(__float_as_uint(f) >> 16);
}
__device__ __forceinline__ void split2t(float x, ushort& h, ushort& l) {
    h = f2bt(x);
    l = f2bt(x - b2f(h));
}

// async global->LDS, 16B per lane; lds dest is wave-uniform base + lane*16
__device__ __forceinline__ void gload16(const ushort* g, ushort* l) {
    __builtin_amdgcn_global_load_lds(
        (const __attribute__((address_space(1))) void*)g,
        (__attribute__((address_space(3))) void*)l, 16, 0, 0);
}

// ---------------------------------------------------------------------------
// Kernel 0a: weight prep -> transposed bf16 hi/lo pairs.
// ---------------------------------------------------------------------------
__global__ __launch_bounds__(256)
void k_cvt(const float* __restrict__ gW1, const float* __restrict__ gW2,
           const float* __restrict__ g_gamma, const float* __restrict__ g_beta,
           const float* __restrict__ gb2,
           const float* __restrict__ cW2, const float* __restrict__ pW2,
           ushort* __restrict__ Wdh, ushort* __restrict__ Wdl,
           ushort* __restrict__ Wbh, ushort* __restrict__ Wbl,
           ushort* __restrict__ g2h, ushort* __restrict__ g2l,
           float* __restrict__ hb,
           ushort* __restrict__ cW2Th, ushort* __restrict__ cW2Tl,
           ushort* __restrict__ pW2Th, ushort* __restrict__ pW2Tl)
{
    const int gid = blockIdx.x * 256 + threadIdx.x;
    ushort h, l;
    if (gid < 65536) {
        const int n = gid >> 8, k = gid & 255;
        split2(gW1[k * 256 + n] - gW1[(k + 256) * 256 + n], h, l);
        Wdh[gid] = h; Wdl[gid] = l;
    } else if (gid < 131072) {
        const int i = gid - 65536, n = i >> 8, k = i & 255;
        split2(gW1[(k + 256) * 256 + n], h, l);
        Wbh[i] = h; Wbl[i] = l;
    } else if (gid < 196608) {
        const int i = gid - 131072, n = i >> 8, k = i & 255;
        split2(g_gamma[k] * gW2[k * 256 + n], h, l);
        g2h[i] = h; g2l[i] = l;
    } else if (gid < 196864) {
        const int n = gid - 196608;
        float s = gb2[n];
        for (int k = 0; k < 256; ++k) s += g_beta[k] * gW2[k * 256 + n];
        hb[n] = s;
    } else if (gid < 213248) {
        const int i = gid - 196864, n = i >> 6, k = i & 63;
        split2(cW2[k * 256 + n], h, l);
        cW2Th[i] = h; cW2Tl[i] = l;
    } else if (gid < 229632) {
        const int i = gid - 213248, n = i >> 6, k = i & 63;
        split2(pW2[k * 256 + n], h, l);
        pW2Th[i] = h; pW2Tl[i] = l;
    }
}

// ---------------------------------------------------------------------------
// Kernel 0b: fold merge GEMM into the MLP weights (linearity).
// ---------------------------------------------------------------------------
__global__ __launch_bounds__(256)
void k_fold(const float* __restrict__ cW2, const float* __restrict__ pW2,
            const float* __restrict__ cb2, const float* __restrict__ pb2,
            const float* __restrict__ mW,
            ushort* __restrict__ WcTh, ushort* __restrict__ WcTl,
            ushort* __restrict__ WpTh, ushort* __restrict__ WpTl,
            float* __restrict__ cbM, float* __restrict__ pbM)
{
    const int gid = blockIdx.x * 256 + threadIdx.x;
    ushort h, l;
    if (gid < 16384) {
        const int j = gid >> 8, n = gid & 255;
        float s = 0.f;
        for (int k = 0; k < 256; ++k) s += cW2[j * 256 + k] * mW[(256 + k) * 256 + n];
        split2(s, h, l);
        WcTh[n * 64 + j] = h; WcTl[n * 64 + j] = l;
    } else if (gid < 32768) {
        const int i = gid - 16384, j = i >> 8, n = i & 255;
        float s = 0.f;
        for (int k = 0; k < 256; ++k) s += pW2[j * 256 + k] * mW[(512 + k) * 256 + n];
        split2(s, h, l);
        WpTh[n * 64 + j] = h; WpTl[n * 64 + j] = l;
    } else if (gid < 33024) {
        const int n = gid - 32768;
        float s = 0.f;
        for (int k = 0; k < 256; ++k) s += cb2[k] * mW[(256 + k) * 256 + n];
        cbM[n] = s;
    } else if (gid < 33280) {
        const int n = gid - 33024;
        float s = 0.f;
        for (int k = 0; k < 256; ++k) s += pb2[k] * mW[(512 + k) * 256 + n];
        pbM[n] = s;
    }
}

// ---------------------------------------------------------------------------
// Kernel 0c: classMn[c] = (class_table[c] / ||class_table[c]||) @ M0.
// ---------------------------------------------------------------------------
__global__ __launch_bounds__(256)
void k_cls(const float* __restrict__ ct, const float* __restrict__ mW,
           float* __restrict__ classMn)
{
    __shared__ float ctn[256];
    __shared__ float red[4];
    const int c = blockIdx.x, t = threadIdx.x;
    const float v = ct[c * 256 + t];
    float ss = v * v;
    #pragma unroll
    for (int s = 32; s > 0; s >>= 1) ss += __shfl_down(ss, s, 64);
    if ((t & 63) == 0) red[t >> 6] = ss;
    __syncthreads();
    const float tot = red[0] + red[1] + red[2] + red[3];
    const float r = 1.f / fmaxf(sqrtf(tot), 1e-12f);
    ctn[t] = v * r;
    __syncthreads();
    float s = 0.f;
    for (int k = 0; k < 256; ++k) s += ctn[k] * mW[k * 256 + t];
    classMn[c * 256 + t] = s;
}

// ---------------------------------------------------------------------------
// Kernel 1: embeddings via folded GEMMs. 16 obj/block, full problem (2048).
// ---------------------------------------------------------------------------
__global__ __launch_bounds__(256)
void k_embed(const float* __restrict__ classMn,
             const float* __restrict__ cW1, const float* __restrict__ cb1,
             const float* __restrict__ cb2,
             const float* __restrict__ pW1, const float* __restrict__ pb1,
             const float* __restrict__ pb2,
             const float* __restrict__ mb,
             const ushort* __restrict__ cW2Th, const ushort* __restrict__ cW2Tl,
             const ushort* __restrict__ pW2Th, const ushort* __restrict__ pW2Tl,
             const ushort* __restrict__ WcTh, const ushort* __restrict__ WcTl,
             const ushort* __restrict__ WpTh, const ushort* __restrict__ WpTl,
             const float* __restrict__ cbM, const float* __restrict__ pbM,
             const float* __restrict__ positions, const float* __restrict__ colors,
             const int* __restrict__ cls, const int cstride,
             ushort* __restrict__ ehi, ushort* __restrict__ elo,
             float* __restrict__ sqn)
{
    __shared__ __align__(16) ushort Ahc[16 * 72];
    __shared__ __align__(16) ushort Alc[16 * 72];
    __shared__ __align__(16) ushort Ahp[16 * 72];
    __shared__ __align__(16) ushort Alp[16 * 72];
    __shared__ float sqc[16][4], sqp_[16][4], sqe[16][4];

    const int t = threadIdx.x, w = t >> 6, lane = t & 63;
    const int l15 = lane & 15, quad = lane >> 4;
    const int obase = blockIdx.x * 16;

    {
        const int o = lane >> 4;
        const int objl = w * 4 + o;
        const int gobj = obase + objl;
        const float c0 = colors[gobj * 3], c1 = colors[gobj * 3 + 1], c2 = colors[gobj * 3 + 2];
        const float q0 = positions[gobj * 3], q1 = positions[gobj * 3 + 1], q2 = positions[gobj * 3 + 2];
        const int u0 = (lane & 15) * 4;
        #pragma unroll
        for (int uu = 0; uu < 4; ++uu) {
            const int u = u0 + uu;
            const float hc = fmaxf(cb1[u] + c0 * cW1[u] + c1 * cW1[64 + u] + c2 * cW1[128 + u], 0.f);
            const float hp = fmaxf(pb1[u] + q0 * pW1[u] + q1 * pW1[64 + u] + q2 * pW1[128 + u], 0.f);
            ushort h, l;
            split2(hc, h, l); Ahc[objl * 72 + u] = h; Alc[objl * 72 + u] = l;
            split2(hp, h, l); Ahp[objl * 72 + u] = h; Alp[objl * 72 + u] = l;
        }
    }
    __syncthreads();

    f32x4 aco[4], ape[4];
    #pragma unroll
    for (int nt = 0; nt < 4; ++nt) { aco[nt] = (f32x4){0.f,0.f,0.f,0.f}; ape[nt] = (f32x4){0.f,0.f,0.f,0.f}; }

    #pragma unroll
    for (int kt = 0; kt < 2; ++kt) {
        const int ao = l15 * 72 + kt * 32 + quad * 8;
        const s16x8 ahc = *(const s16x8*)&Ahc[ao];
        const s16x8 alc = *(const s16x8*)&Alc[ao];
        const s16x8 ahp = *(const s16x8*)&Ahp[ao];
        const s16x8 alp = *(const s16x8*)&Alp[ao];
        #pragma unroll
        for (int nt = 0; nt < 4; ++nt) {
            const int n = w * 64 + nt * 16 + l15;
            const size_t bo = (size_t)n * 64 + kt * 32 + quad * 8;
            const s16x8 cbh = *(const s16x8*)(cW2Th + bo);
            const s16x8 cbl = *(const s16x8*)(cW2Tl + bo);
            const s16x8 pbh = *(const s16x8*)(pW2Th + bo);
            const s16x8 pbl = *(const s16x8*)(pW2Tl + bo);
            aco[nt] = __builtin_amdgcn_mfma_f32_16x16x32_bf16(ahc, cbh, aco[nt], 0, 0, 0);
            ape[nt] = __builtin_amdgcn_mfma_f32_16x16x32_bf16(ahp, pbh, ape[nt], 0, 0, 0);
            aco[nt] = __builtin_amdgcn_mfma_f32_16x16x32_bf16(alc, cbh, aco[nt], 0, 0, 0);
            ape[nt] = __builtin_amdgcn_mfma_f32_16x16x32_bf16(alp, pbh, ape[nt], 0, 0, 0);
            aco[nt] = __builtin_amdgcn_mfma_f32_16x16x32_bf16(ahc, cbl, aco[nt], 0, 0, 0);
            ape[nt] = __builtin_amdgcn_mfma_f32_16x16x32_bf16(ahp, pbl, ape[nt], 0, 0, 0);
        }
    }

    float sc[4] = {0.f,0.f,0.f,0.f}, sp[4] = {0.f,0.f,0.f,0.f};
    #pragma unroll
    for (int nt = 0; nt < 4; ++nt) {
        const int col = w * 64 + nt * 16 + l15;
        const float cbv = cb2[col], pbv = pb2[col];
        #pragma unroll
        for (int r = 0; r < 4; ++r) {
            const float co = aco[nt][r] + cbv;
            const float pe = ape[nt][r] + pbv;
            sc[r] += co * co;
            sp[r] += pe * pe;
        }
    }
    #pragma unroll
    for (int s = 8; s > 0; s >>= 1) {
        #pragma unroll
        for (int r = 0; r < 4; ++r) {
            sc[r] += __shfl_xor(sc[r], s, 64);
            sp[r] += __shfl_xor(sp[r], s, 64);
        }
    }
    if (l15 == 0) {
        #pragma unroll
        for (int r = 0; r < 4; ++r) { sqc[quad * 4 + r][w] = sc[r]; sqp_[quad * 4 + r][w] = sp[r]; }
    }
    __syncthreads();

    float rco[4], rpe[4];
    #pragma unroll
    for (int r = 0; r < 4; ++r) {
        const int row = quad * 4 + r;
        rco[r] = 1.f / fmaxf(sqrtf(sqc[row][0] + sqc[row][1] + sqc[row][2] + sqc[row][3]), 1e-12f);
        rpe[r] = 1.f / fmaxf(sqrtf(sqp_[row][0] + sqp_[row][1] + sqp_[row][2] + sqp_[row][3]), 1e-12f);
    }

    f32x4 ac[4], ap[4];
    #pragma unroll
    for (int nt = 0; nt < 4; ++nt) { ac[nt] = (f32x4){0.f,0.f,0.f,0.f}; ap[nt] = (f32x4){0.f,0.f,0.f,0.f}; }

    #pragma unroll
    for (int kt = 0; kt < 2; ++kt) {
        const int ao = l15 * 72 + kt * 32 + quad * 8;
        const s16x8 ahc = *(const s16x8*)&Ahc[ao];
        const s16x8 alc = *(const s16x8*)&Alc[ao];
        const s16x8 ahp = *(const s16x8*)&Ahp[ao];
        const s16x8 alp = *(const s16x8*)&Alp[ao];
        #pragma unroll
        for (int nt = 0; nt < 4; ++nt) {
            const int n = w * 64 + nt * 16 + l15;
            const size_t bo = (size_t)n * 64 + kt * 32 + quad * 8;
            const s16x8 cbh = *(const s16x8*)(WcTh + bo);
            const s16x8 cbl = *(const s16x8*)(WcTl + bo);
            const s16x8 pbh = *(const s16x8*)(WpTh + bo);
            const s16x8 pbl = *(const s16x8*)(WpTl + bo);
            ac[nt] = __builtin_amdgcn_mfma_f32_16x16x32_bf16(ahc, cbh, ac[nt], 0, 0, 0);
            ap[nt] = __builtin_amdgcn_mfma_f32_16x16x32_bf16(ahp, pbh, ap[nt], 0, 0, 0);
            ac[nt] = __builtin_amdgcn_mfma_f32_16x16x32_bf16(alc, cbh, ac[nt], 0, 0, 0);
            ap[nt] = __builtin_amdgcn_mfma_f32_16x16x32_bf16(alp, pbh, ap[nt], 0, 0, 0);
            ac[nt] = __builtin_amdgcn_mfma_f32_16x16x32_bf16(ahc, cbl, ac[nt], 0, 0, 0);
            ap[nt] = __builtin_amdgcn_mfma_f32_16x16x32_bf16(ahp, pbl, ap[nt], 0, 0, 0);
        }
    }

    int ci[4];
    #pragma unroll
    for (int r = 0; r < 4; ++r) {
        const int gobj = obase + quad * 4 + r;
        int c = cls[(size_t)gobj * cstride];
        if ((unsigned)c > 30u) c = 0;
        ci[r] = c;
    }

    float rp[4] = {0.f,0.f,0.f,0.f};
    #pragma unroll
    for (int nt = 0; nt < 4; ++nt) {
        const int col = w * 64 + nt * 16 + l15;
        const float mbv = mb[col], cbMv = cbM[col], pbMv = pbM[col];
        #pragma unroll
        for (int r = 0; r < 4; ++r) {
            const int row = quad * 4 + r;
            const float e = classMn[ci[r] * 256 + col]
                          + rco[r] * (ac[nt][r] + cbMv)
                          + rpe[r] * (ap[nt][r] + pbMv) + mbv;
            ushort h, l;
            split2(e, h, l);
            ehi[(size_t)(obase + row) * 256 + col] = h;
            elo[(size_t)(obase + row) * 256 + col] = l;
            rp[r] += e * e;
        }
    }
    #pragma unroll
    for (int s = 8; s > 0; s >>= 1) {
        #pragma unroll
        for (int r = 0; r < 4; ++r) rp[r] += __shfl_xor(rp[r], s, 64);
    }
    if (l15 == 0) {
        #pragma unroll
        for (int r = 0; r < 4; ++r) sqe[quad * 4 + r][w] = rp[r];
    }
    __syncthreads();
    if (t < 16) sqn[obase + t] = sqe[t][0] + sqe[t][1] + sqe[t][2] + sqe[t][3];
}

// ---------------------------------------------------------------------------
// Kernel 2: Gram/distance. m97-style 128x128 tile per block, double-buffered
// LDS staged via global_load_lds (width 16), BK=32/step, XOR chunk-swizzle
// on both sides (rule 21). Diagonal tiles stage A only. Nontemporal dist.
// BYTE-IDENTICAL to the passing R8 version (protects kNN bit-stability).
// ---------------------------------------------------------------------------
__global__ __launch_bounds__(256)
void k_gram(const ushort* __restrict__ ehi, const ushort* __restrict__ elo,
            const float* __restrict__ sqn, float* __restrict__ dist)
{
    // [dbuf][Ah,Al,Bh,Bl][128 rows * 32 k], 64 KB total
    __shared__ __align__(16) ushort lds[2][4][4096];

    const int t = threadIdx.x, w = t >> 6, lane = t & 63;
    const int l15 = lane & 15, quad = lane >> 4;
    const int b = blockIdx.x;
    const int xcd = b & 7, rest = b >> 3;        // rest 0..127
    const int cell = xcd * 8 + (rest >> 4);      // 0..63
    const int tile = rest & 15;
    const int p0 = (tile >> 2) * 128, q0 = (tile & 3) * 128;
    const size_t cb = (size_t)cell * NP;
    const int diag = (p0 == q0);
    const int wr = w >> 1, wc = w & 1;           // 2x2 wave grid, 64x64 each

    int srow[2], scol[2];
    #pragma unroll
    for (int i = 0; i < 2; ++i) {
        const int p = (w * 2 + i) * 64 + lane;
        const int row = p >> 2;
        srow[i] = row;
        scol[i] = ((p & 3) ^ ((row >> 1) & 3)) * 8;   // ushort offset of 16B chunk
    }

    #define STAGE(KT, D)                                                         \
    {                                                                            \
        const int kb_ = (KT) * 32;                                               \
        _Pragma("unroll")                                                        \
        for (int i = 0; i < 2; ++i) {                                            \
            const int ls_ = (w * 2 + i) * 512;   /* slot*8 ushorts */            \
            const size_t ga_ = (cb + p0 + srow[i]) * 256 + kb_ + scol[i];        \
            gload16(ehi + ga_, &lds[D][0][ls_]);                                 \
            gload16(elo + ga_, &lds[D][1][ls_]);                                 \
            if (!diag) {                                                         \
                const size_t gq_ = (cb + q0 + srow[i]) * 256 + kb_ + scol[i];    \
                gload16(ehi + gq_, &lds[D][2][ls_]);                             \
                gload16(elo + gq_, &lds[D][3][ls_]);                             \
            }                                                                    \
        }                                                                        \
    }

    f32x4 acc[4][4];
    #pragma unroll
    for (int mt = 0; mt < 4; ++mt)
        #pragma unroll
        for (int nt = 0; nt < 4; ++nt) acc[mt][nt] = (f32x4){0.f, 0.f, 0.f, 0.f};

    const int bB = diag ? 0 : 2;

    STAGE(0, 0);
    __syncthreads();

    for (int kt = 0; kt < 8; ++kt) {
        const int cur = kt & 1;
        if (kt < 7) STAGE(kt + 1, cur ^ 1);      // prefetch next k-slice

        s16x8 ah[4], al[4];
        #pragma unroll
        for (int mt = 0; mt < 4; ++mt) {
            const int r = wr * 64 + mt * 16 + l15;
            const int slot = 4 * r + (quad ^ ((r >> 1) & 3));
            ah[mt] = *(const s16x8*)&lds[cur][0][slot * 8];
            al[mt] = *(const s16x8*)&lds[cur][1][slot * 8];
        }
        #pragma unroll
        for (int nt = 0; nt < 4; ++nt) {
            const int rq = wc * 64 + nt * 16 + l15;
            const int slot = 4 * rq + (quad ^ ((rq >> 1) & 3));
            const s16x8 bh = *(const s16x8*)&lds[cur][bB][slot * 8];
            const s16x8 bl = *(const s16x8*)&lds[cur][bB + 1][slot * 8];
            #pragma unroll
            for (int mt = 0; mt < 4; ++mt) {
                acc[mt][nt] = __builtin_amdgcn_mfma_f32_16x16x32_bf16(ah[mt], bh, acc[mt][nt], 0, 0, 0);
                acc[mt][nt] = __builtin_amdgcn_mfma_f32_16x16x32_bf16(al[mt], bh, acc[mt][nt], 0, 0, 0);
                acc[mt][nt] = __builtin_amdgcn_mfma_f32_16x16x32_bf16(ah[mt], bl, acc[mt][nt], 0, 0, 0);
            }
        }
        __syncthreads();                          // drains vmcnt(0) -> buf ready
    }
    #undef STAGE

    float sqp[4][4];
    #pragma unroll
    for (int mt = 0; mt < 4; ++mt)
        #pragma unroll
        for (int r = 0; r < 4; ++r)
            sqp[mt][r] = sqn[cb + p0 + wr * 64 + mt * 16 + quad * 4 + r];

    #pragma unroll
    for (int nt = 0; nt < 4; ++nt) {
        const int colq = q0 + wc * 64 + nt * 16 + l15;
        const float sq_q = sqn[cb + colq];
        #pragma unroll
        for (int mt = 0; mt < 4; ++mt) {
            #pragma unroll
            for (int r = 0; r < 4; ++r) {
                const int rowp = p0 + wr * 64 + mt * 16 + quad * 4 + r;
                __builtin_nontemporal_store((sqp[mt][r] + sq_q) - 2.f * acc[mt][nt][r],
                                            &dist[(cb + rowp) * NP + colq]);
            }
        }
    }
}

// ---------------------------------------------------------------------------
// Kernel 3: top-8 smallest per point (ties -> lowest index). One wave/point.
// ---------------------------------------------------------------------------
__global__ __launch_bounds__(256)
void k_select(const float* __restrict__ dist, int* __restrict__ nidx)
{
    const int wv = threadIdx.x >> 6, lane = threadIdx.x & 63;
    const int xcd = blockIdx.x & 7, rest = blockIdx.x >> 3;   // rest 0..1023
    const int cell = xcd * 8 + (rest >> 7);                   // 0..63
    const int p = cell * NP + (rest & 127) * 4 + wv;          // global point
    const float* row = dist + (size_t)p * NP;

    float d[8];
    {
        const float4 va = *(const float4*)(row + lane * 8);
        const float4 vb = *(const float4*)(row + lane * 8 + 4);
        d[0] = va.x; d[1] = va.y; d[2] = va.z; d[3] = va.w;
        d[4] = vb.x; d[5] = vb.y; d[6] = vb.z; d[7] = vb.w;
    }

    for (int r = 0; r < KNN; ++r) {
        float bd = d[0]; int bi = 0;
        #pragma unroll
        for (int i = 1; i < 8; ++i)
            if (d[i] < bd) { bd = d[i]; bi = i; }   // strict < keeps lowest i on tie
        int bq = lane * 8 + bi;
        #pragma unroll
        for (int s = 32; s > 0; s >>= 1) {
            const float od = __shfl_down(bd, s, 64);
            const int oq = __shfl_down(bq, s, 64);
            if (od < bd || (od == bd && oq < bq)) { bd = od; bq = oq; }
        }
        const int win = __shfl(bq, 0, 64);
        if (lane == 0) nidx[(size_t)p * KNN + r] = ((p >> 9) << 9) | win;
        if ((win >> 3) == lane) {
            const int wi = win & 7;
            #pragma unroll
            for (int i = 0; i < 8; ++i) if (wi == i) d[i] = 3.4e38f;
        }
    }
}

// ---------------------------------------------------------------------------
// Kernel 4: u = x@Wd+gb1, v = x@Wb via 2-pass split MFMA (A hi+lo, B hi only).
// 64 points/block; A staged per k-step through double-buffered LDS via
// global_load_lds width-16 with XOR chunk-swizzle (both sides, rule 21).
// ---------------------------------------------------------------------------
__global__ __launch_bounds__(256)
void k_uv(const ushort* __restrict__ ehi, const ushort* __restrict__ elo,
          const ushort* __restrict__ Wdh, const ushort* __restrict__ Wbh,
          const float* __restrict__ gb1,
          float* __restrict__ u, float* __restrict__ v)
{
    __shared__ __align__(16) ushort lds[2][2][2048];   // [dbuf][hi/lo][slot*8], 16 KB

    const int t = threadIdx.x, w = t >> 6, lane = t & 63;
    const int l15 = lane & 15, quad = lane >> 4;
    const int isV = blockIdx.x >> 9;           // 1024 blocks total
    const int m0 = (blockIdx.x & 511) * 64;
    const ushort* Wh = isV ? Wbh : Wdh;
    float* out = isV ? v : u;
    const int mh = w & 1, ch = w >> 1;

    // staging: 256 slots of 16B per array (64 rows x 4 chunks); wave w covers
    // slots [w*64, w*64+64). slot p holds (row = p>>2, chunk = (p&3)^((row>>1)&3)).
    const int sp = w * 64 + lane;
    const int srow = sp >> 2;
    const int scol = ((sp & 3) ^ ((srow >> 1) & 3)) * 8;   // ushort offset

    #define STAGE_UV(S, D)                                                       \
    {                                                                            \
        const size_t ga_ = (size_t)(m0 + srow) * 256 + (S) * 32 + scol;          \
        gload16(ehi + ga_, &lds[D][0][sp * 8]);                                  \
        gload16(elo + ga_, &lds[D][1][sp * 8]);                                  \
    }

    // read-side slots for this wave's two A-row fragments
    const int r0 = mh * 32 + l15, r1 = r0 + 16;
    const int slot0 = 4 * r0 + (quad ^ ((r0 >> 1) & 3));
    const int slot1 = 4 * r1 + (quad ^ ((r1 >> 1) & 3));

    f32x4 acc[2][8];
    #pragma unroll
    for (int mt = 0; mt < 2; ++mt)
        #pragma unroll
        for (int nt = 0; nt < 8; ++nt) acc[mt][nt] = (f32x4){0.f, 0.f, 0.f, 0.f};

    STAGE_UV(0, 0);
    __syncthreads();

    for (int s = 0; s < 8; ++s) {
        const int cur = s & 1;
        if (s < 7) STAGE_UV(s + 1, cur ^ 1);   // prefetch next k-slice

        const s16x8 ah0 = *(const s16x8*)&lds[cur][0][slot0 * 8];
        const s16x8 al0 = *(const s16x8*)&lds[cur][1][slot0 * 8];
        const s16x8 ah1 = *(const s16x8*)&lds[cur][0][slot1 * 8];
        const s16x8 al1 = *(const s16x8*)&lds[cur][1][slot1 * 8];
        #pragma unroll
        for (int nt = 0; nt < 8; ++nt) {
            const int n = ch * 128 + nt * 16 + l15;
            const size_t bo = (size_t)n * 256 + s * 32 + quad * 8;
            const s16x8 bh = *(const s16x8*)(Wh + bo);
            acc[0][nt] = __builtin_amdgcn_mfma_f32_16x16x32_bf16(ah0, bh, acc[0][nt], 0, 0, 0);
            acc[0][nt] = __builtin_amdgcn_mfma_f32_16x16x32_bf16(al0, bh, acc[0][nt], 0, 0, 0);
            acc[1][nt] = __builtin_amdgcn_mfma_f32_16x16x32_bf16(ah1, bh, acc[1][nt], 0, 0, 0);
            acc[1][nt] = __builtin_amdgcn_mfma_f32_16x16x32_bf16(al1, bh, acc[1][nt], 0, 0, 0);
        }
        __syncthreads();                        // drains vmcnt(0) -> buf ready
    }
    #undef STAGE_UV

    #pragma unroll
    for (int mt = 0; mt < 2; ++mt) {
        #pragma unroll
        for (int nt = 0; nt < 8; ++nt) {
            const int col = ch * 128 + nt * 16 + l15;
            const float bias = isV ? 0.f : gb1[col];
            #pragma unroll
            for (int r = 0; r < 4; ++r) {
                const int row = mh * 32 + mt * 16 + quad * 4 + r;
                out[(size_t)(m0 + row) * 256 + col] = acc[mt][nt][r] + bias;
            }
        }
    }
}

// ---------------------------------------------------------------------------
// Kernel 5: edge GEMM + max aggregation. RESTRUCTURED for occupancy:
// block = 512 threads (8 waves), still 8 points / 64 edges; wave w owns cols
// w*32..w*32+31 -> accumulator halves to 2 x f32x16 = 32 AGPR (was 64).
// Unified reg budget ~104/wave -> 4 waves/SIMD (was 3 at 136). Same 32x32x16
// MFMA order per acc (s -> kc -> hi,lo) -> bit-identical part. SPLITW
// rescaled: each thread handles 4 k (se=t>>3, kq=t&7). LDS-only inner
// barrier keeps v/B loads in flight.
// ---------------------------------------------------------------------------
__global__ __launch_bounds__(512)
void k_edge(const float* __restrict__ u, const float* __restrict__ v,
            const int* __restrict__ nidx,
            const ushort* __restrict__ g2h,
            const float* __restrict__ hb,
            float* __restrict__ part)
{
    __shared__ ushort Abuf[2][2][2304];   // [dbuf][hi/lo][edge*36+k], 18.4 KB
    __shared__ float ustage[2048];        // 8 pts x 256 k, 8 KB

    const int t = threadIdx.x, w = t >> 6, lane = t & 63;
    const int l31 = lane & 31, kh = lane >> 5;

    const int b = blockIdx.x;
    const int xcd = b & 7, rest = b >> 3;        // rest 0..511
    const int cell = xcd * 8 + (rest >> 6);      // 0..63
    const int pl0 = cell * NP + (rest & 63) * 8;

    // stage u rows once (coalesced, 4 floats per thread x 512 threads)
    {
        const int pt = t >> 6, kk = (t & 63) * 4;
        *(float4*)&ustage[pt * 256 + kk] = *(const float4*)(u + (size_t)(pl0 + pt) * 256 + kk);
    }

    const int se = t >> 3, kq = t & 7;           // edge 0..63, k-quad 0..7 (4 k each)
    const int upt = se >> 3;                     // point within block
    int svrow = nidx[(size_t)(pl0 + upt) * KNN + (se & 7)];
    if ((unsigned)svrow >= (unsigned)NTOT) svrow = 0;

    __syncthreads();                             // ustage visible (one-time)

    float4 vr[2];                                // 2-set v pipeline (4 floats/thread)

    #define VLOAD(S)                                                             \
    {                                                                            \
        const int k0 = (S) * 32 + kq * 4;                                        \
        vr[(S) & 1] = *(const float4*)(v + (size_t)svrow * 256 + k0);            \
    }
    #define SPLITW(S, BUF)                                                       \
    {                                                                            \
        const int k0u = (S) * 32 + kq * 4;                                       \
        const float4 ua = *(const float4*)&ustage[upt * 256 + k0u];              \
        const float4 va = vr[(S) & 1];                                           \
        const float sv[4] = {                                                    \
            fmaxf(ua.x + va.x, 0.f), fmaxf(ua.y + va.y, 0.f),                    \
            fmaxf(ua.z + va.z, 0.f), fmaxf(ua.w + va.w, 0.f)};                   \
        union { uint2 q; ushort us[4]; } th, tl;                                 \
        _Pragma("unroll")                                                        \
        for (int j = 0; j < 4; ++j) { split2t(sv[j], th.us[j], tl.us[j]); }      \
        *(uint2*)&Abuf[BUF][0][se * 36 + kq * 4] = th.q;                         \
        *(uint2*)&Abuf[BUF][1][se * 36 + kq * 4] = tl.q;                         \
    }

    // LDS-only barrier: completes all DS ops issued before it, leaves
    // global loads (vmcnt) in flight across the barrier.
    #define LDS_BARRIER()                                                        \
    {                                                                            \
        asm volatile("s_waitcnt lgkmcnt(0)" ::: "memory");                       \
        __builtin_amdgcn_s_barrier();                                            \
    }

    f32x16 acc[2];
    acc[0] = (f32x16)(0.0f);
    acc[1] = (f32x16)(0.0f);

    VLOAD(0); VLOAD(1);
    SPLITW(0, 0);

    #pragma unroll
    for (int s = 0; s < 8; ++s) {
        LDS_BARRIER();                        // buf[s&1] visible; buf[(s+1)&1] readers done
        if (s < 7) {
            SPLITW(s + 1, (s + 1) & 1);       // u from LDS, v register-resident
            if (s < 6) VLOAD(s + 2);          // stays in flight across barriers
        }

        // A fragments: [m-tile][k-chunk]; row = mt*32 + l31, k = kc*16 + kh*8
        s16x8 ah[2][2], al[2][2];
        #pragma unroll
        for (int mt = 0; mt < 2; ++mt) {
            #pragma unroll
            for (int kc = 0; kc < 2; ++kc) {
                const int ao = (mt * 32 + l31) * 36 + kc * 16 + kh * 8;
                union { uint2 q[2]; s16x8 v8; } Th, Tl;
                Th.q[0] = *(const uint2*)&Abuf[s & 1][0][ao];
                Th.q[1] = *(const uint2*)&Abuf[s & 1][0][ao + 4];
                Tl.q[0] = *(const uint2*)&Abuf[s & 1][1][ao];
                Tl.q[1] = *(const uint2*)&Abuf[s & 1][1][ao + 4];
                ah[mt][kc] = Th.v8; al[mt][kc] = Tl.v8;
            }
        }

        #pragma unroll
        for (int kc = 0; kc < 2; ++kc) {
            const int n = w * 32 + l31;
            const s16x8 bh = *(const s16x8*)(g2h + (size_t)n * 256 + s * 32 + kc * 16 + kh * 8);
            acc[0] = __builtin_amdgcn_mfma_f32_32x32x16_bf16(ah[0][kc], bh, acc[0], 0, 0, 0);
            acc[1] = __builtin_amdgcn_mfma_f32_32x32x16_bf16(ah[1][kc], bh, acc[1], 0, 0, 0);
            acc[0] = __builtin_amdgcn_mfma_f32_32x32x16_bf16(al[0][kc], bh, acc[0], 0, 0, 0);
            acc[1] = __builtin_amdgcn_mfma_f32_32x32x16_bf16(al[1][kc], bh, acc[1], 0, 0, 0);
        }
    }
    #undef VLOAD
    #undef SPLITW
    #undef LDS_BARRIER

    const int slot = rest & 63;
    {
        float rm = -3.4e38f;
        #pragma unroll
        for (int r = 0; r < 16; ++r)
            rm = fmaxf(rm, fmaxf(acc[0][r], acc[1][r]));
        rm = fmaxf(rm, __shfl_xor(rm, 32, 64));   // merge row-halves (lane>>5)
        if (kh == 0) {
            const int col = w * 32 + l31;
            part[((size_t)cell * 64 + slot) * 256 + col] = rm + hb[col];
        }
    }
}

// ---------------------------------------------------------------------------
// Kernel 6: reduce 64 partial maxes per cell, final MLP (f32), L2 normalize.
// ---------------------------------------------------------------------------
__global__ __launch_bounds__(256)
void k_final(const float* __restrict__ part,
             const float* __restrict__ lW1, const float* __restrict__ lb1,
             const float* __restrict__ lW2, const float* __restrict__ lb2,
             float* __restrict__ out)
{
    __shared__ float pooled[256];
    __shared__ float hid[256];
    __shared__ float red[4];

    const int b = blockIdx.x;
    const int t = threadIdx.x;

    float m = -3.4e38f;
    for (int s = 0; s < 64; ++s)
        m = fmaxf(m, part[((size_t)b * 64 + s) * 256 + t]);
    pooled[t] = m;
    __syncthreads();

    float h = lb1[t];
    for (int k = 0; k < 256; k += 4) {
        #pragma unroll
        for (int kk = 0; kk < 4; ++kk)
            h += pooled[k + kk] * lW1[(k + kk) * 256 + t];
    }
    hid[t] = fmaxf(h, 0.f);
    __syncthreads();

    float o = lb2[t];
    for (int k = 0; k < 256; k += 4) {
        #pragma unroll
        for (int kk = 0; kk < 4; ++kk)
            o += hid[k + kk] * lW2[(k + kk) * 256 + t];
    }

    float ss = o * o;
    #pragma unroll
    for (int s = 32; s > 0; s >>= 1) ss += __shfl_down(ss, s, 64);
    if ((t & 63) == 0) red[t >> 6] = ss;
    __syncthreads();
    const float tot = red[0] + red[1] + red[2] + red[3];
    const float rn = 1.f / fmaxf(sqrtf(tot), 1e-12f);
    out[b * 256 + t] = o * rn;
}

// ---------------------------------------------------------------------------
extern "C" void kernel_launch(void* const* d_in, const int* in_sizes, int n_in,
                              void* d_out, int out_size, void* d_ws, size_t ws_size,
                              hipStream_t stream)
{
    (void)n_in; (void)out_size; (void)ws_size;

    const float* class_table = (const float*)d_in[0];
    const float* cW1 = (const float*)d_in[1];
    const float* cb1 = (const float*)d_in[2];
    const float* cW2 = (const float*)d_in[3];
    const float* cb2 = (const float*)d_in[4];
    const float* pW1 = (const float*)d_in[5];
    const float* pb1 = (const float*)d_in[6];
    const float* pW2 = (const float*)d_in[7];
    const float* pb2 = (const float*)d_in[8];
    const float* mW  = (const float*)d_in[9];
    const float* mb  = (const float*)d_in[10];
    const float* gW1 = (const float*)d_in[11];
    const float* gb1 = (const float*)d_in[12];
    const float* g_gamma = (const float*)d_in[13];
    const float* g_beta  = (const float*)d_in[14];
    const float* gW2 = (const float*)d_in[15];
    const float* gb2 = (const float*)d_in[16];
    const float* lW1 = (const float*)d_in[17];
    const float* lb1 = (const float*)d_in[18];
    const float* lW2 = (const float*)d_in[19];
    const float* lb2 = (const float*)d_in[20];
    const float* positions = (const float*)d_in[21];
    const float* colors    = (const float*)d_in[22];
    const int*  cls        = (const int*)d_in[23];

    const int cstride = (in_sizes[23] == 2 * NTOT) ? 2 : 1;

    // workspace layout (bytes), total ~174 MB (ws_size ~268 MB).
    char* base = (char*)d_ws;
    float*   part   = (float*)(base + 0);               //   4,194,304
    ushort*  Wdh    = (ushort*)(base + 4194304);
    ushort*  Wdl    = (ushort*)(base + 4325376);
    ushort*  Wbh    = (ushort*)(base + 4456448);
    ushort*  Wbl    = (ushort*)(base + 4587520);
    ushort*  g2h    = (ushort*)(base + 4718592);
    ushort*  g2l    = (ushort*)(base + 4849664);
    float*   hb     = (float*)(base + 4980736);
    ushort*  cW2Th  = (ushort*)(base + 4981760);
    ushort*  cW2Tl  = (ushort*)(base + 5014528);
    ushort*  pW2Th  = (ushort*)(base + 5047296);
    ushort*  pW2Tl  = (ushort*)(base + 5080064);
    ushort*  WcTh   = (ushort*)(base + 5112832);
    ushort*  WcTl   = (ushort*)(base + 5145600);
    ushort*  WpTh   = (ushort*)(base + 5178368);
    ushort*  WpTl   = (ushort*)(base + 5211136);
    float*   classMn= (float*)(base + 5243904);
    float*   cbM    = (float*)(base + 5275648);
    float*   pbM    = (float*)(base + 5276672);
    int*     nidx   = (int*)(base + 5277696);           //   1,048,576
    float*   sqn    = (float*)(base + 6326272);         //     131,072
    ushort*  ehi    = (ushort*)(base + 6457344);        //  16,777,216
    ushort*  elo    = (ushort*)(base + 23234560);       //  16,777,216
    float*   dist   = (float*)(base + 40011776);        //  67,108,864
    float*   v      = (float*)(base + 107120640);       //  33,554,432
    float*   u      = (float*)(base + 140675072);       //  33,554,432
    float* out = (float*)d_out;

    k_cvt<<<897, 256, 0, stream>>>(gW1, gW2, g_gamma, g_beta, gb2, cW2, pW2,
                                   Wdh, Wdl, Wbh, Wbl, g2h, g2l, hb,
                                   cW2Th, cW2Tl, pW2Th, pW2Tl);
    k_fold<<<130, 256, 0, stream>>>(cW2, pW2, cb2, pb2, mW,
                                    WcTh, WcTl, WpTh, WpTl, cbM, pbM);
    k_cls<<<31, 256, 0, stream>>>(class_table, mW, classMn);

    k_embed<<<NTOT / 16, 256, 0, stream>>>(classMn, cW1, cb1, cb2, pW1, pb1, pb2,
                                           mb, cW2Th, cW2Tl, pW2Th, pW2Tl,
                                           WcTh, WcTl, WpTh, WpTl, cbM, pbM,
                                           positions, colors, cls, cstride,
                                           ehi, elo, sqn);
    k_gram<<<NB * 16, 256, 0, stream>>>(ehi, elo, sqn, dist);
    k_select<<<NTOT / 4, 256, 0, stream>>>(dist, nidx);
    k_uv<<<2 * NTOT / 64, 256, 0, stream>>>(ehi, elo, Wdh, Wbh, gb1, u, v);
    k_edge<<<NTOT / 8, 512, 0, stream>>>(u, v, nidx, g2h, hb, part);
    k_final<<<NB, 256, 0, stream>>>(part, lW1, lb1, lW2, lb2, out);
}

// Round 10
// 423.518 us; speedup vs baseline: 1.0813x; 1.0119x over previous
//
#include <hip/hip_runtime.h>

#define EDIM 256
#define KNN 8
#define NB 64
#define NP 512
#define NTOT (NB * NP)

typedef short s16x8 __attribute__((ext_vector_type(8)));
typedef float f32x4 __attribute__((ext_vector_type(4)));
typedef float f32x16 __attribute__((ext_vector_type(16)));
typedef unsigned short ushort;

__device__ __forceinline__ ushort f2b(float f) {
    unsigned u = __float_as_uint(f);
    u = (u + 0x7fffu + ((u >> 16) & 1u)) >> 16;   // RNE
    return (ushort)u;
}
__device__ __forceinline__ float b2f(ushort h) {
    return __uint_as_float(((unsigned)h) << 16);
}
__device__ __forceinline__ void split2(float x, ushort& h, ushort& l) {
    h = f2b(x);
    l = f2b(x - b2f(h));
}
// truncation split: pair error ~2^-16 relative, fewer VALU
__device__ __forceinline__ ushort f2bt(float f) {
    return (ushort)(__float_as_uint(f) >> 16);
}
__device__ __forceinline__ void split2t(float x, ushort& h, ushort& l) {
    h = f2bt(x);
    l = f2bt(x - b2f(h));
}

// async global->LDS, 16B per lane; lds dest is wave-uniform base + lane*16
__device__ __forceinline__ void gload16(const ushort* g, ushort* l) {
    __builtin_amdgcn_global_load_lds(
        (const __attribute__((address_space(1))) void*)g,
        (__attribute__((address_space(3))) void*)l, 16, 0, 0);
}

// ---------------------------------------------------------------------------
// Kernel 0a: weight prep -> transposed bf16 hi/lo pairs.
// ---------------------------------------------------------------------------
__global__ __launch_bounds__(256)
void k_cvt(const float* __restrict__ gW1, const float* __restrict__ gW2,
           const float* __restrict__ g_gamma, const float* __restrict__ g_beta,
           const float* __restrict__ gb2,
           const float* __restrict__ cW2, const float* __restrict__ pW2,
           ushort* __restrict__ Wdh, ushort* __restrict__ Wdl,
           ushort* __restrict__ Wbh, ushort* __restrict__ Wbl,
           ushort* __restrict__ g2h, ushort* __restrict__ g2l,
           float* __restrict__ hb,
           ushort* __restrict__ cW2Th, ushort* __restrict__ cW2Tl,
           ushort* __restrict__ pW2Th, ushort* __restrict__ pW2Tl)
{
    const int gid = blockIdx.x * 256 + threadIdx.x;
    ushort h, l;
    if (gid < 65536) {
        const int n = gid >> 8, k = gid & 255;
        split2(gW1[k * 256 + n] - gW1[(k + 256) * 256 + n], h, l);
        Wdh[gid] = h; Wdl[gid] = l;
    } else if (gid < 131072) {
        const int i = gid - 65536, n = i >> 8, k = i & 255;
        split2(gW1[(k + 256) * 256 + n], h, l);
        Wbh[i] = h; Wbl[i] = l;
    } else if (gid < 196608) {
        const int i = gid - 131072, n = i >> 8, k = i & 255;
        split2(g_gamma[k] * gW2[k * 256 + n], h, l);
        g2h[i] = h; g2l[i] = l;
    } else if (gid < 196864) {
        const int n = gid - 196608;
        float s = gb2[n];
        for (int k = 0; k < 256; ++k) s += g_beta[k] * gW2[k * 256 + n];
        hb[n] = s;
    } else if (gid < 213248) {
        const int i = gid - 196864, n = i >> 6, k = i & 63;
        split2(cW2[k * 256 + n], h, l);
        cW2Th[i] = h; cW2Tl[i] = l;
    } else if (gid < 229632) {
        const int i = gid - 213248, n = i >> 6, k = i & 63;
        split2(pW2[k * 256 + n], h, l);
        pW2Th[i] = h; pW2Tl[i] = l;
    }
}

// ---------------------------------------------------------------------------
// Kernel 0b: fold merge GEMM into the MLP weights (linearity).
// ---------------------------------------------------------------------------
__global__ __launch_bounds__(256)
void k_fold(const float* __restrict__ cW2, const float* __restrict__ pW2,
            const float* __restrict__ cb2, const float* __restrict__ pb2,
            const float* __restrict__ mW,
            ushort* __restrict__ WcTh, ushort* __restrict__ WcTl,
            ushort* __restrict__ WpTh, ushort* __restrict__ WpTl,
            float* __restrict__ cbM, float* __restrict__ pbM)
{
    const int gid = blockIdx.x * 256 + threadIdx.x;
    ushort h, l;
    if (gid < 16384) {
        const int j = gid >> 8, n = gid & 255;
        float s = 0.f;
        for (int k = 0; k < 256; ++k) s += cW2[j * 256 + k] * mW[(256 + k) * 256 + n];
        split2(s, h, l);
        WcTh[n * 64 + j] = h; WcTl[n * 64 + j] = l;
    } else if (gid < 32768) {
        const int i = gid - 16384, j = i >> 8, n = i & 255;
        float s = 0.f;
        for (int k = 0; k < 256; ++k) s += pW2[j * 256 + k] * mW[(512 + k) * 256 + n];
        split2(s, h, l);
        WpTh[n * 64 + j] = h; WpTl[n * 64 + j] = l;
    } else if (gid < 33024) {
        const int n = gid - 32768;
        float s = 0.f;
        for (int k = 0; k < 256; ++k) s += cb2[k] * mW[(256 + k) * 256 + n];
        cbM[n] = s;
    } else if (gid < 33280) {
        const int n = gid - 33024;
        float s = 0.f;
        for (int k = 0; k < 256; ++k) s += pb2[k] * mW[(512 + k) * 256 + n];
        pbM[n] = s;
    }
}

// ---------------------------------------------------------------------------
// Kernel 0c: classMn[c] = (class_table[c] / ||class_table[c]||) @ M0.
// ---------------------------------------------------------------------------
__global__ __launch_bounds__(256)
void k_cls(const float* __restrict__ ct, const float* __restrict__ mW,
           float* __restrict__ classMn)
{
    __shared__ float ctn[256];
    __shared__ float red[4];
    const int c = blockIdx.x, t = threadIdx.x;
    const float v = ct[c * 256 + t];
    float ss = v * v;
    #pragma unroll
    for (int s = 32; s > 0; s >>= 1) ss += __shfl_down(ss, s, 64);
    if ((t & 63) == 0) red[t >> 6] = ss;
    __syncthreads();
    const float tot = red[0] + red[1] + red[2] + red[3];
    const float r = 1.f / fmaxf(sqrtf(tot), 1e-12f);
    ctn[t] = v * r;
    __syncthreads();
    float s = 0.f;
    for (int k = 0; k < 256; ++k) s += ctn[k] * mW[k * 256 + t];
    classMn[c * 256 + t] = s;
}

// ---------------------------------------------------------------------------
// Kernel 1: embeddings via folded GEMMs. 16 obj/block, full problem (2048).
// ---------------------------------------------------------------------------
__global__ __launch_bounds__(256)
void k_embed(const float* __restrict__ classMn,
             const float* __restrict__ cW1, const float* __restrict__ cb1,
             const float* __restrict__ cb2,
             const float* __restrict__ pW1, const float* __restrict__ pb1,
             const float* __restrict__ pb2,
             const float* __restrict__ mb,
             const ushort* __restrict__ cW2Th, const ushort* __restrict__ cW2Tl,
             const ushort* __restrict__ pW2Th, const ushort* __restrict__ pW2Tl,
             const ushort* __restrict__ WcTh, const ushort* __restrict__ WcTl,
             const ushort* __restrict__ WpTh, const ushort* __restrict__ WpTl,
             const float* __restrict__ cbM, const float* __restrict__ pbM,
             const float* __restrict__ positions, const float* __restrict__ colors,
             const int* __restrict__ cls, const int cstride,
             ushort* __restrict__ ehi, ushort* __restrict__ elo,
             float* __restrict__ sqn)
{
    __shared__ __align__(16) ushort Ahc[16 * 72];
    __shared__ __align__(16) ushort Alc[16 * 72];
    __shared__ __align__(16) ushort Ahp[16 * 72];
    __shared__ __align__(16) ushort Alp[16 * 72];
    __shared__ float sqc[16][4], sqp_[16][4], sqe[16][4];

    const int t = threadIdx.x, w = t >> 6, lane = t & 63;
    const int l15 = lane & 15, quad = lane >> 4;
    const int obase = blockIdx.x * 16;

    {
        const int o = lane >> 4;
        const int objl = w * 4 + o;
        const int gobj = obase + objl;
        const float c0 = colors[gobj * 3], c1 = colors[gobj * 3 + 1], c2 = colors[gobj * 3 + 2];
        const float q0 = positions[gobj * 3], q1 = positions[gobj * 3 + 1], q2 = positions[gobj * 3 + 2];
        const int u0 = (lane & 15) * 4;
        #pragma unroll
        for (int uu = 0; uu < 4; ++uu) {
            const int u = u0 + uu;
            const float hc = fmaxf(cb1[u] + c0 * cW1[u] + c1 * cW1[64 + u] + c2 * cW1[128 + u], 0.f);
            const float hp = fmaxf(pb1[u] + q0 * pW1[u] + q1 * pW1[64 + u] + q2 * pW1[128 + u], 0.f);
            ushort h, l;
            split2(hc, h, l); Ahc[objl * 72 + u] = h; Alc[objl * 72 + u] = l;
            split2(hp, h, l); Ahp[objl * 72 + u] = h; Alp[objl * 72 + u] = l;
        }
    }
    __syncthreads();

    f32x4 aco[4], ape[4];
    #pragma unroll
    for (int nt = 0; nt < 4; ++nt) { aco[nt] = (f32x4){0.f,0.f,0.f,0.f}; ape[nt] = (f32x4){0.f,0.f,0.f,0.f}; }

    #pragma unroll
    for (int kt = 0; kt < 2; ++kt) {
        const int ao = l15 * 72 + kt * 32 + quad * 8;
        const s16x8 ahc = *(const s16x8*)&Ahc[ao];
        const s16x8 alc = *(const s16x8*)&Alc[ao];
        const s16x8 ahp = *(const s16x8*)&Ahp[ao];
        const s16x8 alp = *(const s16x8*)&Alp[ao];
        #pragma unroll
        for (int nt = 0; nt < 4; ++nt) {
            const int n = w * 64 + nt * 16 + l15;
            const size_t bo = (size_t)n * 64 + kt * 32 + quad * 8;
            const s16x8 cbh = *(const s16x8*)(cW2Th + bo);
            const s16x8 cbl = *(const s16x8*)(cW2Tl + bo);
            const s16x8 pbh = *(const s16x8*)(pW2Th + bo);
            const s16x8 pbl = *(const s16x8*)(pW2Tl + bo);
            aco[nt] = __builtin_amdgcn_mfma_f32_16x16x32_bf16(ahc, cbh, aco[nt], 0, 0, 0);
            ape[nt] = __builtin_amdgcn_mfma_f32_16x16x32_bf16(ahp, pbh, ape[nt], 0, 0, 0);
            aco[nt] = __builtin_amdgcn_mfma_f32_16x16x32_bf16(alc, cbh, aco[nt], 0, 0, 0);
            ape[nt] = __builtin_amdgcn_mfma_f32_16x16x32_bf16(alp, pbh, ape[nt], 0, 0, 0);
            aco[nt] = __builtin_amdgcn_mfma_f32_16x16x32_bf16(ahc, cbl, aco[nt], 0, 0, 0);
            ape[nt] = __builtin_amdgcn_mfma_f32_16x16x32_bf16(ahp, pbl, ape[nt], 0, 0, 0);
        }
    }

    float sc[4] = {0.f,0.f,0.f,0.f}, sp[4] = {0.f,0.f,0.f,0.f};
    #pragma unroll
    for (int nt = 0; nt < 4; ++nt) {
        const int col = w * 64 + nt * 16 + l15;
        const float cbv = cb2[col], pbv = pb2[col];
        #pragma unroll
        for (int r = 0; r < 4; ++r) {
            const float co = aco[nt][r] + cbv;
            const float pe = ape[nt][r] + pbv;
            sc[r] += co * co;
            sp[r] += pe * pe;
        }
    }
    #pragma unroll
    for (int s = 8; s > 0; s >>= 1) {
        #pragma unroll
        for (int r = 0; r < 4; ++r) {
            sc[r] += __shfl_xor(sc[r], s, 64);
            sp[r] += __shfl_xor(sp[r], s, 64);
        }
    }
    if (l15 == 0) {
        #pragma unroll
        for (int r = 0; r < 4; ++r) { sqc[quad * 4 + r][w] = sc[r]; sqp_[quad * 4 + r][w] = sp[r]; }
    }
    __syncthreads();

    float rco[4], rpe[4];
    #pragma unroll
    for (int r = 0; r < 4; ++r) {
        const int row = quad * 4 + r;
        rco[r] = 1.f / fmaxf(sqrtf(sqc[row][0] + sqc[row][1] + sqc[row][2] + sqc[row][3]), 1e-12f);
        rpe[r] = 1.f / fmaxf(sqrtf(sqp_[row][0] + sqp_[row][1] + sqp_[row][2] + sqp_[row][3]), 1e-12f);
    }

    f32x4 ac[4], ap[4];
    #pragma unroll
    for (int nt = 0; nt < 4; ++nt) { ac[nt] = (f32x4){0.f,0.f,0.f,0.f}; ap[nt] = (f32x4){0.f,0.f,0.f,0.f}; }

    #pragma unroll
    for (int kt = 0; kt < 2; ++kt) {
        const int ao = l15 * 72 + kt * 32 + quad * 8;
        const s16x8 ahc = *(const s16x8*)&Ahc[ao];
        const s16x8 alc = *(const s16x8*)&Alc[ao];
        const s16x8 ahp = *(const s16x8*)&Ahp[ao];
        const s16x8 alp = *(const s16x8*)&Alp[ao];
        #pragma unroll
        for (int nt = 0; nt < 4; ++nt) {
            const int n = w * 64 + nt * 16 + l15;
            const size_t bo = (size_t)n * 64 + kt * 32 + quad * 8;
            const s16x8 cbh = *(const s16x8*)(WcTh + bo);
            const s16x8 cbl = *(const s16x8*)(WcTl + bo);
            const s16x8 pbh = *(const s16x8*)(WpTh + bo);
            const s16x8 pbl = *(const s16x8*)(WpTl + bo);
            ac[nt] = __builtin_amdgcn_mfma_f32_16x16x32_bf16(ahc, cbh, ac[nt], 0, 0, 0);
            ap[nt] = __builtin_amdgcn_mfma_f32_16x16x32_bf16(ahp, pbh, ap[nt], 0, 0, 0);
            ac[nt] = __builtin_amdgcn_mfma_f32_16x16x32_bf16(alc, cbh, ac[nt], 0, 0, 0);
            ap[nt] = __builtin_amdgcn_mfma_f32_16x16x32_bf16(alp, pbh, ap[nt], 0, 0, 0);
            ac[nt] = __builtin_amdgcn_mfma_f32_16x16x32_bf16(ahc, cbl, ac[nt], 0, 0, 0);
            ap[nt] = __builtin_amdgcn_mfma_f32_16x16x32_bf16(ahp, pbl, ap[nt], 0, 0, 0);
        }
    }

    int ci[4];
    #pragma unroll
    for (int r = 0; r < 4; ++r) {
        const int gobj = obase + quad * 4 + r;
        int c = cls[(size_t)gobj * cstride];
        if ((unsigned)c > 30u) c = 0;
        ci[r] = c;
    }

    float rp[4] = {0.f,0.f,0.f,0.f};
    #pragma unroll
    for (int nt = 0; nt < 4; ++nt) {
        const int col = w * 64 + nt * 16 + l15;
        const float mbv = mb[col], cbMv = cbM[col], pbMv = pbM[col];
        #pragma unroll
        for (int r = 0; r < 4; ++r) {
            const int row = quad * 4 + r;
            const float e = classMn[ci[r] * 256 + col]
                          + rco[r] * (ac[nt][r] + cbMv)
                          + rpe[r] * (ap[nt][r] + pbMv) + mbv;
            ushort h, l;
            split2(e, h, l);
            ehi[(size_t)(obase + row) * 256 + col] = h;
            elo[(size_t)(obase + row) * 256 + col] = l;
            rp[r] += e * e;
        }
    }
    #pragma unroll
    for (int s = 8; s > 0; s >>= 1) {
        #pragma unroll
        for (int r = 0; r < 4; ++r) rp[r] += __shfl_xor(rp[r], s, 64);
    }
    if (l15 == 0) {
        #pragma unroll
        for (int r = 0; r < 4; ++r) sqe[quad * 4 + r][w] = rp[r];
    }
    __syncthreads();
    if (t < 16) sqn[obase + t] = sqe[t][0] + sqe[t][1] + sqe[t][2] + sqe[t][3];
}

// ---------------------------------------------------------------------------
// Kernel 2: Gram/distance. m97-style 128x128 tile per block, double-buffered
// LDS staged via global_load_lds (width 16), BK=32/step, XOR chunk-swizzle
// on both sides (rule 21). Diagonal tiles stage A only. Nontemporal dist.
// BYTE-IDENTICAL to the passing R9 version (protects kNN bit-stability).
// ---------------------------------------------------------------------------
__global__ __launch_bounds__(256)
void k_gram(const ushort* __restrict__ ehi, const ushort* __restrict__ elo,
            const float* __restrict__ sqn, float* __restrict__ dist)
{
    // [dbuf][Ah,Al,Bh,Bl][128 rows * 32 k], 64 KB total
    __shared__ __align__(16) ushort lds[2][4][4096];

    const int t = threadIdx.x, w = t >> 6, lane = t & 63;
    const int l15 = lane & 15, quad = lane >> 4;
    const int b = blockIdx.x;
    const int xcd = b & 7, rest = b >> 3;        // rest 0..127
    const int cell = xcd * 8 + (rest >> 4);      // 0..63
    const int tile = rest & 15;
    const int p0 = (tile >> 2) * 128, q0 = (tile & 3) * 128;
    const size_t cb = (size_t)cell * NP;
    const int diag = (p0 == q0);
    const int wr = w >> 1, wc = w & 1;           // 2x2 wave grid, 64x64 each

    int srow[2], scol[2];
    #pragma unroll
    for (int i = 0; i < 2; ++i) {
        const int p = (w * 2 + i) * 64 + lane;
        const int row = p >> 2;
        srow[i] = row;
        scol[i] = ((p & 3) ^ ((row >> 1) & 3)) * 8;   // ushort offset of 16B chunk
    }

    #define STAGE(KT, D)                                                         \
    {                                                                            \
        const int kb_ = (KT) * 32;                                               \
        _Pragma("unroll")                                                        \
        for (int i = 0; i < 2; ++i) {                                            \
            const int ls_ = (w * 2 + i) * 512;   /* slot*8 ushorts */            \
            const size_t ga_ = (cb + p0 + srow[i]) * 256 + kb_ + scol[i];        \
            gload16(ehi + ga_, &lds[D][0][ls_]);                                 \
            gload16(elo + ga_, &lds[D][1][ls_]);                                 \
            if (!diag) {                                                         \
                const size_t gq_ = (cb + q0 + srow[i]) * 256 + kb_ + scol[i];    \
                gload16(ehi + gq_, &lds[D][2][ls_]);                             \
                gload16(elo + gq_, &lds[D][3][ls_]);                             \
            }                                                                    \
        }                                                                        \
    }

    f32x4 acc[4][4];
    #pragma unroll
    for (int mt = 0; mt < 4; ++mt)
        #pragma unroll
        for (int nt = 0; nt < 4; ++nt) acc[mt][nt] = (f32x4){0.f, 0.f, 0.f, 0.f};

    const int bB = diag ? 0 : 2;

    STAGE(0, 0);
    __syncthreads();

    for (int kt = 0; kt < 8; ++kt) {
        const int cur = kt & 1;
        if (kt < 7) STAGE(kt + 1, cur ^ 1);      // prefetch next k-slice

        s16x8 ah[4], al[4];
        #pragma unroll
        for (int mt = 0; mt < 4; ++mt) {
            const int r = wr * 64 + mt * 16 + l15;
            const int slot = 4 * r + (quad ^ ((r >> 1) & 3));
            ah[mt] = *(const s16x8*)&lds[cur][0][slot * 8];
            al[mt] = *(const s16x8*)&lds[cur][1][slot * 8];
        }
        #pragma unroll
        for (int nt = 0; nt < 4; ++nt) {
            const int rq = wc * 64 + nt * 16 + l15;
            const int slot = 4 * rq + (quad ^ ((rq >> 1) & 3));
            const s16x8 bh = *(const s16x8*)&lds[cur][bB][slot * 8];
            const s16x8 bl = *(const s16x8*)&lds[cur][bB + 1][slot * 8];
            #pragma unroll
            for (int mt = 0; mt < 4; ++mt) {
                acc[mt][nt] = __builtin_amdgcn_mfma_f32_16x16x32_bf16(ah[mt], bh, acc[mt][nt], 0, 0, 0);
                acc[mt][nt] = __builtin_amdgcn_mfma_f32_16x16x32_bf16(al[mt], bh, acc[mt][nt], 0, 0, 0);
                acc[mt][nt] = __builtin_amdgcn_mfma_f32_16x16x32_bf16(ah[mt], bl, acc[mt][nt], 0, 0, 0);
            }
        }
        __syncthreads();                          // drains vmcnt(0) -> buf ready
    }
    #undef STAGE

    float sqp[4][4];
    #pragma unroll
    for (int mt = 0; mt < 4; ++mt)
        #pragma unroll
        for (int r = 0; r < 4; ++r)
            sqp[mt][r] = sqn[cb + p0 + wr * 64 + mt * 16 + quad * 4 + r];

    #pragma unroll
    for (int nt = 0; nt < 4; ++nt) {
        const int colq = q0 + wc * 64 + nt * 16 + l15;
        const float sq_q = sqn[cb + colq];
        #pragma unroll
        for (int mt = 0; mt < 4; ++mt) {
            #pragma unroll
            for (int r = 0; r < 4; ++r) {
                const int rowp = p0 + wr * 64 + mt * 16 + quad * 4 + r;
                __builtin_nontemporal_store((sqp[mt][r] + sq_q) - 2.f * acc[mt][nt][r],
                                            &dist[(cb + rowp) * NP + colq]);
            }
        }
    }
}

// ---------------------------------------------------------------------------
// Kernel 3: top-8 smallest per point (ties -> lowest index). One wave/point.
// ---------------------------------------------------------------------------
__global__ __launch_bounds__(256)
void k_select(const float* __restrict__ dist, int* __restrict__ nidx)
{
    const int wv = threadIdx.x >> 6, lane = threadIdx.x & 63;
    const int xcd = blockIdx.x & 7, rest = blockIdx.x >> 3;   // rest 0..1023
    const int cell = xcd * 8 + (rest >> 7);                   // 0..63
    const int p = cell * NP + (rest & 127) * 4 + wv;          // global point
    const float* row = dist + (size_t)p * NP;

    float d[8];
    {
        const float4 va = *(const float4*)(row + lane * 8);
        const float4 vb = *(const float4*)(row + lane * 8 + 4);
        d[0] = va.x; d[1] = va.y; d[2] = va.z; d[3] = va.w;
        d[4] = vb.x; d[5] = vb.y; d[6] = vb.z; d[7] = vb.w;
    }

    for (int r = 0; r < KNN; ++r) {
        float bd = d[0]; int bi = 0;
        #pragma unroll
        for (int i = 1; i < 8; ++i)
            if (d[i] < bd) { bd = d[i]; bi = i; }   // strict < keeps lowest i on tie
        int bq = lane * 8 + bi;
        #pragma unroll
        for (int s = 32; s > 0; s >>= 1) {
            const float od = __shfl_down(bd, s, 64);
            const int oq = __shfl_down(bq, s, 64);
            if (od < bd || (od == bd && oq < bq)) { bd = od; bq = oq; }
        }
        const int win = __shfl(bq, 0, 64);
        if (lane == 0) nidx[(size_t)p * KNN + r] = ((p >> 9) << 9) | win;
        if ((win >> 3) == lane) {
            const int wi = win & 7;
            #pragma unroll
            for (int i = 0; i < 8; ++i) if (wi == i) d[i] = 3.4e38f;
        }
    }
}

// ---------------------------------------------------------------------------
// Kernel 4: u = x@Wd+gb1, v = x@Wb via 2-pass split MFMA (A hi+lo, B hi only).
// 64 points/block; A staged per k-step through double-buffered LDS via
// global_load_lds width-16 with XOR chunk-swizzle (both sides, rule 21).
// ---------------------------------------------------------------------------
__global__ __launch_bounds__(256)
void k_uv(const ushort* __restrict__ ehi, const ushort* __restrict__ elo,
          const ushort* __restrict__ Wdh, const ushort* __restrict__ Wbh,
          const float* __restrict__ gb1,
          float* __restrict__ u, float* __restrict__ v)
{
    __shared__ __align__(16) ushort lds[2][2][2048];   // [dbuf][hi/lo][slot*8], 16 KB

    const int t = threadIdx.x, w = t >> 6, lane = t & 63;
    const int l15 = lane & 15, quad = lane >> 4;
    const int isV = blockIdx.x >> 9;           // 1024 blocks total
    const int m0 = (blockIdx.x & 511) * 64;
    const ushort* Wh = isV ? Wbh : Wdh;
    float* out = isV ? v : u;
    const int mh = w & 1, ch = w >> 1;

    // staging: 256 slots of 16B per array (64 rows x 4 chunks); wave w covers
    // slots [w*64, w*64+64). slot p holds (row = p>>2, chunk = (p&3)^((row>>1)&3)).
    const int sp = w * 64 + lane;
    const int srow = sp >> 2;
    const int scol = ((sp & 3) ^ ((srow >> 1) & 3)) * 8;   // ushort offset

    #define STAGE_UV(S, D)                                                       \
    {                                                                            \
        const size_t ga_ = (size_t)(m0 + srow) * 256 + (S) * 32 + scol;          \
        gload16(ehi + ga_, &lds[D][0][sp * 8]);                                  \
        gload16(elo + ga_, &lds[D][1][sp * 8]);                                  \
    }

    // read-side slots for this wave's two A-row fragments
    const int r0 = mh * 32 + l15, r1 = r0 + 16;
    const int slot0 = 4 * r0 + (quad ^ ((r0 >> 1) & 3));
    const int slot1 = 4 * r1 + (quad ^ ((r1 >> 1) & 3));

    f32x4 acc[2][8];
    #pragma unroll
    for (int mt = 0; mt < 2; ++mt)
        #pragma unroll
        for (int nt = 0; nt < 8; ++nt) acc[mt][nt] = (f32x4){0.f, 0.f, 0.f, 0.f};

    STAGE_UV(0, 0);
    __syncthreads();

    for (int s = 0; s < 8; ++s) {
        const int cur = s & 1;
        if (s < 7) STAGE_UV(s + 1, cur ^ 1);   // prefetch next k-slice

        const s16x8 ah0 = *(const s16x8*)&lds[cur][0][slot0 * 8];
        const s16x8 al0 = *(const s16x8*)&lds[cur][1][slot0 * 8];
        const s16x8 ah1 = *(const s16x8*)&lds[cur][0][slot1 * 8];
        const s16x8 al1 = *(const s16x8*)&lds[cur][1][slot1 * 8];
        #pragma unroll
        for (int nt = 0; nt < 8; ++nt) {
            const int n = ch * 128 + nt * 16 + l15;
            const size_t bo = (size_t)n * 256 + s * 32 + quad * 8;
            const s16x8 bh = *(const s16x8*)(Wh + bo);
            acc[0][nt] = __builtin_amdgcn_mfma_f32_16x16x32_bf16(ah0, bh, acc[0][nt], 0, 0, 0);
            acc[0][nt] = __builtin_amdgcn_mfma_f32_16x16x32_bf16(al0, bh, acc[0][nt], 0, 0, 0);
            acc[1][nt] = __builtin_amdgcn_mfma_f32_16x16x32_bf16(ah1, bh, acc[1][nt], 0, 0, 0);
            acc[1][nt] = __builtin_amdgcn_mfma_f32_16x16x32_bf16(al1, bh, acc[1][nt], 0, 0, 0);
        }
        __syncthreads();                        // drains vmcnt(0) -> buf ready
    }
    #undef STAGE_UV

    #pragma unroll
    for (int mt = 0; mt < 2; ++mt) {
        #pragma unroll
        for (int nt = 0; nt < 8; ++nt) {
            const int col = ch * 128 + nt * 16 + l15;
            const float bias = isV ? 0.f : gb1[col];
            #pragma unroll
            for (int r = 0; r < 4; ++r) {
                const int row = mh * 32 + mt * 16 + quad * 4 + r;
                out[(size_t)(m0 + row) * 256 + col] = acc[mt][nt][r] + bias;
            }
        }
    }
}

// ---------------------------------------------------------------------------
// Kernel 5: edge GEMM + max aggregation. SINGLE-PASS A (R7's pre-registered
// follow-up): A is one RNE bf16 term (was trunc-split hi+lo) -- B (g2h) has
// been hi-only all along and absmax had 4x headroom (9.77e-4 vs 3.87e-3).
// Halves MFMA work, Abuf LDS writes, and A-fragment LDS reads. 512-thread /
// 8-wave structure from R9 (occupancy 41%): wave w owns cols w*32..+31,
// acc = 2 x f32x16 = 32 AGPR. LDS-only inner barrier keeps v loads in
// flight across barriers.
// ---------------------------------------------------------------------------
__global__ __launch_bounds__(512)
void k_edge(const float* __restrict__ u, const float* __restrict__ v,
            const int* __restrict__ nidx,
            const ushort* __restrict__ g2h,
            const float* __restrict__ hb,
            float* __restrict__ part)
{
    __shared__ ushort Abuf[2][2304];      // [dbuf][edge*36+k] hi only, 9.2 KB
    __shared__ float ustage[2048];        // 8 pts x 256 k, 8 KB

    const int t = threadIdx.x, w = t >> 6, lane = t & 63;
    const int l31 = lane & 31, kh = lane >> 5;

    const int b = blockIdx.x;
    const int xcd = b & 7, rest = b >> 3;        // rest 0..511
    const int cell = xcd * 8 + (rest >> 6);      // 0..63
    const int pl0 = cell * NP + (rest & 63) * 8;

    // stage u rows once (coalesced, 4 floats per thread x 512 threads)
    {
        const int pt = t >> 6, kk = (t & 63) * 4;
        *(float4*)&ustage[pt * 256 + kk] = *(const float4*)(u + (size_t)(pl0 + pt) * 256 + kk);
    }

    const int se = t >> 3, kq = t & 7;           // edge 0..63, k-quad 0..7 (4 k each)
    const int upt = se >> 3;                     // point within block
    int svrow = nidx[(size_t)(pl0 + upt) * KNN + (se & 7)];
    if ((unsigned)svrow >= (unsigned)NTOT) svrow = 0;

    __syncthreads();                             // ustage visible (one-time)

    float4 vr[2];                                // 2-set v pipeline (4 floats/thread)

    #define VLOAD(S)                                                             \
    {                                                                            \
        const int k0 = (S) * 32 + kq * 4;                                        \
        vr[(S) & 1] = *(const float4*)(v + (size_t)svrow * 256 + k0);            \
    }
    #define SPLITW(S, BUF)                                                       \
    {                                                                            \
        const int k0u = (S) * 32 + kq * 4;                                       \
        const float4 ua = *(const float4*)&ustage[upt * 256 + k0u];              \
        const float4 va = vr[(S) & 1];                                           \
        const float sv[4] = {                                                    \
            fmaxf(ua.x + va.x, 0.f), fmaxf(ua.y + va.y, 0.f),                    \
            fmaxf(ua.z + va.z, 0.f), fmaxf(ua.w + va.w, 0.f)};                   \
        union { uint2 q; ushort us[4]; } th;                                     \
        _Pragma("unroll")                                                        \
        for (int j = 0; j < 4; ++j) { th.us[j] = f2b(sv[j]); }                   \
        *(uint2*)&Abuf[BUF][se * 36 + kq * 4] = th.q;                            \
    }

    // LDS-only barrier: completes all DS ops issued before it, leaves
    // global loads (vmcnt) in flight across the barrier.
    #define LDS_BARRIER()                                                        \
    {                                                                            \
        asm volatile("s_waitcnt lgkmcnt(0)" ::: "memory");                       \
        __builtin_amdgcn_s_barrier();                                            \
    }

    f32x16 acc[2];
    acc[0] = (f32x16)(0.0f);
    acc[1] = (f32x16)(0.0f);

    VLOAD(0); VLOAD(1);
    SPLITW(0, 0);

    #pragma unroll
    for (int s = 0; s < 8; ++s) {
        LDS_BARRIER();                        // buf[s&1] visible; buf[(s+1)&1] readers done
        if (s < 7) {
            SPLITW(s + 1, (s + 1) & 1);       // u from LDS, v register-resident
            if (s < 6) VLOAD(s + 2);          // stays in flight across barriers
        }

        // A fragments: [m-tile][k-chunk]; row = mt*32 + l31, k = kc*16 + kh*8
        s16x8 ah[2][2];
        #pragma unroll
        for (int mt = 0; mt < 2; ++mt) {
            #pragma unroll
            for (int kc = 0; kc < 2; ++kc) {
                const int ao = (mt * 32 + l31) * 36 + kc * 16 + kh * 8;
                union { uint2 q[2]; s16x8 v8; } Th;
                Th.q[0] = *(const uint2*)&Abuf[s & 1][ao];
                Th.q[1] = *(const uint2*)&Abuf[s & 1][ao + 4];
                ah[mt][kc] = Th.v8;
            }
        }

        #pragma unroll
        for (int kc = 0; kc < 2; ++kc) {
            const int n = w * 32 + l31;
            const s16x8 bh = *(const s16x8*)(g2h + (size_t)n * 256 + s * 32 + kc * 16 + kh * 8);
            acc[0] = __builtin_amdgcn_mfma_f32_32x32x16_bf16(ah[0][kc], bh, acc[0], 0, 0, 0);
            acc[1] = __builtin_amdgcn_mfma_f32_32x32x16_bf16(ah[1][kc], bh, acc[1], 0, 0, 0);
        }
    }
    #undef VLOAD
    #undef SPLITW
    #undef LDS_BARRIER

    const int slot = rest & 63;
    {
        float rm = -3.4e38f;
        #pragma unroll
        for (int r = 0; r < 16; ++r)
            rm = fmaxf(rm, fmaxf(acc[0][r], acc[1][r]));
        rm = fmaxf(rm, __shfl_xor(rm, 32, 64));   // merge row-halves (lane>>5)
        if (kh == 0) {
            const int col = w * 32 + l31;
            part[((size_t)cell * 64 + slot) * 256 + col] = rm + hb[col];
        }
    }
}

// ---------------------------------------------------------------------------
// Kernel 6: reduce 64 partial maxes per cell, final MLP (f32), L2 normalize.
// ---------------------------------------------------------------------------
__global__ __launch_bounds__(256)
void k_final(const float* __restrict__ part,
             const float* __restrict__ lW1, const float* __restrict__ lb1,
             const float* __restrict__ lW2, const float* __restrict__ lb2,
             float* __restrict__ out)
{
    __shared__ float pooled[256];
    __shared__ float hid[256];
    __shared__ float red[4];

    const int b = blockIdx.x;
    const int t = threadIdx.x;

    float m = -3.4e38f;
    for (int s = 0; s < 64; ++s)
        m = fmaxf(m, part[((size_t)b * 64 + s) * 256 + t]);
    pooled[t] = m;
    __syncthreads();

    float h = lb1[t];
    for (int k = 0; k < 256; k += 4) {
        #pragma unroll
        for (int kk = 0; kk < 4; ++kk)
            h += pooled[k + kk] * lW1[(k + kk) * 256 + t];
    }
    hid[t] = fmaxf(h, 0.f);
    __syncthreads();

    float o = lb2[t];
    for (int k = 0; k < 256; k += 4) {
        #pragma unroll
        for (int kk = 0; kk < 4; ++kk)
            o += hid[k + kk] * lW2[(k + kk) * 256 + t];
    }

    float ss = o * o;
    #pragma unroll
    for (int s = 32; s > 0; s >>= 1) ss += __shfl_down(ss, s, 64);
    if ((t & 63) == 0) red[t >> 6] = ss;
    __syncthreads();
    const float tot = red[0] + red[1] + red[2] + red[3];
    const float rn = 1.f / fmaxf(sqrtf(tot), 1e-12f);
    out[b * 256 + t] = o * rn;
}

// ---------------------------------------------------------------------------
extern "C" void kernel_launch(void* const* d_in, const int* in_sizes, int n_in,
                              void* d_out, int out_size, void* d_ws, size_t ws_size,
                              hipStream_t stream)
{
    (void)n_in; (void)out_size; (void)ws_size;

    const float* class_table = (const float*)d_in[0];
    const float* cW1 = (const float*)d_in[1];
    const float* cb1 = (const float*)d_in[2];
    const float* cW2 = (const float*)d_in[3];
    const float* cb2 = (const float*)d_in[4];
    const float* pW1 = (const float*)d_in[5];
    const float* pb1 = (const float*)d_in[6];
    const float* pW2 = (const float*)d_in[7];
    const float* pb2 = (const float*)d_in[8];
    const float* mW  = (const float*)d_in[9];
    const float* mb  = (const float*)d_in[10];
    const float* gW1 = (const float*)d_in[11];
    const float* gb1 = (const float*)d_in[12];
    const float* g_gamma = (const float*)d_in[13];
    const float* g_beta  = (const float*)d_in[14];
    const float* gW2 = (const float*)d_in[15];
    const float* gb2 = (const float*)d_in[16];
    const float* lW1 = (const float*)d_in[17];
    const float* lb1 = (const float*)d_in[18];
    const float* lW2 = (const float*)d_in[19];
    const float* lb2 = (const float*)d_in[20];
    const float* positions = (const float*)d_in[21];
    const float* colors    = (const float*)d_in[22];
    const int*  cls        = (const int*)d_in[23];

    const int cstride = (in_sizes[23] == 2 * NTOT) ? 2 : 1;

    // workspace layout (bytes), total ~174 MB (ws_size ~268 MB).
    char* base = (char*)d_ws;
    float*   part   = (float*)(base + 0);               //   4,194,304
    ushort*  Wdh    = (ushort*)(base + 4194304);
    ushort*  Wdl    = (ushort*)(base + 4325376);
    ushort*  Wbh    = (ushort*)(base + 4456448);
    ushort*  Wbl    = (ushort*)(base + 4587520);
    ushort*  g2h    = (ushort*)(base + 4718592);
    ushort*  g2l    = (ushort*)(base + 4849664);
    float*   hb     = (float*)(base + 4980736);
    ushort*  cW2Th  = (ushort*)(base + 4981760);
    ushort*  cW2Tl  = (ushort*)(base + 5014528);
    ushort*  pW2Th  = (ushort*)(base + 5047296);
    ushort*  pW2Tl  = (ushort*)(base + 5080064);
    ushort*  WcTh   = (ushort*)(base + 5112832);
    ushort*  WcTl   = (ushort*)(base + 5145600);
    ushort*  WpTh   = (ushort*)(base + 5178368);
    ushort*  WpTl   = (ushort*)(base + 5211136);
    float*   classMn= (float*)(base + 5243904);
    float*   cbM    = (float*)(base + 5275648);
    float*   pbM    = (float*)(base + 5276672);
    int*     nidx   = (int*)(base + 5277696);           //   1,048,576
    float*   sqn    = (float*)(base + 6326272);         //     131,072
    ushort*  ehi    = (ushort*)(base + 6457344);        //  16,777,216
    ushort*  elo    = (ushort*)(base + 23234560);       //  16,777,216
    float*   dist   = (float*)(base + 40011776);        //  67,108,864
    float*   v      = (float*)(base + 107120640);       //  33,554,432
    float*   u      = (float*)(base + 140675072);       //  33,554,432
    float* out = (float*)d_out;

    k_cvt<<<897, 256, 0, stream>>>(gW1, gW2, g_gamma, g_beta, gb2, cW2, pW2,
                                   Wdh, Wdl, Wbh, Wbl, g2h, g2l, hb,
                                   cW2Th, cW2Tl, pW2Th, pW2Tl);
    k_fold<<<130, 256, 0, stream>>>(cW2, pW2, cb2, pb2, mW,
                                    WcTh, WcTl, WpTh, WpTl, cbM, pbM);
    k_cls<<<31, 256, 0, stream>>>(class_table, mW, classMn);

    k_embed<<<NTOT / 16, 256, 0, stream>>>(classMn, cW1, cb1, cb2, pW1, pb1, pb2,
                                           mb, cW2Th, cW2Tl, pW2Th, pW2Tl,
                                           WcTh, WcTl, WpTh, WpTl, cbM, pbM,
                                           positions, colors, cls, cstride,
                                           ehi, elo, sqn);
    k_gram<<<NB * 16, 256, 0, stream>>>(ehi, elo, sqn, dist);
    k_select<<<NTOT / 4, 256, 0, stream>>>(dist, nidx);
    k_uv<<<2 * NTOT / 64, 256, 0, stream>>>(ehi, elo, Wdh, Wbh, gb1, u, v);
    k_edge<<<NTOT / 8, 512, 0, stream>>>(u, v, nidx, g2h, hb, part);
    k_final<<<NB, 256, 0, stream>>>(part, lW1, lb1, lW2, lb2, out);
}

// Round 11
// 417.407 us; speedup vs baseline: 1.0971x; 1.0146x over previous
//
#include <hip/hip_runtime.h>

#define EDIM 256
#define KNN 8
#define NB 64
#define NP 512
#define NTOT (NB * NP)

typedef short s16x8 __attribute__((ext_vector_type(8)));
typedef float f32x4 __attribute__((ext_vector_type(4)));
typedef float f32x16 __attribute__((ext_vector_type(16)));
typedef unsigned short ushort;

__device__ __forceinline__ ushort f2b(float f) {
    unsigned u = __float_as_uint(f);
    u = (u + 0x7fffu + ((u >> 16) & 1u)) >> 16;   // RNE
    return (ushort)u;
}
__device__ __forceinline__ float b2f(ushort h) {
    return __uint_as_float(((unsigned)h) << 16);
}
__device__ __forceinline__ void split2(float x, ushort& h, ushort& l) {
    h = f2b(x);
    l = f2b(x - b2f(h));
}
// truncation split: pair error ~2^-16 relative, fewer VALU
__device__ __forceinline__ ushort f2bt(float f) {
    return (ushort)(__float_as_uint(f) >> 16);
}
__device__ __forceinline__ void split2t(float x, ushort& h, ushort& l) {
    h = f2bt(x);
    l = f2bt(x - b2f(h));
}

// async global->LDS, 16B per lane; lds dest is wave-uniform base + lane*16
__device__ __forceinline__ void gload16(const ushort* g, ushort* l) {
    __builtin_amdgcn_global_load_lds(
        (const __attribute__((address_space(1))) void*)g,
        (__attribute__((address_space(3))) void*)l, 16, 0, 0);
}

// ---------------------------------------------------------------------------
// Kernel 0a: weight prep -> transposed bf16 hi/lo pairs.
// ---------------------------------------------------------------------------
__global__ __launch_bounds__(256)
void k_cvt(const float* __restrict__ gW1, const float* __restrict__ gW2,
           const float* __restrict__ g_gamma, const float* __restrict__ g_beta,
           const float* __restrict__ gb2,
           const float* __restrict__ cW2, const float* __restrict__ pW2,
           ushort* __restrict__ Wdh, ushort* __restrict__ Wdl,
           ushort* __restrict__ Wbh, ushort* __restrict__ Wbl,
           ushort* __restrict__ g2h, ushort* __restrict__ g2l,
           float* __restrict__ hb,
           ushort* __restrict__ cW2Th, ushort* __restrict__ cW2Tl,
           ushort* __restrict__ pW2Th, ushort* __restrict__ pW2Tl)
{
    const int gid = blockIdx.x * 256 + threadIdx.x;
    ushort h, l;
    if (gid < 65536) {
        const int n = gid >> 8, k = gid & 255;
        split2(gW1[k * 256 + n] - gW1[(k + 256) * 256 + n], h, l);
        Wdh[gid] = h; Wdl[gid] = l;
    } else if (gid < 131072) {
        const int i = gid - 65536, n = i >> 8, k = i & 255;
        split2(gW1[(k + 256) * 256 + n], h, l);
        Wbh[i] = h; Wbl[i] = l;
    } else if (gid < 196608) {
        const int i = gid - 131072, n = i >> 8, k = i & 255;
        split2(g_gamma[k] * gW2[k * 256 + n], h, l);
        g2h[i] = h; g2l[i] = l;
    } else if (gid < 196864) {
        const int n = gid - 196608;
        float s = gb2[n];
        for (int k = 0; k < 256; ++k) s += g_beta[k] * gW2[k * 256 + n];
        hb[n] = s;
    } else if (gid < 213248) {
        const int i = gid - 196864, n = i >> 6, k = i & 63;
        split2(cW2[k * 256 + n], h, l);
        cW2Th[i] = h; cW2Tl[i] = l;
    } else if (gid < 229632) {
        const int i = gid - 213248, n = i >> 6, k = i & 63;
        split2(pW2[k * 256 + n], h, l);
        pW2Th[i] = h; pW2Tl[i] = l;
    }
}

// ---------------------------------------------------------------------------
// Kernel 0b: fold merge GEMM into the MLP weights (linearity).
// ---------------------------------------------------------------------------
__global__ __launch_bounds__(256)
void k_fold(const float* __restrict__ cW2, const float* __restrict__ pW2,
            const float* __restrict__ cb2, const float* __restrict__ pb2,
            const float* __restrict__ mW,
            ushort* __restrict__ WcTh, ushort* __restrict__ WcTl,
            ushort* __restrict__ WpTh, ushort* __restrict__ WpTl,
            float* __restrict__ cbM, float* __restrict__ pbM)
{
    const int gid = blockIdx.x * 256 + threadIdx.x;
    ushort h, l;
    if (gid < 16384) {
        const int j = gid >> 8, n = gid & 255;
        float s = 0.f;
        for (int k = 0; k < 256; ++k) s += cW2[j * 256 + k] * mW[(256 + k) * 256 + n];
        split2(s, h, l);
        WcTh[n * 64 + j] = h; WcTl[n * 64 + j] = l;
    } else if (gid < 32768) {
        const int i = gid - 16384, j = i >> 8, n = i & 255;
        float s = 0.f;
        for (int k = 0; k < 256; ++k) s += pW2[j * 256 + k] * mW[(512 + k) * 256 + n];
        split2(s, h, l);
        WpTh[n * 64 + j] = h; WpTl[n * 64 + j] = l;
    } else if (gid < 33024) {
        const int n = gid - 32768;
        float s = 0.f;
        for (int k = 0; k < 256; ++k) s += cb2[k] * mW[(256 + k) * 256 + n];
        cbM[n] = s;
    } else if (gid < 33280) {
        const int n = gid - 33024;
        float s = 0.f;
        for (int k = 0; k < 256; ++k) s += pb2[k] * mW[(512 + k) * 256 + n];
        pbM[n] = s;
    }
}

// ---------------------------------------------------------------------------
// Kernel 0c: classMn[c] = (class_table[c] / ||class_table[c]||) @ M0.
// ---------------------------------------------------------------------------
__global__ __launch_bounds__(256)
void k_cls(const float* __restrict__ ct, const float* __restrict__ mW,
           float* __restrict__ classMn)
{
    __shared__ float ctn[256];
    __shared__ float red[4];
    const int c = blockIdx.x, t = threadIdx.x;
    const float v = ct[c * 256 + t];
    float ss = v * v;
    #pragma unroll
    for (int s = 32; s > 0; s >>= 1) ss += __shfl_down(ss, s, 64);
    if ((t & 63) == 0) red[t >> 6] = ss;
    __syncthreads();
    const float tot = red[0] + red[1] + red[2] + red[3];
    const float r = 1.f / fmaxf(sqrtf(tot), 1e-12f);
    ctn[t] = v * r;
    __syncthreads();
    float s = 0.f;
    for (int k = 0; k < 256; ++k) s += ctn[k] * mW[k * 256 + t];
    classMn[c * 256 + t] = s;
}

// ---------------------------------------------------------------------------
// Kernel 1: embeddings via folded GEMMs. 16 obj/block, full problem (2048).
// ---------------------------------------------------------------------------
__global__ __launch_bounds__(256)
void k_embed(const float* __restrict__ classMn,
             const float* __restrict__ cW1, const float* __restrict__ cb1,
             const float* __restrict__ cb2,
             const float* __restrict__ pW1, const float* __restrict__ pb1,
             const float* __restrict__ pb2,
             const float* __restrict__ mb,
             const ushort* __restrict__ cW2Th, const ushort* __restrict__ cW2Tl,
             const ushort* __restrict__ pW2Th, const ushort* __restrict__ pW2Tl,
             const ushort* __restrict__ WcTh, const ushort* __restrict__ WcTl,
             const ushort* __restrict__ WpTh, const ushort* __restrict__ WpTl,
             const float* __restrict__ cbM, const float* __restrict__ pbM,
             const float* __restrict__ positions, const float* __restrict__ colors,
             const int* __restrict__ cls, const int cstride,
             ushort* __restrict__ ehi, ushort* __restrict__ elo,
             float* __restrict__ sqn)
{
    __shared__ __align__(16) ushort Ahc[16 * 72];
    __shared__ __align__(16) ushort Alc[16 * 72];
    __shared__ __align__(16) ushort Ahp[16 * 72];
    __shared__ __align__(16) ushort Alp[16 * 72];
    __shared__ float sqc[16][4], sqp_[16][4], sqe[16][4];

    const int t = threadIdx.x, w = t >> 6, lane = t & 63;
    const int l15 = lane & 15, quad = lane >> 4;
    const int obase = blockIdx.x * 16;

    {
        const int o = lane >> 4;
        const int objl = w * 4 + o;
        const int gobj = obase + objl;
        const float c0 = colors[gobj * 3], c1 = colors[gobj * 3 + 1], c2 = colors[gobj * 3 + 2];
        const float q0 = positions[gobj * 3], q1 = positions[gobj * 3 + 1], q2 = positions[gobj * 3 + 2];
        const int u0 = (lane & 15) * 4;
        #pragma unroll
        for (int uu = 0; uu < 4; ++uu) {
            const int u = u0 + uu;
            const float hc = fmaxf(cb1[u] + c0 * cW1[u] + c1 * cW1[64 + u] + c2 * cW1[128 + u], 0.f);
            const float hp = fmaxf(pb1[u] + q0 * pW1[u] + q1 * pW1[64 + u] + q2 * pW1[128 + u], 0.f);
            ushort h, l;
            split2(hc, h, l); Ahc[objl * 72 + u] = h; Alc[objl * 72 + u] = l;
            split2(hp, h, l); Ahp[objl * 72 + u] = h; Alp[objl * 72 + u] = l;
        }
    }
    __syncthreads();

    f32x4 aco[4], ape[4];
    #pragma unroll
    for (int nt = 0; nt < 4; ++nt) { aco[nt] = (f32x4){0.f,0.f,0.f,0.f}; ape[nt] = (f32x4){0.f,0.f,0.f,0.f}; }

    #pragma unroll
    for (int kt = 0; kt < 2; ++kt) {
        const int ao = l15 * 72 + kt * 32 + quad * 8;
        const s16x8 ahc = *(const s16x8*)&Ahc[ao];
        const s16x8 alc = *(const s16x8*)&Alc[ao];
        const s16x8 ahp = *(const s16x8*)&Ahp[ao];
        const s16x8 alp = *(const s16x8*)&Alp[ao];
        #pragma unroll
        for (int nt = 0; nt < 4; ++nt) {
            const int n = w * 64 + nt * 16 + l15;
            const size_t bo = (size_t)n * 64 + kt * 32 + quad * 8;
            const s16x8 cbh = *(const s16x8*)(cW2Th + bo);
            const s16x8 cbl = *(const s16x8*)(cW2Tl + bo);
            const s16x8 pbh = *(const s16x8*)(pW2Th + bo);
            const s16x8 pbl = *(const s16x8*)(pW2Tl + bo);
            aco[nt] = __builtin_amdgcn_mfma_f32_16x16x32_bf16(ahc, cbh, aco[nt], 0, 0, 0);
            ape[nt] = __builtin_amdgcn_mfma_f32_16x16x32_bf16(ahp, pbh, ape[nt], 0, 0, 0);
            aco[nt] = __builtin_amdgcn_mfma_f32_16x16x32_bf16(alc, cbh, aco[nt], 0, 0, 0);
            ape[nt] = __builtin_amdgcn_mfma_f32_16x16x32_bf16(alp, pbh, ape[nt], 0, 0, 0);
            aco[nt] = __builtin_amdgcn_mfma_f32_16x16x32_bf16(ahc, cbl, aco[nt], 0, 0, 0);
            ape[nt] = __builtin_amdgcn_mfma_f32_16x16x32_bf16(ahp, pbl, ape[nt], 0, 0, 0);
        }
    }

    float sc[4] = {0.f,0.f,0.f,0.f}, sp[4] = {0.f,0.f,0.f,0.f};
    #pragma unroll
    for (int nt = 0; nt < 4; ++nt) {
        const int col = w * 64 + nt * 16 + l15;
        const float cbv = cb2[col], pbv = pb2[col];
        #pragma unroll
        for (int r = 0; r < 4; ++r) {
            const float co = aco[nt][r] + cbv;
            const float pe = ape[nt][r] + pbv;
            sc[r] += co * co;
            sp[r] += pe * pe;
        }
    }
    #pragma unroll
    for (int s = 8; s > 0; s >>= 1) {
        #pragma unroll
        for (int r = 0; r < 4; ++r) {
            sc[r] += __shfl_xor(sc[r], s, 64);
            sp[r] += __shfl_xor(sp[r], s, 64);
        }
    }
    if (l15 == 0) {
        #pragma unroll
        for (int r = 0; r < 4; ++r) { sqc[quad * 4 + r][w] = sc[r]; sqp_[quad * 4 + r][w] = sp[r]; }
    }
    __syncthreads();

    float rco[4], rpe[4];
    #pragma unroll
    for (int r = 0; r < 4; ++r) {
        const int row = quad * 4 + r;
        rco[r] = 1.f / fmaxf(sqrtf(sqc[row][0] + sqc[row][1] + sqc[row][2] + sqc[row][3]), 1e-12f);
        rpe[r] = 1.f / fmaxf(sqrtf(sqp_[row][0] + sqp_[row][1] + sqp_[row][2] + sqp_[row][3]), 1e-12f);
    }

    f32x4 ac[4], ap[4];
    #pragma unroll
    for (int nt = 0; nt < 4; ++nt) { ac[nt] = (f32x4){0.f,0.f,0.f,0.f}; ap[nt] = (f32x4){0.f,0.f,0.f,0.f}; }

    #pragma unroll
    for (int kt = 0; kt < 2; ++kt) {
        const int ao = l15 * 72 + kt * 32 + quad * 8;
        const s16x8 ahc = *(const s16x8*)&Ahc[ao];
        const s16x8 alc = *(const s16x8*)&Alc[ao];
        const s16x8 ahp = *(const s16x8*)&Ahp[ao];
        const s16x8 alp = *(const s16x8*)&Alp[ao];
        #pragma unroll
        for (int nt = 0; nt < 4; ++nt) {
            const int n = w * 64 + nt * 16 + l15;
            const size_t bo = (size_t)n * 64 + kt * 32 + quad * 8;
            const s16x8 cbh = *(const s16x8*)(WcTh + bo);
            const s16x8 cbl = *(const s16x8*)(WcTl + bo);
            const s16x8 pbh = *(const s16x8*)(WpTh + bo);
            const s16x8 pbl = *(const s16x8*)(WpTl + bo);
            ac[nt] = __builtin_amdgcn_mfma_f32_16x16x32_bf16(ahc, cbh, ac[nt], 0, 0, 0);
            ap[nt] = __builtin_amdgcn_mfma_f32_16x16x32_bf16(ahp, pbh, ap[nt], 0, 0, 0);
            ac[nt] = __builtin_amdgcn_mfma_f32_16x16x32_bf16(alc, cbh, ac[nt], 0, 0, 0);
            ap[nt] = __builtin_amdgcn_mfma_f32_16x16x32_bf16(alp, pbh, ap[nt], 0, 0, 0);
            ac[nt] = __builtin_amdgcn_mfma_f32_16x16x32_bf16(ahc, cbl, ac[nt], 0, 0, 0);
            ap[nt] = __builtin_amdgcn_mfma_f32_16x16x32_bf16(ahp, pbl, ap[nt], 0, 0, 0);
        }
    }

    int ci[4];
    #pragma unroll
    for (int r = 0; r < 4; ++r) {
        const int gobj = obase + quad * 4 + r;
        int c = cls[(size_t)gobj * cstride];
        if ((unsigned)c > 30u) c = 0;
        ci[r] = c;
    }

    float rp[4] = {0.f,0.f,0.f,0.f};
    #pragma unroll
    for (int nt = 0; nt < 4; ++nt) {
        const int col = w * 64 + nt * 16 + l15;
        const float mbv = mb[col], cbMv = cbM[col], pbMv = pbM[col];
        #pragma unroll
        for (int r = 0; r < 4; ++r) {
            const int row = quad * 4 + r;
            const float e = classMn[ci[r] * 256 + col]
                          + rco[r] * (ac[nt][r] + cbMv)
                          + rpe[r] * (ap[nt][r] + pbMv) + mbv;
            ushort h, l;
            split2(e, h, l);
            ehi[(size_t)(obase + row) * 256 + col] = h;
            elo[(size_t)(obase + row) * 256 + col] = l;
            rp[r] += e * e;
        }
    }
    #pragma unroll
    for (int s = 8; s > 0; s >>= 1) {
        #pragma unroll
        for (int r = 0; r < 4; ++r) rp[r] += __shfl_xor(rp[r], s, 64);
    }
    if (l15 == 0) {
        #pragma unroll
        for (int r = 0; r < 4; ++r) sqe[quad * 4 + r][w] = rp[r];
    }
    __syncthreads();
    if (t < 16) sqn[obase + t] = sqe[t][0] + sqe[t][1] + sqe[t][2] + sqe[t][3];
}

// ---------------------------------------------------------------------------
// Kernel 2: Gram/distance. m97-style 128x128 tile per block, double-buffered
// LDS staged via global_load_lds (width 16), BK=32/step, XOR chunk-swizzle
// on both sides (rule 21). Diagonal tiles stage A only. Nontemporal dist.
// BYTE-IDENTICAL to the passing R10 version (protects kNN bit-stability).
// ---------------------------------------------------------------------------
__global__ __launch_bounds__(256)
void k_gram(const ushort* __restrict__ ehi, const ushort* __restrict__ elo,
            const float* __restrict__ sqn, float* __restrict__ dist)
{
    // [dbuf][Ah,Al,Bh,Bl][128 rows * 32 k], 64 KB total
    __shared__ __align__(16) ushort lds[2][4][4096];

    const int t = threadIdx.x, w = t >> 6, lane = t & 63;
    const int l15 = lane & 15, quad = lane >> 4;
    const int b = blockIdx.x;
    const int xcd = b & 7, rest = b >> 3;        // rest 0..127
    const int cell = xcd * 8 + (rest >> 4);      // 0..63
    const int tile = rest & 15;
    const int p0 = (tile >> 2) * 128, q0 = (tile & 3) * 128;
    const size_t cb = (size_t)cell * NP;
    const int diag = (p0 == q0);
    const int wr = w >> 1, wc = w & 1;           // 2x2 wave grid, 64x64 each

    int srow[2], scol[2];
    #pragma unroll
    for (int i = 0; i < 2; ++i) {
        const int p = (w * 2 + i) * 64 + lane;
        const int row = p >> 2;
        srow[i] = row;
        scol[i] = ((p & 3) ^ ((row >> 1) & 3)) * 8;   // ushort offset of 16B chunk
    }

    #define STAGE(KT, D)                                                         \
    {                                                                            \
        const int kb_ = (KT) * 32;                                               \
        _Pragma("unroll")                                                        \
        for (int i = 0; i < 2; ++i) {                                            \
            const int ls_ = (w * 2 + i) * 512;   /* slot*8 ushorts */            \
            const size_t ga_ = (cb + p0 + srow[i]) * 256 + kb_ + scol[i];        \
            gload16(ehi + ga_, &lds[D][0][ls_]);                                 \
            gload16(elo + ga_, &lds[D][1][ls_]);                                 \
            if (!diag) {                                                         \
                const size_t gq_ = (cb + q0 + srow[i]) * 256 + kb_ + scol[i];    \
                gload16(ehi + gq_, &lds[D][2][ls_]);                             \
                gload16(elo + gq_, &lds[D][3][ls_]);                             \
            }                                                                    \
        }                                                                        \
    }

    f32x4 acc[4][4];
    #pragma unroll
    for (int mt = 0; mt < 4; ++mt)
        #pragma unroll
        for (int nt = 0; nt < 4; ++nt) acc[mt][nt] = (f32x4){0.f, 0.f, 0.f, 0.f};

    const int bB = diag ? 0 : 2;

    STAGE(0, 0);
    __syncthreads();

    for (int kt = 0; kt < 8; ++kt) {
        const int cur = kt & 1;
        if (kt < 7) STAGE(kt + 1, cur ^ 1);      // prefetch next k-slice

        s16x8 ah[4], al[4];
        #pragma unroll
        for (int mt = 0; mt < 4; ++mt) {
            const int r = wr * 64 + mt * 16 + l15;
            const int slot = 4 * r + (quad ^ ((r >> 1) & 3));
            ah[mt] = *(const s16x8*)&lds[cur][0][slot * 8];
            al[mt] = *(const s16x8*)&lds[cur][1][slot * 8];
        }
        #pragma unroll
        for (int nt = 0; nt < 4; ++nt) {
            const int rq = wc * 64 + nt * 16 + l15;
            const int slot = 4 * rq + (quad ^ ((rq >> 1) & 3));
            const s16x8 bh = *(const s16x8*)&lds[cur][bB][slot * 8];
            const s16x8 bl = *(const s16x8*)&lds[cur][bB + 1][slot * 8];
            #pragma unroll
            for (int mt = 0; mt < 4; ++mt) {
                acc[mt][nt] = __builtin_amdgcn_mfma_f32_16x16x32_bf16(ah[mt], bh, acc[mt][nt], 0, 0, 0);
                acc[mt][nt] = __builtin_amdgcn_mfma_f32_16x16x32_bf16(al[mt], bh, acc[mt][nt], 0, 0, 0);
                acc[mt][nt] = __builtin_amdgcn_mfma_f32_16x16x32_bf16(ah[mt], bl, acc[mt][nt], 0, 0, 0);
            }
        }
        __syncthreads();                          // drains vmcnt(0) -> buf ready
    }
    #undef STAGE

    float sqp[4][4];
    #pragma unroll
    for (int mt = 0; mt < 4; ++mt)
        #pragma unroll
        for (int r = 0; r < 4; ++r)
            sqp[mt][r] = sqn[cb + p0 + wr * 64 + mt * 16 + quad * 4 + r];

    #pragma unroll
    for (int nt = 0; nt < 4; ++nt) {
        const int colq = q0 + wc * 64 + nt * 16 + l15;
        const float sq_q = sqn[cb + colq];
        #pragma unroll
        for (int mt = 0; mt < 4; ++mt) {
            #pragma unroll
            for (int r = 0; r < 4; ++r) {
                const int rowp = p0 + wr * 64 + mt * 16 + quad * 4 + r;
                __builtin_nontemporal_store((sqp[mt][r] + sq_q) - 2.f * acc[mt][nt][r],
                                            &dist[(cb + rowp) * NP + colq]);
            }
        }
    }
}

// ---------------------------------------------------------------------------
// Kernel 3: top-8 smallest per point (ties -> lowest index). One wave/point.
// ---------------------------------------------------------------------------
__global__ __launch_bounds__(256)
void k_select(const float* __restrict__ dist, int* __restrict__ nidx)
{
    const int wv = threadIdx.x >> 6, lane = threadIdx.x & 63;
    const int xcd = blockIdx.x & 7, rest = blockIdx.x >> 3;   // rest 0..1023
    const int cell = xcd * 8 + (rest >> 7);                   // 0..63
    const int p = cell * NP + (rest & 127) * 4 + wv;          // global point
    const float* row = dist + (size_t)p * NP;

    float d[8];
    {
        const float4 va = *(const float4*)(row + lane * 8);
        const float4 vb = *(const float4*)(row + lane * 8 + 4);
        d[0] = va.x; d[1] = va.y; d[2] = va.z; d[3] = va.w;
        d[4] = vb.x; d[5] = vb.y; d[6] = vb.z; d[7] = vb.w;
    }

    for (int r = 0; r < KNN; ++r) {
        float bd = d[0]; int bi = 0;
        #pragma unroll
        for (int i = 1; i < 8; ++i)
            if (d[i] < bd) { bd = d[i]; bi = i; }   // strict < keeps lowest i on tie
        int bq = lane * 8 + bi;
        #pragma unroll
        for (int s = 32; s > 0; s >>= 1) {
            const float od = __shfl_down(bd, s, 64);
            const int oq = __shfl_down(bq, s, 64);
            if (od < bd || (od == bd && oq < bq)) { bd = od; bq = oq; }
        }
        const int win = __shfl(bq, 0, 64);
        if (lane == 0) nidx[(size_t)p * KNN + r] = ((p >> 9) << 9) | win;
        if ((win >> 3) == lane) {
            const int wi = win & 7;
            #pragma unroll
            for (int i = 0; i < 8; ++i) if (wi == i) d[i] = 3.4e38f;
        }
    }
}

// ---------------------------------------------------------------------------
// Kernel 4: u = x@Wd+gb1, v = x@Wb. SINGLE-PASS A (same insight as k_edge
// R10: absmax is pinned at the output-bf16 floor, and u+v gets RNE'd to one
// bf16 in k_edge anyway -- hi-only A error is the same order). MFMA halves
// (16/step), staging halves (ehi only, LDS 8 KB). B (Wh) stays direct.
// ---------------------------------------------------------------------------
__global__ __launch_bounds__(256)
void k_uv(const ushort* __restrict__ ehi, const ushort* __restrict__ elo,
          const ushort* __restrict__ Wdh, const ushort* __restrict__ Wbh,
          const float* __restrict__ gb1,
          float* __restrict__ u, float* __restrict__ v)
{
    (void)elo;
    __shared__ __align__(16) ushort lds[2][2048];   // [dbuf][slot*8] hi only, 8 KB

    const int t = threadIdx.x, w = t >> 6, lane = t & 63;
    const int l15 = lane & 15, quad = lane >> 4;
    const int isV = blockIdx.x >> 9;           // 1024 blocks total
    const int m0 = (blockIdx.x & 511) * 64;
    const ushort* Wh = isV ? Wbh : Wdh;
    float* out = isV ? v : u;
    const int mh = w & 1, ch = w >> 1;

    // staging: 256 slots of 16B (64 rows x 4 chunks); wave w covers slots
    // [w*64, w*64+64). slot p holds (row = p>>2, chunk = (p&3)^((row>>1)&3)).
    const int sp = w * 64 + lane;
    const int srow = sp >> 2;
    const int scol = ((sp & 3) ^ ((srow >> 1) & 3)) * 8;   // ushort offset

    #define STAGE_UV(S, D)                                                       \
    {                                                                            \
        const size_t ga_ = (size_t)(m0 + srow) * 256 + (S) * 32 + scol;          \
        gload16(ehi + ga_, &lds[D][sp * 8]);                                     \
    }

    // read-side slots for this wave's two A-row fragments
    const int r0 = mh * 32 + l15, r1 = r0 + 16;
    const int slot0 = 4 * r0 + (quad ^ ((r0 >> 1) & 3));
    const int slot1 = 4 * r1 + (quad ^ ((r1 >> 1) & 3));

    f32x4 acc[2][8];
    #pragma unroll
    for (int mt = 0; mt < 2; ++mt)
        #pragma unroll
        for (int nt = 0; nt < 8; ++nt) acc[mt][nt] = (f32x4){0.f, 0.f, 0.f, 0.f};

    STAGE_UV(0, 0);
    __syncthreads();

    for (int s = 0; s < 8; ++s) {
        const int cur = s & 1;
        if (s < 7) STAGE_UV(s + 1, cur ^ 1);   // prefetch next k-slice

        const s16x8 ah0 = *(const s16x8*)&lds[cur][slot0 * 8];
        const s16x8 ah1 = *(const s16x8*)&lds[cur][slot1 * 8];
        #pragma unroll
        for (int nt = 0; nt < 8; ++nt) {
            const int n = ch * 128 + nt * 16 + l15;
            const size_t bo = (size_t)n * 256 + s * 32 + quad * 8;
            const s16x8 bh = *(const s16x8*)(Wh + bo);
            acc[0][nt] = __builtin_amdgcn_mfma_f32_16x16x32_bf16(ah0, bh, acc[0][nt], 0, 0, 0);
            acc[1][nt] = __builtin_amdgcn_mfma_f32_16x16x32_bf16(ah1, bh, acc[1][nt], 0, 0, 0);
        }
        __syncthreads();                        // drains vmcnt(0) -> buf ready
    }
    #undef STAGE_UV

    #pragma unroll
    for (int mt = 0; mt < 2; ++mt) {
        #pragma unroll
        for (int nt = 0; nt < 8; ++nt) {
            const int col = ch * 128 + nt * 16 + l15;
            const float bias = isV ? 0.f : gb1[col];
            #pragma unroll
            for (int r = 0; r < 4; ++r) {
                const int row = mh * 32 + mt * 16 + quad * 4 + r;
                out[(size_t)(m0 + row) * 256 + col] = acc[mt][nt][r] + bias;
            }
        }
    }
}

// ---------------------------------------------------------------------------
// Kernel 5: edge GEMM + max aggregation. Single-pass RNE A, 512-thread /
// 8-wave structure (occupancy 81%): wave w owns cols w*32..+31, acc = 2 x
// f32x16 = 32 AGPR. LDS-only inner barrier keeps v loads in flight.
// BYTE-IDENTICAL to the passing R10 version.
// ---------------------------------------------------------------------------
__global__ __launch_bounds__(512)
void k_edge(const float* __restrict__ u, const float* __restrict__ v,
            const int* __restrict__ nidx,
            const ushort* __restrict__ g2h,
            const float* __restrict__ hb,
            float* __restrict__ part)
{
    __shared__ ushort Abuf[2][2304];      // [dbuf][edge*36+k] hi only, 9.2 KB
    __shared__ float ustage[2048];        // 8 pts x 256 k, 8 KB

    const int t = threadIdx.x, w = t >> 6, lane = t & 63;
    const int l31 = lane & 31, kh = lane >> 5;

    const int b = blockIdx.x;
    const int xcd = b & 7, rest = b >> 3;        // rest 0..511
    const int cell = xcd * 8 + (rest >> 6);      // 0..63
    const int pl0 = cell * NP + (rest & 63) * 8;

    // stage u rows once (coalesced, 4 floats per thread x 512 threads)
    {
        const int pt = t >> 6, kk = (t & 63) * 4;
        *(float4*)&ustage[pt * 256 + kk] = *(const float4*)(u + (size_t)(pl0 + pt) * 256 + kk);
    }

    const int se = t >> 3, kq = t & 7;           // edge 0..63, k-quad 0..7 (4 k each)
    const int upt = se >> 3;                     // point within block
    int svrow = nidx[(size_t)(pl0 + upt) * KNN + (se & 7)];
    if ((unsigned)svrow >= (unsigned)NTOT) svrow = 0;

    __syncthreads();                             // ustage visible (one-time)

    float4 vr[2];                                // 2-set v pipeline (4 floats/thread)

    #define VLOAD(S)                                                             \
    {                                                                            \
        const int k0 = (S) * 32 + kq * 4;                                        \
        vr[(S) & 1] = *(const float4*)(v + (size_t)svrow * 256 + k0);            \
    }
    #define SPLITW(S, BUF)                                                       \
    {                                                                            \
        const int k0u = (S) * 32 + kq * 4;                                       \
        const float4 ua = *(const float4*)&ustage[upt * 256 + k0u];              \
        const float4 va = vr[(S) & 1];                                           \
        const float sv[4] = {                                                    \
            fmaxf(ua.x + va.x, 0.f), fmaxf(ua.y + va.y, 0.f),                    \
            fmaxf(ua.z + va.z, 0.f), fmaxf(ua.w + va.w, 0.f)};                   \
        union { uint2 q; ushort us[4]; } th;                                     \
        _Pragma("unroll")                                                        \
        for (int j = 0; j < 4; ++j) { th.us[j] = f2b(sv[j]); }                   \
        *(uint2*)&Abuf[BUF][se * 36 + kq * 4] = th.q;                            \
    }

    // LDS-only barrier: completes all DS ops issued before it, leaves
    // global loads (vmcnt) in flight across the barrier.
    #define LDS_BARRIER()                                                        \
    {                                                                            \
        asm volatile("s_waitcnt lgkmcnt(0)" ::: "memory");                       \
        __builtin_amdgcn_s_barrier();                                            \
    }

    f32x16 acc[2];
    acc[0] = (f32x16)(0.0f);
    acc[1] = (f32x16)(0.0f);

    VLOAD(0); VLOAD(1);
    SPLITW(0, 0);

    #pragma unroll
    for (int s = 0; s < 8; ++s) {
        LDS_BARRIER();                        // buf[s&1] visible; buf[(s+1)&1] readers done
        if (s < 7) {
            SPLITW(s + 1, (s + 1) & 1);       // u from LDS, v register-resident
            if (s < 6) VLOAD(s + 2);          // stays in flight across barriers
        }

        // A fragments: [m-tile][k-chunk]; row = mt*32 + l31, k = kc*16 + kh*8
        s16x8 ah[2][2];
        #pragma unroll
        for (int mt = 0; mt < 2; ++mt) {
            #pragma unroll
            for (int kc = 0; kc < 2; ++kc) {
                const int ao = (mt * 32 + l31) * 36 + kc * 16 + kh * 8;
                union { uint2 q[2]; s16x8 v8; } Th;
                Th.q[0] = *(const uint2*)&Abuf[s & 1][ao];
                Th.q[1] = *(const uint2*)&Abuf[s & 1][ao + 4];
                ah[mt][kc] = Th.v8;
            }
        }

        #pragma unroll
        for (int kc = 0; kc < 2; ++kc) {
            const int n = w * 32 + l31;
            const s16x8 bh = *(const s16x8*)(g2h + (size_t)n * 256 + s * 32 + kc * 16 + kh * 8);
            acc[0] = __builtin_amdgcn_mfma_f32_32x32x16_bf16(ah[0][kc], bh, acc[0], 0, 0, 0);
            acc[1] = __builtin_amdgcn_mfma_f32_32x32x16_bf16(ah[1][kc], bh, acc[1], 0, 0, 0);
        }
    }
    #undef VLOAD
    #undef SPLITW
    #undef LDS_BARRIER

    const int slot = rest & 63;
    {
        float rm = -3.4e38f;
        #pragma unroll
        for (int r = 0; r < 16; ++r)
            rm = fmaxf(rm, fmaxf(acc[0][r], acc[1][r]));
        rm = fmaxf(rm, __shfl_xor(rm, 32, 64));   // merge row-halves (lane>>5)
        if (kh == 0) {
            const int col = w * 32 + l31;
            part[((size_t)cell * 64 + slot) * 256 + col] = rm + hb[col];
        }
    }
}

// ---------------------------------------------------------------------------
// Kernel 6: reduce 64 partial maxes per cell, final MLP (f32), L2 normalize.
// ---------------------------------------------------------------------------
__global__ __launch_bounds__(256)
void k_final(const float* __restrict__ part,
             const float* __restrict__ lW1, const float* __restrict__ lb1,
             const float* __restrict__ lW2, const float* __restrict__ lb2,
             float* __restrict__ out)
{
    __shared__ float pooled[256];
    __shared__ float hid[256];
    __shared__ float red[4];

    const int b = blockIdx.x;
    const int t = threadIdx.x;

    float m = -3.4e38f;
    for (int s = 0; s < 64; ++s)
        m = fmaxf(m, part[((size_t)b * 64 + s) * 256 + t]);
    pooled[t] = m;
    __syncthreads();

    float h = lb1[t];
    for (int k = 0; k < 256; k += 4) {
        #pragma unroll
        for (int kk = 0; kk < 4; ++kk)
            h += pooled[k + kk] * lW1[(k + kk) * 256 + t];
    }
    hid[t] = fmaxf(h, 0.f);
    __syncthreads();

    float o = lb2[t];
    for (int k = 0; k < 256; k += 4) {
        #pragma unroll
        for (int kk = 0; kk < 4; ++kk)
            o += hid[k + kk] * lW2[(k + kk) * 256 + t];
    }

    float ss = o * o;
    #pragma unroll
    for (int s = 32; s > 0; s >>= 1) ss += __shfl_down(ss, s, 64);
    if ((t & 63) == 0) red[t >> 6] = ss;
    __syncthreads();
    const float tot = red[0] + red[1] + red[2] + red[3];
    const float rn = 1.f / fmaxf(sqrtf(tot), 1e-12f);
    out[b * 256 + t] = o * rn;
}

// ---------------------------------------------------------------------------
extern "C" void kernel_launch(void* const* d_in, const int* in_sizes, int n_in,
                              void* d_out, int out_size, void* d_ws, size_t ws_size,
                              hipStream_t stream)
{
    (void)n_in; (void)out_size; (void)ws_size;

    const float* class_table = (const float*)d_in[0];
    const float* cW1 = (const float*)d_in[1];
    const float* cb1 = (const float*)d_in[2];
    const float* cW2 = (const float*)d_in[3];
    const float* cb2 = (const float*)d_in[4];
    const float* pW1 = (const float*)d_in[5];
    const float* pb1 = (const float*)d_in[6];
    const float* pW2 = (const float*)d_in[7];
    const float* pb2 = (const float*)d_in[8];
    const float* mW  = (const float*)d_in[9];
    const float* mb  = (const float*)d_in[10];
    const float* gW1 = (const float*)d_in[11];
    const float* gb1 = (const float*)d_in[12];
    const float* g_gamma = (const float*)d_in[13];
    const float* g_beta  = (const float*)d_in[14];
    const float* gW2 = (const float*)d_in[15];
    const float* gb2 = (const float*)d_in[16];
    const float* lW1 = (const float*)d_in[17];
    const float* lb1 = (const float*)d_in[18];
    const float* lW2 = (const float*)d_in[19];
    const float* lb2 = (const float*)d_in[20];
    const float* positions = (const float*)d_in[21];
    const float* colors    = (const float*)d_in[22];
    const int*  cls        = (const int*)d_in[23];

    const int cstride = (in_sizes[23] == 2 * NTOT) ? 2 : 1;

    // workspace layout (bytes), total ~174 MB (ws_size ~268 MB).
    char* base = (char*)d_ws;
    float*   part   = (float*)(base + 0);               //   4,194,304
    ushort*  Wdh    = (ushort*)(base + 4194304);
    ushort*  Wdl    = (ushort*)(base + 4325376);
    ushort*  Wbh    = (ushort*)(base + 4456448);
    ushort*  Wbl    = (ushort*)(base + 4587520);
    ushort*  g2h    = (ushort*)(base + 4718592);
    ushort*  g2l    = (ushort*)(base + 4849664);
    float*   hb     = (float*)(base + 4980736);
    ushort*  cW2Th  = (ushort*)(base + 4981760);
    ushort*  cW2Tl  = (ushort*)(base + 5014528);
    ushort*  pW2Th  = (ushort*)(base + 5047296);
    ushort*  pW2Tl  = (ushort*)(base + 5080064);
    ushort*  WcTh   = (ushort*)(base + 5112832);
    ushort*  WcTl   = (ushort*)(base + 5145600);
    ushort*  WpTh   = (ushort*)(base + 5178368);
    ushort*  WpTl   = (ushort*)(base + 5211136);
    float*   classMn= (float*)(base + 5243904);
    float*   cbM    = (float*)(base + 5275648);
    float*   pbM    = (float*)(base + 5276672);
    int*     nidx   = (int*)(base + 5277696);           //   1,048,576
    float*   sqn    = (float*)(base + 6326272);         //     131,072
    ushort*  ehi    = (ushort*)(base + 6457344);        //  16,777,216
    ushort*  elo    = (ushort*)(base + 23234560);       //  16,777,216
    float*   dist   = (float*)(base + 40011776);        //  67,108,864
    float*   v      = (float*)(base + 107120640);       //  33,554,432
    float*   u      = (float*)(base + 140675072);       //  33,554,432
    float* out = (float*)d_out;

    k_cvt<<<897, 256, 0, stream>>>(gW1, gW2, g_gamma, g_beta, gb2, cW2, pW2,
                                   Wdh, Wdl, Wbh, Wbl, g2h, g2l, hb,
                                   cW2Th, cW2Tl, pW2Th, pW2Tl);
    k_fold<<<130, 256, 0, stream>>>(cW2, pW2, cb2, pb2, mW,
                                    WcTh, WcTl, WpTh, WpTl, cbM, pbM);
    k_cls<<<31, 256, 0, stream>>>(class_table, mW, classMn);

    k_embed<<<NTOT / 16, 256, 0, stream>>>(classMn, cW1, cb1, cb2, pW1, pb1, pb2,
                                           mb, cW2Th, cW2Tl, pW2Th, pW2Tl,
                                           WcTh, WcTl, WpTh, WpTl, cbM, pbM,
                                           positions, colors, cls, cstride,
                                           ehi, elo, sqn);
    k_gram<<<NB * 16, 256, 0, stream>>>(ehi, elo, sqn, dist);
    k_select<<<NTOT / 4, 256, 0, stream>>>(dist, nidx);
    k_uv<<<2 * NTOT / 64, 256, 0, stream>>>(ehi, elo, Wdh, Wbh, gb1, u, v);
    k_edge<<<NTOT / 8, 512, 0, stream>>>(u, v, nidx, g2h, hb, part);
    k_final<<<NB, 256, 0, stream>>>(part, lW1, lb1, lW2, lb2, out);
}

// Round 13
// 404.858 us; speedup vs baseline: 1.1311x; 1.0310x over previous
//
#include <hip/hip_runtime.h>

#define EDIM 256
#define KNN 8
#define NB 64
#define NP 512
#define NTOT (NB * NP)

typedef short s16x8 __attribute__((ext_vector_type(8)));
typedef float f32x4 __attribute__((ext_vector_type(4)));
typedef float f32x16 __attribute__((ext_vector_type(16)));
typedef unsigned short ushort;

__device__ __forceinline__ ushort f2b(float f) {
    unsigned u = __float_as_uint(f);
    u = (u + 0x7fffu + ((u >> 16) & 1u)) >> 16;   // RNE
    return (ushort)u;
}
__device__ __forceinline__ float b2f(ushort h) {
    return __uint_as_float(((unsigned)h) << 16);
}
__device__ __forceinline__ void split2(float x, ushort& h, ushort& l) {
    h = f2b(x);
    l = f2b(x - b2f(h));
}

// async global->LDS, 16B per lane; lds dest is wave-uniform base + lane*16
__device__ __forceinline__ void gload16(const ushort* g, ushort* l) {
    __builtin_amdgcn_global_load_lds(
        (const __attribute__((address_space(1))) void*)g,
        (__attribute__((address_space(3))) void*)l, 16, 0, 0);
}

// ---------------------------------------------------------------------------
// Kernel 0: merged prep (cvt + fold + cls). The three phases are mutually
// independent (all read only original inputs) -> one launch, branch on bid.
// ---------------------------------------------------------------------------
__global__ __launch_bounds__(256)
void k_prep(const float* __restrict__ gW1, const float* __restrict__ gW2,
            const float* __restrict__ g_gamma, const float* __restrict__ g_beta,
            const float* __restrict__ gb2,
            const float* __restrict__ cW2, const float* __restrict__ pW2,
            const float* __restrict__ cb2, const float* __restrict__ pb2,
            const float* __restrict__ mW, const float* __restrict__ ct,
            ushort* __restrict__ Wdh, ushort* __restrict__ Wdl,
            ushort* __restrict__ Wbh, ushort* __restrict__ Wbl,
            ushort* __restrict__ g2h, ushort* __restrict__ g2l,
            float* __restrict__ hb,
            ushort* __restrict__ cW2Th, ushort* __restrict__ cW2Tl,
            ushort* __restrict__ pW2Th, ushort* __restrict__ pW2Tl,
            ushort* __restrict__ WcTh, ushort* __restrict__ WcTl,
            ushort* __restrict__ WpTh, ushort* __restrict__ WpTl,
            float* __restrict__ cbM, float* __restrict__ pbM,
            float* __restrict__ classMn)
{
    __shared__ float ctn[256];
    __shared__ float red[4];
    const int bid = blockIdx.x, t = threadIdx.x;
    ushort h, l;

    if (bid < 897) {                              // ---- cvt phase ----
        const int gid = bid * 256 + t;
        if (gid < 65536) {
            const int n = gid >> 8, k = gid & 255;
            split2(gW1[k * 256 + n] - gW1[(k + 256) * 256 + n], h, l);
            Wdh[gid] = h; Wdl[gid] = l;
        } else if (gid < 131072) {
            const int i = gid - 65536, n = i >> 8, k = i & 255;
            split2(gW1[(k + 256) * 256 + n], h, l);
            Wbh[i] = h; Wbl[i] = l;
        } else if (gid < 196608) {
            const int i = gid - 131072, n = i >> 8, k = i & 255;
            split2(g_gamma[k] * gW2[k * 256 + n], h, l);
            g2h[i] = h; g2l[i] = l;
        } else if (gid < 196864) {
            const int n = gid - 196608;
            float s = gb2[n];
            for (int k = 0; k < 256; ++k) s += g_beta[k] * gW2[k * 256 + n];
            hb[n] = s;
        } else if (gid < 213248) {
            const int i = gid - 196864, n = i >> 6, k = i & 63;
            split2(cW2[k * 256 + n], h, l);
            cW2Th[i] = h; cW2Tl[i] = l;
        } else if (gid < 229632) {
            const int i = gid - 213248, n = i >> 6, k = i & 63;
            split2(pW2[k * 256 + n], h, l);
            pW2Th[i] = h; pW2Tl[i] = l;
        }
        return;
    }
    if (bid < 1027) {                             // ---- fold phase ----
        const int gid = (bid - 897) * 256 + t;
        if (gid < 16384) {
            const int j = gid >> 8, n = gid & 255;
            float s = 0.f;
            for (int k = 0; k < 256; ++k) s += cW2[j * 256 + k] * mW[(256 + k) * 256 + n];
            split2(s, h, l);
            WcTh[n * 64 + j] = h; WcTl[n * 64 + j] = l;
        } else if (gid < 32768) {
            const int i = gid - 16384, j = i >> 8, n = i & 255;
            float s = 0.f;
            for (int k = 0; k < 256; ++k) s += pW2[j * 256 + k] * mW[(512 + k) * 256 + n];
            split2(s, h, l);
            WpTh[n * 64 + j] = h; WpTl[n * 64 + j] = l;
        } else if (gid < 33024) {
            const int n = gid - 32768;
            float s = 0.f;
            for (int k = 0; k < 256; ++k) s += cb2[k] * mW[(256 + k) * 256 + n];
            cbM[n] = s;
        } else if (gid < 33280) {
            const int n = gid - 33024;
            float s = 0.f;
            for (int k = 0; k < 256; ++k) s += pb2[k] * mW[(512 + k) * 256 + n];
            pbM[n] = s;
        }
        return;
    }
    {                                             // ---- cls phase ----
        const int c = bid - 1027;
        const float v = ct[c * 256 + t];
        float ss = v * v;
        #pragma unroll
        for (int s = 32; s > 0; s >>= 1) ss += __shfl_down(ss, s, 64);
        if ((t & 63) == 0) red[t >> 6] = ss;
        __syncthreads();
        const float tot = red[0] + red[1] + red[2] + red[3];
        const float r = 1.f / fmaxf(sqrtf(tot), 1e-12f);
        ctn[t] = v * r;
        __syncthreads();
        float s = 0.f;
        for (int k = 0; k < 256; ++k) s += ctn[k] * mW[k * 256 + t];
        classMn[c * 256 + t] = s;
    }
}

// ---------------------------------------------------------------------------
// Kernel 1: embeddings via folded GEMMs. 16 obj/block, full problem (2048).
// ---------------------------------------------------------------------------
__global__ __launch_bounds__(256)
void k_embed(const float* __restrict__ classMn,
             const float* __restrict__ cW1, const float* __restrict__ cb1,
             const float* __restrict__ cb2,
             const float* __restrict__ pW1, const float* __restrict__ pb1,
             const float* __restrict__ pb2,
             const float* __restrict__ mb,
             const ushort* __restrict__ cW2Th, const ushort* __restrict__ cW2Tl,
             const ushort* __restrict__ pW2Th, const ushort* __restrict__ pW2Tl,
             const ushort* __restrict__ WcTh, const ushort* __restrict__ WcTl,
             const ushort* __restrict__ WpTh, const ushort* __restrict__ WpTl,
             const float* __restrict__ cbM, const float* __restrict__ pbM,
             const float* __restrict__ positions, const float* __restrict__ colors,
             const int* __restrict__ cls, const int cstride,
             ushort* __restrict__ ehi, ushort* __restrict__ elo,
             float* __restrict__ sqn)
{
    __shared__ __align__(16) ushort Ahc[16 * 72];
    __shared__ __align__(16) ushort Alc[16 * 72];
    __shared__ __align__(16) ushort Ahp[16 * 72];
    __shared__ __align__(16) ushort Alp[16 * 72];
    __shared__ float sqc[16][4], sqp_[16][4], sqe[16][4];

    const int t = threadIdx.x, w = t >> 6, lane = t & 63;
    const int l15 = lane & 15, quad = lane >> 4;
    const int obase = blockIdx.x * 16;

    {
        const int o = lane >> 4;
        const int objl = w * 4 + o;
        const int gobj = obase + objl;
        const float c0 = colors[gobj * 3], c1 = colors[gobj * 3 + 1], c2 = colors[gobj * 3 + 2];
        const float q0 = positions[gobj * 3], q1 = positions[gobj * 3 + 1], q2 = positions[gobj * 3 + 2];
        const int u0 = (lane & 15) * 4;
        #pragma unroll
        for (int uu = 0; uu < 4; ++uu) {
            const int u = u0 + uu;
            const float hc = fmaxf(cb1[u] + c0 * cW1[u] + c1 * cW1[64 + u] + c2 * cW1[128 + u], 0.f);
            const float hp = fmaxf(pb1[u] + q0 * pW1[u] + q1 * pW1[64 + u] + q2 * pW1[128 + u], 0.f);
            ushort h, l;
            split2(hc, h, l); Ahc[objl * 72 + u] = h; Alc[objl * 72 + u] = l;
            split2(hp, h, l); Ahp[objl * 72 + u] = h; Alp[objl * 72 + u] = l;
        }
    }
    __syncthreads();

    f32x4 aco[4], ape[4];
    #pragma unroll
    for (int nt = 0; nt < 4; ++nt) { aco[nt] = (f32x4){0.f,0.f,0.f,0.f}; ape[nt] = (f32x4){0.f,0.f,0.f,0.f}; }

    #pragma unroll
    for (int kt = 0; kt < 2; ++kt) {
        const int ao = l15 * 72 + kt * 32 + quad * 8;
        const s16x8 ahc = *(const s16x8*)&Ahc[ao];
        const s16x8 alc = *(const s16x8*)&Alc[ao];
        const s16x8 ahp = *(const s16x8*)&Ahp[ao];
        const s16x8 alp = *(const s16x8*)&Alp[ao];
        #pragma unroll
        for (int nt = 0; nt < 4; ++nt) {
            const int n = w * 64 + nt * 16 + l15;
            const size_t bo = (size_t)n * 64 + kt * 32 + quad * 8;
            const s16x8 cbh = *(const s16x8*)(cW2Th + bo);
            const s16x8 cbl = *(const s16x8*)(cW2Tl + bo);
            const s16x8 pbh = *(const s16x8*)(pW2Th + bo);
            const s16x8 pbl = *(const s16x8*)(pW2Tl + bo);
            aco[nt] = __builtin_amdgcn_mfma_f32_16x16x32_bf16(ahc, cbh, aco[nt], 0, 0, 0);
            ape[nt] = __builtin_amdgcn_mfma_f32_16x16x32_bf16(ahp, pbh, ape[nt], 0, 0, 0);
            aco[nt] = __builtin_amdgcn_mfma_f32_16x16x32_bf16(alc, cbh, aco[nt], 0, 0, 0);
            ape[nt] = __builtin_amdgcn_mfma_f32_16x16x32_bf16(alp, pbh, ape[nt], 0, 0, 0);
            aco[nt] = __builtin_amdgcn_mfma_f32_16x16x32_bf16(ahc, cbl, aco[nt], 0, 0, 0);
            ape[nt] = __builtin_amdgcn_mfma_f32_16x16x32_bf16(ahp, pbl, ape[nt], 0, 0, 0);
        }
    }

    float sc[4] = {0.f,0.f,0.f,0.f}, sp[4] = {0.f,0.f,0.f,0.f};
    #pragma unroll
    for (int nt = 0; nt < 4; ++nt) {
        const int col = w * 64 + nt * 16 + l15;
        const float cbv = cb2[col], pbv = pb2[col];
        #pragma unroll
        for (int r = 0; r < 4; ++r) {
            const float co = aco[nt][r] + cbv;
            const float pe = ape[nt][r] + pbv;
            sc[r] += co * co;
            sp[r] += pe * pe;
        }
    }
    #pragma unroll
    for (int s = 8; s > 0; s >>= 1) {
        #pragma unroll
        for (int r = 0; r < 4; ++r) {
            sc[r] += __shfl_xor(sc[r], s, 64);
            sp[r] += __shfl_xor(sp[r], s, 64);
        }
    }
    if (l15 == 0) {
        #pragma unroll
        for (int r = 0; r < 4; ++r) { sqc[quad * 4 + r][w] = sc[r]; sqp_[quad * 4 + r][w] = sp[r]; }
    }
    __syncthreads();

    float rco[4], rpe[4];
    #pragma unroll
    for (int r = 0; r < 4; ++r) {
        const int row = quad * 4 + r;
        rco[r] = 1.f / fmaxf(sqrtf(sqc[row][0] + sqc[row][1] + sqc[row][2] + sqc[row][3]), 1e-12f);
        rpe[r] = 1.f / fmaxf(sqrtf(sqp_[row][0] + sqp_[row][1] + sqp_[row][2] + sqp_[row][3]), 1e-12f);
    }

    f32x4 ac[4], ap[4];
    #pragma unroll
    for (int nt = 0; nt < 4; ++nt) { ac[nt] = (f32x4){0.f,0.f,0.f,0.f}; ap[nt] = (f32x4){0.f,0.f,0.f,0.f}; }

    #pragma unroll
    for (int kt = 0; kt < 2; ++kt) {
        const int ao = l15 * 72 + kt * 32 + quad * 8;
        const s16x8 ahc = *(const s16x8*)&Ahc[ao];
        const s16x8 alc = *(const s16x8*)&Alc[ao];
        const s16x8 ahp = *(const s16x8*)&Ahp[ao];
        const s16x8 alp = *(const s16x8*)&Alp[ao];
        #pragma unroll
        for (int nt = 0; nt < 4; ++nt) {
            const int n = w * 64 + nt * 16 + l15;
            const size_t bo = (size_t)n * 64 + kt * 32 + quad * 8;
            const s16x8 cbh = *(const s16x8*)(WcTh + bo);
            const s16x8 cbl = *(const s16x8*)(WcTl + bo);
            const s16x8 pbh = *(const s16x8*)(WpTh + bo);
            const s16x8 pbl = *(const s16x8*)(WpTl + bo);
            ac[nt] = __builtin_amdgcn_mfma_f32_16x16x32_bf16(ahc, cbh, ac[nt], 0, 0, 0);
            ap[nt] = __builtin_amdgcn_mfma_f32_16x16x32_bf16(ahp, pbh, ap[nt], 0, 0, 0);
            ac[nt] = __builtin_amdgcn_mfma_f32_16x16x32_bf16(alc, cbh, ac[nt], 0, 0, 0);
            ap[nt] = __builtin_amdgcn_mfma_f32_16x16x32_bf16(alp, pbh, ap[nt], 0, 0, 0);
            ac[nt] = __builtin_amdgcn_mfma_f32_16x16x32_bf16(ahc, cbl, ac[nt], 0, 0, 0);
            ap[nt] = __builtin_amdgcn_mfma_f32_16x16x32_bf16(ahp, pbl, ap[nt], 0, 0, 0);
        }
    }

    int ci[4];
    #pragma unroll
    for (int r = 0; r < 4; ++r) {
        const int gobj = obase + quad * 4 + r;
        int c = cls[(size_t)gobj * cstride];
        if ((unsigned)c > 30u) c = 0;
        ci[r] = c;
    }

    float rp[4] = {0.f,0.f,0.f,0.f};
    #pragma unroll
    for (int nt = 0; nt < 4; ++nt) {
        const int col = w * 64 + nt * 16 + l15;
        const float mbv = mb[col], cbMv = cbM[col], pbMv = pbM[col];
        #pragma unroll
        for (int r = 0; r < 4; ++r) {
            const int row = quad * 4 + r;
            const float e = classMn[ci[r] * 256 + col]
                          + rco[r] * (ac[nt][r] + cbMv)
                          + rpe[r] * (ap[nt][r] + pbMv) + mbv;
            ushort h, l;
            split2(e, h, l);
            ehi[(size_t)(obase + row) * 256 + col] = h;
            elo[(size_t)(obase + row) * 256 + col] = l;
            rp[r] += e * e;
        }
    }
    #pragma unroll
    for (int s = 8; s > 0; s >>= 1) {
        #pragma unroll
        for (int r = 0; r < 4; ++r) rp[r] += __shfl_xor(rp[r], s, 64);
    }
    if (l15 == 0) {
        #pragma unroll
        for (int r = 0; r < 4; ++r) sqe[quad * 4 + r][w] = rp[r];
    }
    __syncthreads();
    if (t < 16) sqn[obase + t] = sqe[t][0] + sqe[t][1] + sqe[t][2] + sqe[t][3];
}

// ---------------------------------------------------------------------------
// Kernel 2: Gram/distance, UPPER-TRIANGLE ONLY (10 tiles/cell instead of 16,
// -37.5% GEMM work). Off-diagonal tiles mirror-write dist[q][p] via an LDS
// transpose reusing the 64KB staging buffer (dead after the k-loop); XOR
// swizzle col^((row&7)<<4) keeps stores <=8-way and f32x4 mirror reads
// conflict-free; mirror global writes coalesced. Mirror values differ from
// the old lower-tile computation only in f32 last-ULP accumulation order.
// ---------------------------------------------------------------------------
__global__ __launch_bounds__(256)
void k_gram(const ushort* __restrict__ ehi, const ushort* __restrict__ elo,
            const float* __restrict__ sqn, float* __restrict__ dist)
{
    // [dbuf][Ah,Al,Bh,Bl][128 rows * 32 k], 64 KB; reused as f32[128][128]
    __shared__ __align__(16) ushort lds[2][4][4096];

    const int t = threadIdx.x, w = t >> 6, lane = t & 63;
    const int l15 = lane & 15, quad = lane >> 4;
    const int b = blockIdx.x;
    const int xcd = b & 7, rest = b >> 3;        // rest 0..79
    const int cell = xcd * 8 + rest / 10;        // 0..63
    const int tt = rest % 10;
    // upper-triangle enumeration: (0,0)(0,1)(0,2)(0,3)(1,1)(1,2)(1,3)(2,2)(2,3)(3,3)
    const int ti = (tt < 4) ? 0 : (tt < 7) ? 1 : (tt < 9) ? 2 : 3;
    const int tbase = (ti == 0) ? 0 : (ti == 1) ? 4 : (ti == 2) ? 7 : 9;
    const int tj = ti + (tt - tbase);
    const int p0 = ti * 128, q0 = tj * 128;
    const size_t cb = (size_t)cell * NP;
    const int diag = (ti == tj);
    const int wr = w >> 1, wc = w & 1;           // 2x2 wave grid, 64x64 each

    int srow[2], scol[2];
    #pragma unroll
    for (int i = 0; i < 2; ++i) {
        const int p = (w * 2 + i) * 64 + lane;
        const int row = p >> 2;
        srow[i] = row;
        scol[i] = ((p & 3) ^ ((row >> 1) & 3)) * 8;   // ushort offset of 16B chunk
    }

    #define STAGE(KT, D)                                                         \
    {                                                                            \
        const int kb_ = (KT) * 32;                                               \
        _Pragma("unroll")                                                        \
        for (int i = 0; i < 2; ++i) {                                            \
            const int ls_ = (w * 2 + i) * 512;   /* slot*8 ushorts */            \
            const size_t ga_ = (cb + p0 + srow[i]) * 256 + kb_ + scol[i];        \
            gload16(ehi + ga_, &lds[D][0][ls_]);                                 \
            gload16(elo + ga_, &lds[D][1][ls_]);                                 \
            if (!diag) {                                                         \
                const size_t gq_ = (cb + q0 + srow[i]) * 256 + kb_ + scol[i];    \
                gload16(ehi + gq_, &lds[D][2][ls_]);                             \
                gload16(elo + gq_, &lds[D][3][ls_]);                             \
            }                                                                    \
        }                                                                        \
    }

    f32x4 acc[4][4];
    #pragma unroll
    for (int mt = 0; mt < 4; ++mt)
        #pragma unroll
        for (int nt = 0; nt < 4; ++nt) acc[mt][nt] = (f32x4){0.f, 0.f, 0.f, 0.f};

    const int bB = diag ? 0 : 2;

    STAGE(0, 0);
    __syncthreads();

    for (int kt = 0; kt < 8; ++kt) {
        const int cur = kt & 1;
        if (kt < 7) STAGE(kt + 1, cur ^ 1);      // prefetch next k-slice

        s16x8 ah[4], al[4];
        #pragma unroll
        for (int mt = 0; mt < 4; ++mt) {
            const int r = wr * 64 + mt * 16 + l15;
            const int slot = 4 * r + (quad ^ ((r >> 1) & 3));
            ah[mt] = *(const s16x8*)&lds[cur][0][slot * 8];
            al[mt] = *(const s16x8*)&lds[cur][1][slot * 8];
        }
        #pragma unroll
        for (int nt = 0; nt < 4; ++nt) {
            const int rq = wc * 64 + nt * 16 + l15;
            const int slot = 4 * rq + (quad ^ ((rq >> 1) & 3));
            const s16x8 bh = *(const s16x8*)&lds[cur][bB][slot * 8];
            const s16x8 bl = *(const s16x8*)&lds[cur][bB + 1][slot * 8];
            #pragma unroll
            for (int mt = 0; mt < 4; ++mt) {
                acc[mt][nt] = __builtin_amdgcn_mfma_f32_16x16x32_bf16(ah[mt], bh, acc[mt][nt], 0, 0, 0);
                acc[mt][nt] = __builtin_amdgcn_mfma_f32_16x16x32_bf16(al[mt], bh, acc[mt][nt], 0, 0, 0);
                acc[mt][nt] = __builtin_amdgcn_mfma_f32_16x16x32_bf16(ah[mt], bl, acc[mt][nt], 0, 0, 0);
            }
        }
        __syncthreads();                          // drains vmcnt(0) -> buf ready
    }
    #undef STAGE

    float sqp[4][4];
    #pragma unroll
    for (int mt = 0; mt < 4; ++mt)
        #pragma unroll
        for (int r = 0; r < 4; ++r)
            sqp[mt][r] = sqn[cb + p0 + wr * 64 + mt * 16 + quad * 4 + r];

    float* T = (float*)&lds[0][0][0];            // 128x128 f32 transpose buffer

    #pragma unroll
    for (int nt = 0; nt < 4; ++nt) {
        const int cq_l = wc * 64 + nt * 16 + l15;
        const int colq = q0 + cq_l;
        const float sq_q = sqn[cb + colq];
        #pragma unroll
        for (int mt = 0; mt < 4; ++mt) {
            #pragma unroll
            for (int r = 0; r < 4; ++r) {
                const int rp_l = wr * 64 + mt * 16 + quad * 4 + r;
                const float d = (sqp[mt][r] + sq_q) - 2.f * acc[mt][nt][r];
                __builtin_nontemporal_store(d, &dist[(cb + p0 + rp_l) * NP + colq]);
                if (!diag) T[cq_l * 128 + (rp_l ^ ((cq_l & 7) << 4))] = d;
            }
        }
    }

    if (!diag) {                                  // mirror block (rows q, cols p)
        __syncthreads();
        const int l31 = t & 31, rbase = t >> 5;   // 8 row-groups x 16 iters
        #pragma unroll
        for (int i = 0; i < 16; ++i) {
            const int row = rbase + i * 8;        // q_local
            const int p4 = l31 * 4;
            const f32x4 vv = *(const f32x4*)&T[row * 128 + (p4 ^ ((row & 7) << 4))];
            __builtin_nontemporal_store(vv, (f32x4*)&dist[(cb + q0 + row) * NP + p0 + p4]);
        }
    }
}

// ---------------------------------------------------------------------------
// Kernel 3: top-8 smallest per point (ties -> lowest index). One wave/point.
// ---------------------------------------------------------------------------
__global__ __launch_bounds__(256)
void k_select(const float* __restrict__ dist, int* __restrict__ nidx)
{
    const int wv = threadIdx.x >> 6, lane = threadIdx.x & 63;
    const int xcd = blockIdx.x & 7, rest = blockIdx.x >> 3;   // rest 0..1023
    const int cell = xcd * 8 + (rest >> 7);                   // 0..63
    const int p = cell * NP + (rest & 127) * 4 + wv;          // global point
    const float* row = dist + (size_t)p * NP;

    float d[8];
    {
        const float4 va = *(const float4*)(row + lane * 8);
        const float4 vb = *(const float4*)(row + lane * 8 + 4);
        d[0] = va.x; d[1] = va.y; d[2] = va.z; d[3] = va.w;
        d[4] = vb.x; d[5] = vb.y; d[6] = vb.z; d[7] = vb.w;
    }

    for (int r = 0; r < KNN; ++r) {
        float bd = d[0]; int bi = 0;
        #pragma unroll
        for (int i = 1; i < 8; ++i)
            if (d[i] < bd) { bd = d[i]; bi = i; }   // strict < keeps lowest i on tie
        int bq = lane * 8 + bi;
        #pragma unroll
        for (int s = 32; s > 0; s >>= 1) {
            const float od = __shfl_down(bd, s, 64);
            const int oq = __shfl_down(bq, s, 64);
            if (od < bd || (od == bd && oq < bq)) { bd = od; bq = oq; }
        }
        const int win = __shfl(bq, 0, 64);
        if (lane == 0) nidx[(size_t)p * KNN + r] = ((p >> 9) << 9) | win;
        if ((win >> 3) == lane) {
            const int wi = win & 7;
            #pragma unroll
            for (int i = 0; i < 8; ++i) if (wi == i) d[i] = 3.4e38f;
        }
    }
}

// ---------------------------------------------------------------------------
// Kernel 4: u = x@Wd+gb1, v = x@Wb. Single-pass A (hi only), LDS-staged via
// global_load_lds width-16 with XOR chunk-swizzle. B (Wh) direct.
// ---------------------------------------------------------------------------
__global__ __launch_bounds__(256)
void k_uv(const ushort* __restrict__ ehi, const ushort* __restrict__ elo,
          const ushort* __restrict__ Wdh, const ushort* __restrict__ Wbh,
          const float* __restrict__ gb1,
          float* __restrict__ u, float* __restrict__ v)
{
    (void)elo;
    __shared__ __align__(16) ushort lds[2][2048];   // [dbuf][slot*8] hi only, 8 KB

    const int t = threadIdx.x, w = t >> 6, lane = t & 63;
    const int l15 = lane & 15, quad = lane >> 4;
    const int isV = blockIdx.x >> 9;           // 1024 blocks total
    const int m0 = (blockIdx.x & 511) * 64;
    const ushort* Wh = isV ? Wbh : Wdh;
    float* out = isV ? v : u;
    const int mh = w & 1, ch = w >> 1;

    const int sp = w * 64 + lane;
    const int srow = sp >> 2;
    const int scol = ((sp & 3) ^ ((srow >> 1) & 3)) * 8;   // ushort offset

    #define STAGE_UV(S, D)                                                       \
    {                                                                            \
        const size_t ga_ = (size_t)(m0 + srow) * 256 + (S) * 32 + scol;          \
        gload16(ehi + ga_, &lds[D][sp * 8]);                                     \
    }

    const int r0 = mh * 32 + l15, r1 = r0 + 16;
    const int slot0 = 4 * r0 + (quad ^ ((r0 >> 1) & 3));
    const int slot1 = 4 * r1 + (quad ^ ((r1 >> 1) & 3));

    f32x4 acc[2][8];
    #pragma unroll
    for (int mt = 0; mt < 2; ++mt)
        #pragma unroll
        for (int nt = 0; nt < 8; ++nt) acc[mt][nt] = (f32x4){0.f, 0.f, 0.f, 0.f};

    STAGE_UV(0, 0);
    __syncthreads();

    for (int s = 0; s < 8; ++s) {
        const int cur = s & 1;
        if (s < 7) STAGE_UV(s + 1, cur ^ 1);   // prefetch next k-slice

        const s16x8 ah0 = *(const s16x8*)&lds[cur][slot0 * 8];
        const s16x8 ah1 = *(const s16x8*)&lds[cur][slot1 * 8];
        #pragma unroll
        for (int nt = 0; nt < 8; ++nt) {
            const int n = ch * 128 + nt * 16 + l15;
            const size_t bo = (size_t)n * 256 + s * 32 + quad * 8;
            const s16x8 bh = *(const s16x8*)(Wh + bo);
            acc[0][nt] = __builtin_amdgcn_mfma_f32_16x16x32_bf16(ah0, bh, acc[0][nt], 0, 0, 0);
            acc[1][nt] = __builtin_amdgcn_mfma_f32_16x16x32_bf16(ah1, bh, acc[1][nt], 0, 0, 0);
        }
        __syncthreads();                        // drains vmcnt(0) -> buf ready
    }
    #undef STAGE_UV

    #pragma unroll
    for (int mt = 0; mt < 2; ++mt) {
        #pragma unroll
        for (int nt = 0; nt < 8; ++nt) {
            const int col = ch * 128 + nt * 16 + l15;
            const float bias = isV ? 0.f : gb1[col];
            #pragma unroll
            for (int r = 0; r < 4; ++r) {
                const int row = mh * 32 + mt * 16 + quad * 4 + r;
                out[(size_t)(m0 + row) * 256 + col] = acc[mt][nt][r] + bias;
            }
        }
    }
}

// ---------------------------------------------------------------------------
// Kernel 5: edge GEMM + max aggregation. Single-pass RNE A, 512-thread /
// 8-wave structure (occupancy ~80%): wave w owns cols w*32..+31, acc = 2 x
// f32x16 = 32 AGPR. LDS-only inner barrier keeps v loads in flight.
// BYTE-IDENTICAL to the passing R11 version.
// ---------------------------------------------------------------------------
__global__ __launch_bounds__(512)
void k_edge(const float* __restrict__ u, const float* __restrict__ v,
            const int* __restrict__ nidx,
            const ushort* __restrict__ g2h,
            const float* __restrict__ hb,
            float* __restrict__ part)
{
    __shared__ ushort Abuf[2][2304];      // [dbuf][edge*36+k] hi only, 9.2 KB
    __shared__ float ustage[2048];        // 8 pts x 256 k, 8 KB

    const int t = threadIdx.x, w = t >> 6, lane = t & 63;
    const int l31 = lane & 31, kh = lane >> 5;

    const int b = blockIdx.x;
    const int xcd = b & 7, rest = b >> 3;        // rest 0..511
    const int cell = xcd * 8 + (rest >> 6);      // 0..63
    const int pl0 = cell * NP + (rest & 63) * 8;

    // stage u rows once (coalesced, 4 floats per thread x 512 threads)
    {
        const int pt = t >> 6, kk = (t & 63) * 4;
        *(float4*)&ustage[pt * 256 + kk] = *(const float4*)(u + (size_t)(pl0 + pt) * 256 + kk);
    }

    const int se = t >> 3, kq = t & 7;           // edge 0..63, k-quad 0..7 (4 k each)
    const int upt = se >> 3;                     // point within block
    int svrow = nidx[(size_t)(pl0 + upt) * KNN + (se & 7)];
    if ((unsigned)svrow >= (unsigned)NTOT) svrow = 0;

    __syncthreads();                             // ustage visible (one-time)

    float4 vr[2];                                // 2-set v pipeline (4 floats/thread)

    #define VLOAD(S)                                                             \
    {                                                                            \
        const int k0 = (S) * 32 + kq * 4;                                        \
        vr[(S) & 1] = *(const float4*)(v + (size_t)svrow * 256 + k0);            \
    }
    #define SPLITW(S, BUF)                                                       \
    {                                                                            \
        const int k0u = (S) * 32 + kq * 4;                                       \
        const float4 ua = *(const float4*)&ustage[upt * 256 + k0u];              \
        const float4 va = vr[(S) & 1];                                           \
        const float sv[4] = {                                                    \
            fmaxf(ua.x + va.x, 0.f), fmaxf(ua.y + va.y, 0.f),                    \
            fmaxf(ua.z + va.z, 0.f), fmaxf(ua.w + va.w, 0.f)};                   \
        union { uint2 q; ushort us[4]; } th;                                     \
        _Pragma("unroll")                                                        \
        for (int j = 0; j < 4; ++j) { th.us[j] = f2b(sv[j]); }                   \
        *(uint2*)&Abuf[BUF][se * 36 + kq * 4] = th.q;                            \
    }

    #define LDS_BARRIER()                                                        \
    {                                                                            \
        asm volatile("s_waitcnt lgkmcnt(0)" ::: "memory");                       \
        __builtin_amdgcn_s_barrier();                                            \
    }

    f32x16 acc[2];
    acc[0] = (f32x16)(0.0f);
    acc[1] = (f32x16)(0.0f);

    VLOAD(0); VLOAD(1);
    SPLITW(0, 0);

    #pragma unroll
    for (int s = 0; s < 8; ++s) {
        LDS_BARRIER();                        // buf[s&1] visible; buf[(s+1)&1] readers done
        if (s < 7) {
            SPLITW(s + 1, (s + 1) & 1);       // u from LDS, v register-resident
            if (s < 6) VLOAD(s + 2);          // stays in flight across barriers
        }

        s16x8 ah[2][2];
        #pragma unroll
        for (int mt = 0; mt < 2; ++mt) {
            #pragma unroll
            for (int kc = 0; kc < 2; ++kc) {
                const int ao = (mt * 32 + l31) * 36 + kc * 16 + kh * 8;
                union { uint2 q[2]; s16x8 v8; } Th;
                Th.q[0] = *(const uint2*)&Abuf[s & 1][ao];
                Th.q[1] = *(const uint2*)&Abuf[s & 1][ao + 4];
                ah[mt][kc] = Th.v8;
            }
        }

        #pragma unroll
        for (int kc = 0; kc < 2; ++kc) {
            const int n = w * 32 + l31;
            const s16x8 bh = *(const s16x8*)(g2h + (size_t)n * 256 + s * 32 + kc * 16 + kh * 8);
            acc[0] = __builtin_amdgcn_mfma_f32_32x32x16_bf16(ah[0][kc], bh, acc[0], 0, 0, 0);
            acc[1] = __builtin_amdgcn_mfma_f32_32x32x16_bf16(ah[1][kc], bh, acc[1], 0, 0, 0);
        }
    }
    #undef VLOAD
    #undef SPLITW
    #undef LDS_BARRIER

    const int slot = rest & 63;
    {
        float rm = -3.4e38f;
        #pragma unroll
        for (int r = 0; r < 16; ++r)
            rm = fmaxf(rm, fmaxf(acc[0][r], acc[1][r]));
        rm = fmaxf(rm, __shfl_xor(rm, 32, 64));   // merge row-halves (lane>>5)
        if (kh == 0) {
            const int col = w * 32 + l31;
            part[((size_t)cell * 64 + slot) * 256 + col] = rm + hb[col];
        }
    }
}

// ---------------------------------------------------------------------------
// Kernel 6: reduce 64 partial maxes per cell, final MLP (f32), L2 normalize.
// ---------------------------------------------------------------------------
__global__ __launch_bounds__(256)
void k_final(const float* __restrict__ part,
             const float* __restrict__ lW1, const float* __restrict__ lb1,
             const float* __restrict__ lW2, const float* __restrict__ lb2,
             float* __restrict__ out)
{
    __shared__ float pooled[256];
    __shared__ float hid[256];
    __shared__ float red[4];

    const int b = blockIdx.x;
    const int t = threadIdx.x;

    float m = -3.4e38f;
    for (int s = 0; s < 64; ++s)
        m = fmaxf(m, part[((size_t)b * 64 + s) * 256 + t]);
    pooled[t] = m;
    __syncthreads();

    float h = lb1[t];
    for (int k = 0; k < 256; k += 4) {
        #pragma unroll
        for (int kk = 0; kk < 4; ++kk)
            h += pooled[k + kk] * lW1[(k + kk) * 256 + t];
    }
    hid[t] = fmaxf(h, 0.f);
    __syncthreads();

    float o = lb2[t];
    for (int k = 0; k < 256; k += 4) {
        #pragma unroll
        for (int kk = 0; kk < 4; ++kk)
            o += hid[k + kk] * lW2[(k + kk) * 256 + t];
    }

    float ss = o * o;
    #pragma unroll
    for (int s = 32; s > 0; s >>= 1) ss += __shfl_down(ss, s, 64);
    if ((t & 63) == 0) red[t >> 6] = ss;
    __syncthreads();
    const float tot = red[0] + red[1] + red[2] + red[3];
    const float rn = 1.f / fmaxf(sqrtf(tot), 1e-12f);
    out[b * 256 + t] = o * rn;
}

// ---------------------------------------------------------------------------
extern "C" void kernel_launch(void* const* d_in, const int* in_sizes, int n_in,
                              void* d_out, int out_size, void* d_ws, size_t ws_size,
                              hipStream_t stream)
{
    (void)n_in; (void)out_size; (void)ws_size;

    const float* class_table = (const float*)d_in[0];
    const float* cW1 = (const float*)d_in[1];
    const float* cb1 = (const float*)d_in[2];
    const float* cW2 = (const float*)d_in[3];
    const float* cb2 = (const float*)d_in[4];
    const float* pW1 = (const float*)d_in[5];
    const float* pb1 = (const float*)d_in[6];
    const float* pW2 = (const float*)d_in[7];
    const float* pb2 = (const float*)d_in[8];
    const float* mW  = (const float*)d_in[9];
    const float* mb  = (const float*)d_in[10];
    const float* gW1 = (const float*)d_in[11];
    const float* gb1 = (const float*)d_in[12];
    const float* g_gamma = (const float*)d_in[13];
    const float* g_beta  = (const float*)d_in[14];
    const float* gW2 = (const float*)d_in[15];
    const float* gb2 = (const float*)d_in[16];
    const float* lW1 = (const float*)d_in[17];
    const float* lb1 = (const float*)d_in[18];
    const float* lW2 = (const float*)d_in[19];
    const float* lb2 = (const float*)d_in[20];
    const float* positions = (const float*)d_in[21];
    const float* colors    = (const float*)d_in[22];
    const int*  cls        = (const int*)d_in[23];

    const int cstride = (in_sizes[23] == 2 * NTOT) ? 2 : 1;

    // workspace layout (bytes), total ~174 MB (ws_size ~268 MB).
    char* base = (char*)d_ws;
    float*   part   = (float*)(base + 0);               //   4,194,304
    ushort*  Wdh    = (ushort*)(base + 4194304);
    ushort*  Wdl    = (ushort*)(base + 4325376);
    ushort*  Wbh    = (ushort*)(base + 4456448);
    ushort*  Wbl    = (ushort*)(base + 4587520);
    ushort*  g2h    = (ushort*)(base + 4718592);
    ushort*  g2l    = (ushort*)(base + 4849664);
    float*   hb     = (float*)(base + 4980736);
    ushort*  cW2Th  = (ushort*)(base + 4981760);
    ushort*  cW2Tl  = (ushort*)(base + 5014528);
    ushort*  pW2Th  = (ushort*)(base + 5047296);
    ushort*  pW2Tl  = (ushort*)(base + 5080064);
    ushort*  WcTh   = (ushort*)(base + 5112832);
    ushort*  WcTl   = (ushort*)(base + 5145600);
    ushort*  WpTh   = (ushort*)(base + 5178368);
    ushort*  WpTl   = (ushort*)(base + 5211136);
    float*   classMn= (float*)(base + 5243904);
    float*   cbM    = (float*)(base + 5275648);
    float*   pbM    = (float*)(base + 5276672);
    int*     nidx   = (int*)(base + 5277696);           //   1,048,576
    float*   sqn    = (float*)(base + 6326272);         //     131,072
    ushort*  ehi    = (ushort*)(base + 6457344);        //  16,777,216
    ushort*  elo    = (ushort*)(base + 23234560);       //  16,777,216
    float*   dist   = (float*)(base + 40011776);        //  67,108,864
    float*   v      = (float*)(base + 107120640);       //  33,554,432
    float*   u      = (float*)(base + 140675072);       //  33,554,432
    float* out = (float*)d_out;

    k_prep<<<1058, 256, 0, stream>>>(gW1, gW2, g_gamma, g_beta, gb2, cW2, pW2,
                                     cb2, pb2, mW, class_table,
                                     Wdh, Wdl, Wbh, Wbl, g2h, g2l, hb,
                                     cW2Th, cW2Tl, pW2Th, pW2Tl,
                                     WcTh, WcTl, WpTh, WpTl, cbM, pbM, classMn);

    k_embed<<<NTOT / 16, 256, 0, stream>>>(classMn, cW1, cb1, cb2, pW1, pb1, pb2,
                                           mb, cW2Th, cW2Tl, pW2Th, pW2Tl,
                                           WcTh, WcTl, WpTh, WpTl, cbM, pbM,
                                           positions, colors, cls, cstride,
                                           ehi, elo, sqn);
    k_gram<<<NB * 10, 256, 0, stream>>>(ehi, elo, sqn, dist);
    k_select<<<NTOT / 4, 256, 0, stream>>>(dist, nidx);
    k_uv<<<2 * NTOT / 64, 256, 0, stream>>>(ehi, elo, Wdh, Wbh, gb1, u, v);
    k_edge<<<NTOT / 8, 512, 0, stream>>>(u, v, nidx, g2h, hb, part);
    k_final<<<NB, 256, 0, stream>>>(part, lW1, lb1, lW2, lb2, out);
}

// Round 15
// 404.014 us; speedup vs baseline: 1.1335x; 1.0021x over previous
//
#include <hip/hip_runtime.h>

#define EDIM 256
#define KNN 8
#define NB 64
#define NP 512
#define NTOT (NB * NP)

typedef short s16x8 __attribute__((ext_vector_type(8)));
typedef float f32x4 __attribute__((ext_vector_type(4)));
typedef float f32x16 __attribute__((ext_vector_type(16)));
typedef unsigned short ushort;
typedef unsigned long long u64;

__device__ __forceinline__ ushort f2b(float f) {
    unsigned u = __float_as_uint(f);
    u = (u + 0x7fffu + ((u >> 16) & 1u)) >> 16;   // RNE
    return (ushort)u;
}
__device__ __forceinline__ float b2f(ushort h) {
    return __uint_as_float(((unsigned)h) << 16);
}
__device__ __forceinline__ void split2(float x, ushort& h, ushort& l) {
    h = f2b(x);
    l = f2b(x - b2f(h));
}

// monotone float->uint map: ascending float order == ascending uint order
__device__ __forceinline__ unsigned fkey(float f) {
    const unsigned b = __float_as_uint(f);
    return (b & 0x80000000u) ? ~b : (b | 0x80000000u);
}

// branchless sorted-ascending top-8 insert (k[0] smallest)
__device__ __forceinline__ void ins8(u64* k, u64 x) {
    #pragma unroll
    for (int j = 7; j >= 1; --j)
        k[j] = (x < k[j - 1]) ? k[j - 1] : ((x < k[j]) ? x : k[j]);
    k[0] = (x < k[0]) ? x : k[0];
}

// async global->LDS, 16B per lane; lds dest is wave-uniform base + lane*16
__device__ __forceinline__ void gload16(const ushort* g, ushort* l) {
    __builtin_amdgcn_global_load_lds(
        (const __attribute__((address_space(1))) void*)g,
        (__attribute__((address_space(3))) void*)l, 16, 0, 0);
}

// ---------------------------------------------------------------------------
// Kernel 0: merged prep (cvt + fold + cls). The three phases are mutually
// independent (all read only original inputs) -> one launch, branch on bid.
// ---------------------------------------------------------------------------
__global__ __launch_bounds__(256)
void k_prep(const float* __restrict__ gW1, const float* __restrict__ gW2,
            const float* __restrict__ g_gamma, const float* __restrict__ g_beta,
            const float* __restrict__ gb2,
            const float* __restrict__ cW2, const float* __restrict__ pW2,
            const float* __restrict__ cb2, const float* __restrict__ pb2,
            const float* __restrict__ mW, const float* __restrict__ ct,
            ushort* __restrict__ Wdh, ushort* __restrict__ Wdl,
            ushort* __restrict__ Wbh, ushort* __restrict__ Wbl,
            ushort* __restrict__ g2h, ushort* __restrict__ g2l,
            float* __restrict__ hb,
            ushort* __restrict__ cW2Th, ushort* __restrict__ cW2Tl,
            ushort* __restrict__ pW2Th, ushort* __restrict__ pW2Tl,
            ushort* __restrict__ WcTh, ushort* __restrict__ WcTl,
            ushort* __restrict__ WpTh, ushort* __restrict__ WpTl,
            float* __restrict__ cbM, float* __restrict__ pbM,
            float* __restrict__ classMn)
{
    __shared__ float ctn[256];
    __shared__ float red[4];
    const int bid = blockIdx.x, t = threadIdx.x;
    ushort h, l;

    if (bid < 897) {                              // ---- cvt phase ----
        const int gid = bid * 256 + t;
        if (gid < 65536) {
            const int n = gid >> 8, k = gid & 255;
            split2(gW1[k * 256 + n] - gW1[(k + 256) * 256 + n], h, l);
            Wdh[gid] = h; Wdl[gid] = l;
        } else if (gid < 131072) {
            const int i = gid - 65536, n = i >> 8, k = i & 255;
            split2(gW1[(k + 256) * 256 + n], h, l);
            Wbh[i] = h; Wbl[i] = l;
        } else if (gid < 196608) {
            const int i = gid - 131072, n = i >> 8, k = i & 255;
            split2(g_gamma[k] * gW2[k * 256 + n], h, l);
            g2h[i] = h; g2l[i] = l;
        } else if (gid < 196864) {
            const int n = gid - 196608;
            float s = gb2[n];
            for (int k = 0; k < 256; ++k) s += g_beta[k] * gW2[k * 256 + n];
            hb[n] = s;
        } else if (gid < 213248) {
            const int i = gid - 196864, n = i >> 6, k = i & 63;
            split2(cW2[k * 256 + n], h, l);
            cW2Th[i] = h; cW2Tl[i] = l;
        } else if (gid < 229632) {
            const int i = gid - 213248, n = i >> 6, k = i & 63;
            split2(pW2[k * 256 + n], h, l);
            pW2Th[i] = h; pW2Tl[i] = l;
        }
        return;
    }
    if (bid < 1027) {                             // ---- fold phase ----
        const int gid = (bid - 897) * 256 + t;
        if (gid < 16384) {
            const int j = gid >> 8, n = gid & 255;
            float s = 0.f;
            for (int k = 0; k < 256; ++k) s += cW2[j * 256 + k] * mW[(256 + k) * 256 + n];
            split2(s, h, l);
            WcTh[n * 64 + j] = h; WcTl[n * 64 + j] = l;
        } else if (gid < 32768) {
            const int i = gid - 16384, j = i >> 8, n = i & 255;
            float s = 0.f;
            for (int k = 0; k < 256; ++k) s += pW2[j * 256 + k] * mW[(512 + k) * 256 + n];
            split2(s, h, l);
            WpTh[n * 64 + j] = h; WpTl[n * 64 + j] = l;
        } else if (gid < 33024) {
            const int n = gid - 32768;
            float s = 0.f;
            for (int k = 0; k < 256; ++k) s += cb2[k] * mW[(256 + k) * 256 + n];
            cbM[n] = s;
        } else if (gid < 33280) {
            const int n = gid - 33024;
            float s = 0.f;
            for (int k = 0; k < 256; ++k) s += pb2[k] * mW[(512 + k) * 256 + n];
            pbM[n] = s;
        }
        return;
    }
    {                                             // ---- cls phase ----
        const int c = bid - 1027;
        const float v = ct[c * 256 + t];
        float ss = v * v;
        #pragma unroll
        for (int s = 32; s > 0; s >>= 1) ss += __shfl_down(ss, s, 64);
        if ((t & 63) == 0) red[t >> 6] = ss;
        __syncthreads();
        const float tot = red[0] + red[1] + red[2] + red[3];
        const float r = 1.f / fmaxf(sqrtf(tot), 1e-12f);
        ctn[t] = v * r;
        __syncthreads();
        float s = 0.f;
        for (int k = 0; k < 256; ++k) s += ctn[k] * mW[k * 256 + t];
        classMn[c * 256 + t] = s;
    }
}

// ---------------------------------------------------------------------------
// Kernel 1: embeddings via folded GEMMs. 16 obj/block, full problem (2048).
// ---------------------------------------------------------------------------
__global__ __launch_bounds__(256)
void k_embed(const float* __restrict__ classMn,
             const float* __restrict__ cW1, const float* __restrict__ cb1,
             const float* __restrict__ cb2,
             const float* __restrict__ pW1, const float* __restrict__ pb1,
             const float* __restrict__ pb2,
             const float* __restrict__ mb,
             const ushort* __restrict__ cW2Th, const ushort* __restrict__ cW2Tl,
             const ushort* __restrict__ pW2Th, const ushort* __restrict__ pW2Tl,
             const ushort* __restrict__ WcTh, const ushort* __restrict__ WcTl,
             const ushort* __restrict__ WpTh, const ushort* __restrict__ WpTl,
             const float* __restrict__ cbM, const float* __restrict__ pbM,
             const float* __restrict__ positions, const float* __restrict__ colors,
             const int* __restrict__ cls, const int cstride,
             ushort* __restrict__ ehi, ushort* __restrict__ elo,
             float* __restrict__ sqn)
{
    __shared__ __align__(16) ushort Ahc[16 * 72];
    __shared__ __align__(16) ushort Alc[16 * 72];
    __shared__ __align__(16) ushort Ahp[16 * 72];
    __shared__ __align__(16) ushort Alp[16 * 72];
    __shared__ float sqc[16][4], sqp_[16][4], sqe[16][4];

    const int t = threadIdx.x, w = t >> 6, lane = t & 63;
    const int l15 = lane & 15, quad = lane >> 4;
    const int obase = blockIdx.x * 16;

    {
        const int o = lane >> 4;
        const int objl = w * 4 + o;
        const int gobj = obase + objl;
        const float c0 = colors[gobj * 3], c1 = colors[gobj * 3 + 1], c2 = colors[gobj * 3 + 2];
        const float q0 = positions[gobj * 3], q1 = positions[gobj * 3 + 1], q2 = positions[gobj * 3 + 2];
        const int u0 = (lane & 15) * 4;
        #pragma unroll
        for (int uu = 0; uu < 4; ++uu) {
            const int u = u0 + uu;
            const float hc = fmaxf(cb1[u] + c0 * cW1[u] + c1 * cW1[64 + u] + c2 * cW1[128 + u], 0.f);
            const float hp = fmaxf(pb1[u] + q0 * pW1[u] + q1 * pW1[64 + u] + q2 * pW1[128 + u], 0.f);
            ushort h, l;
            split2(hc, h, l); Ahc[objl * 72 + u] = h; Alc[objl * 72 + u] = l;
            split2(hp, h, l); Ahp[objl * 72 + u] = h; Alp[objl * 72 + u] = l;
        }
    }
    __syncthreads();

    f32x4 aco[4], ape[4];
    #pragma unroll
    for (int nt = 0; nt < 4; ++nt) { aco[nt] = (f32x4){0.f,0.f,0.f,0.f}; ape[nt] = (f32x4){0.f,0.f,0.f,0.f}; }

    #pragma unroll
    for (int kt = 0; kt < 2; ++kt) {
        const int ao = l15 * 72 + kt * 32 + quad * 8;
        const s16x8 ahc = *(const s16x8*)&Ahc[ao];
        const s16x8 alc = *(const s16x8*)&Alc[ao];
        const s16x8 ahp = *(const s16x8*)&Ahp[ao];
        const s16x8 alp = *(const s16x8*)&Alp[ao];
        #pragma unroll
        for (int nt = 0; nt < 4; ++nt) {
            const int n = w * 64 + nt * 16 + l15;
            const size_t bo = (size_t)n * 64 + kt * 32 + quad * 8;
            const s16x8 cbh = *(const s16x8*)(cW2Th + bo);
            const s16x8 cbl = *(const s16x8*)(cW2Tl + bo);
            const s16x8 pbh = *(const s16x8*)(pW2Th + bo);
            const s16x8 pbl = *(const s16x8*)(pW2Tl + bo);
            aco[nt] = __builtin_amdgcn_mfma_f32_16x16x32_bf16(ahc, cbh, aco[nt], 0, 0, 0);
            ape[nt] = __builtin_amdgcn_mfma_f32_16x16x32_bf16(ahp, pbh, ape[nt], 0, 0, 0);
            aco[nt] = __builtin_amdgcn_mfma_f32_16x16x32_bf16(alc, cbh, aco[nt], 0, 0, 0);
            ape[nt] = __builtin_amdgcn_mfma_f32_16x16x32_bf16(alp, pbh, ape[nt], 0, 0, 0);
            aco[nt] = __builtin_amdgcn_mfma_f32_16x16x32_bf16(ahc, cbl, aco[nt], 0, 0, 0);
            ape[nt] = __builtin_amdgcn_mfma_f32_16x16x32_bf16(ahp, pbl, ape[nt], 0, 0, 0);
        }
    }

    float sc[4] = {0.f,0.f,0.f,0.f}, sp[4] = {0.f,0.f,0.f,0.f};
    #pragma unroll
    for (int nt = 0; nt < 4; ++nt) {
        const int col = w * 64 + nt * 16 + l15;
        const float cbv = cb2[col], pbv = pb2[col];
        #pragma unroll
        for (int r = 0; r < 4; ++r) {
            const float co = aco[nt][r] + cbv;
            const float pe = ape[nt][r] + pbv;
            sc[r] += co * co;
            sp[r] += pe * pe;
        }
    }
    #pragma unroll
    for (int s = 8; s > 0; s >>= 1) {
        #pragma unroll
        for (int r = 0; r < 4; ++r) {
            sc[r] += __shfl_xor(sc[r], s, 64);
            sp[r] += __shfl_xor(sp[r], s, 64);
        }
    }
    if (l15 == 0) {
        #pragma unroll
        for (int r = 0; r < 4; ++r) { sqc[quad * 4 + r][w] = sc[r]; sqp_[quad * 4 + r][w] = sp[r]; }
    }
    __syncthreads();

    float rco[4], rpe[4];
    #pragma unroll
    for (int r = 0; r < 4; ++r) {
        const int row = quad * 4 + r;
        rco[r] = 1.f / fmaxf(sqrtf(sqc[row][0] + sqc[row][1] + sqc[row][2] + sqc[row][3]), 1e-12f);
        rpe[r] = 1.f / fmaxf(sqrtf(sqp_[row][0] + sqp_[row][1] + sqp_[row][2] + sqp_[row][3]), 1e-12f);
    }

    f32x4 ac[4], ap[4];
    #pragma unroll
    for (int nt = 0; nt < 4; ++nt) { ac[nt] = (f32x4){0.f,0.f,0.f,0.f}; ap[nt] = (f32x4){0.f,0.f,0.f,0.f}; }

    #pragma unroll
    for (int kt = 0; kt < 2; ++kt) {
        const int ao = l15 * 72 + kt * 32 + quad * 8;
        const s16x8 ahc = *(const s16x8*)&Ahc[ao];
        const s16x8 alc = *(const s16x8*)&Alc[ao];
        const s16x8 ahp = *(const s16x8*)&Ahp[ao];
        const s16x8 alp = *(const s16x8*)&Alp[ao];
        #pragma unroll
        for (int nt = 0; nt < 4; ++nt) {
            const int n = w * 64 + nt * 16 + l15;
            const size_t bo = (size_t)n * 64 + kt * 32 + quad * 8;
            const s16x8 cbh = *(const s16x8*)(WcTh + bo);
            const s16x8 cbl = *(const s16x8*)(WcTl + bo);
            const s16x8 pbh = *(const s16x8*)(WpTh + bo);
            const s16x8 pbl = *(const s16x8*)(WpTl + bo);
            ac[nt] = __builtin_amdgcn_mfma_f32_16x16x32_bf16(ahc, cbh, ac[nt], 0, 0, 0);
            ap[nt] = __builtin_amdgcn_mfma_f32_16x16x32_bf16(ahp, pbh, ap[nt], 0, 0, 0);
            ac[nt] = __builtin_amdgcn_mfma_f32_16x16x32_bf16(alc, cbh, ac[nt], 0, 0, 0);
            ap[nt] = __builtin_amdgcn_mfma_f32_16x16x32_bf16(alp, pbh, ap[nt], 0, 0, 0);
            ac[nt] = __builtin_amdgcn_mfma_f32_16x16x32_bf16(ahc, cbl, ac[nt], 0, 0, 0);
            ap[nt] = __builtin_amdgcn_mfma_f32_16x16x32_bf16(ahp, pbl, ap[nt], 0, 0, 0);
        }
    }

    int ci[4];
    #pragma unroll
    for (int r = 0; r < 4; ++r) {
        const int gobj = obase + quad * 4 + r;
        int c = cls[(size_t)gobj * cstride];
        if ((unsigned)c > 30u) c = 0;
        ci[r] = c;
    }

    float rp[4] = {0.f,0.f,0.f,0.f};
    #pragma unroll
    for (int nt = 0; nt < 4; ++nt) {
        const int col = w * 64 + nt * 16 + l15;
        const float mbv = mb[col], cbMv = cbM[col], pbMv = pbM[col];
        #pragma unroll
        for (int r = 0; r < 4; ++r) {
            const int row = quad * 4 + r;
            const float e = classMn[ci[r] * 256 + col]
                          + rco[r] * (ac[nt][r] + cbMv)
                          + rpe[r] * (ap[nt][r] + pbMv) + mbv;
            ushort h, l;
            split2(e, h, l);
            ehi[(size_t)(obase + row) * 256 + col] = h;
            elo[(size_t)(obase + row) * 256 + col] = l;
            rp[r] += e * e;
        }
    }
    #pragma unroll
    for (int s = 8; s > 0; s >>= 1) {
        #pragma unroll
        for (int r = 0; r < 4; ++r) rp[r] += __shfl_xor(rp[r], s, 64);
    }
    if (l15 == 0) {
        #pragma unroll
        for (int r = 0; r < 4; ++r) sqe[quad * 4 + r][w] = rp[r];
    }
    __syncthreads();
    if (t < 16) sqn[obase + t] = sqe[t][0] + sqe[t][1] + sqe[t][2] + sqe[t][3];
}

// ---------------------------------------------------------------------------
// Kernel 2: Gram + FUSED partial top-8. Upper-triangle tiles (10/cell). The
// 128x128 d-tile goes to LDS (row-XOR swizzle col^row: conflict-free for
// both row scans and column scans), then per row each thread-pair computes
// the exact per-tile top-8 as sortable u64 keys (monotone-f32<<32 | idx;
// lexicographic (d,idx) == k_select's tie rule). Off-diag also selects the
// mirror side by scanning columns. dist is never materialized. FIXED vs
// R14: pairwise merge snapshots the partner's 8 keys BEFORE inserting
// (interleaved shfl+ins8 corrupted both lists).
// ---------------------------------------------------------------------------
__global__ __launch_bounds__(256)
void k_gram(const ushort* __restrict__ ehi, const ushort* __restrict__ elo,
            const float* __restrict__ sqn, u64* __restrict__ cand)
{
    // [dbuf][Ah,Al,Bh,Bl][128 rows * 32 k], 64 KB; reused as f32[128][128]
    __shared__ __align__(16) ushort lds[2][4][4096];

    const int t = threadIdx.x, w = t >> 6, lane = t & 63;
    const int l15 = lane & 15, quad = lane >> 4;
    const int b = blockIdx.x;
    const int xcd = b & 7, rest = b >> 3;        // rest 0..79
    const int cell = xcd * 8 + rest / 10;        // 0..63
    const int tt = rest % 10;
    // upper-triangle enumeration: (0,0)(0,1)(0,2)(0,3)(1,1)(1,2)(1,3)(2,2)(2,3)(3,3)
    const int ti = (tt < 4) ? 0 : (tt < 7) ? 1 : (tt < 9) ? 2 : 3;
    const int tbase = (ti == 0) ? 0 : (ti == 1) ? 4 : (ti == 2) ? 7 : 9;
    const int tj = ti + (tt - tbase);
    const int p0 = ti * 128, q0 = tj * 128;
    const size_t cb = (size_t)cell * NP;
    const int diag = (ti == tj);
    const int wr = w >> 1, wc = w & 1;           // 2x2 wave grid, 64x64 each

    int srow[2], scol[2];
    #pragma unroll
    for (int i = 0; i < 2; ++i) {
        const int p = (w * 2 + i) * 64 + lane;
        const int row = p >> 2;
        srow[i] = row;
        scol[i] = ((p & 3) ^ ((row >> 1) & 3)) * 8;   // ushort offset of 16B chunk
    }

    #define STAGE(KT, D)                                                         \
    {                                                                            \
        const int kb_ = (KT) * 32;                                               \
        _Pragma("unroll")                                                        \
        for (int i = 0; i < 2; ++i) {                                            \
            const int ls_ = (w * 2 + i) * 512;   /* slot*8 ushorts */            \
            const size_t ga_ = (cb + p0 + srow[i]) * 256 + kb_ + scol[i];        \
            gload16(ehi + ga_, &lds[D][0][ls_]);                                 \
            gload16(elo + ga_, &lds[D][1][ls_]);                                 \
            if (!diag) {                                                         \
                const size_t gq_ = (cb + q0 + srow[i]) * 256 + kb_ + scol[i];    \
                gload16(ehi + gq_, &lds[D][2][ls_]);                             \
                gload16(elo + gq_, &lds[D][3][ls_]);                             \
            }                                                                    \
        }                                                                        \
    }

    f32x4 acc[4][4];
    #pragma unroll
    for (int mt = 0; mt < 4; ++mt)
        #pragma unroll
        for (int nt = 0; nt < 4; ++nt) acc[mt][nt] = (f32x4){0.f, 0.f, 0.f, 0.f};

    const int bB = diag ? 0 : 2;

    STAGE(0, 0);
    __syncthreads();

    for (int kt = 0; kt < 8; ++kt) {
        const int cur = kt & 1;
        if (kt < 7) STAGE(kt + 1, cur ^ 1);      // prefetch next k-slice

        s16x8 ah[4], al[4];
        #pragma unroll
        for (int mt = 0; mt < 4; ++mt) {
            const int r = wr * 64 + mt * 16 + l15;
            const int slot = 4 * r + (quad ^ ((r >> 1) & 3));
            ah[mt] = *(const s16x8*)&lds[cur][0][slot * 8];
            al[mt] = *(const s16x8*)&lds[cur][1][slot * 8];
        }
        #pragma unroll
        for (int nt = 0; nt < 4; ++nt) {
            const int rq = wc * 64 + nt * 16 + l15;
            const int slot = 4 * rq + (quad ^ ((rq >> 1) & 3));
            const s16x8 bh = *(const s16x8*)&lds[cur][bB][slot * 8];
            const s16x8 bl = *(const s16x8*)&lds[cur][bB + 1][slot * 8];
            #pragma unroll
            for (int mt = 0; mt < 4; ++mt) {
                acc[mt][nt] = __builtin_amdgcn_mfma_f32_16x16x32_bf16(ah[mt], bh, acc[mt][nt], 0, 0, 0);
                acc[mt][nt] = __builtin_amdgcn_mfma_f32_16x16x32_bf16(al[mt], bh, acc[mt][nt], 0, 0, 0);
                acc[mt][nt] = __builtin_amdgcn_mfma_f32_16x16x32_bf16(ah[mt], bl, acc[mt][nt], 0, 0, 0);
            }
        }
        __syncthreads();                          // drains vmcnt(0) -> buf ready
    }
    #undef STAGE

    float sqp[4][4];
    #pragma unroll
    for (int mt = 0; mt < 4; ++mt)
        #pragma unroll
        for (int r = 0; r < 4; ++r)
            sqp[mt][r] = sqn[cb + p0 + wr * 64 + mt * 16 + quad * 4 + r];

    float* T = (float*)&lds[0][0][0];            // 128x128 f32, col ^ row swizzle

    #pragma unroll
    for (int nt = 0; nt < 4; ++nt) {
        const int cq_l = wc * 64 + nt * 16 + l15;
        const float sq_q = sqn[cb + q0 + cq_l];
        #pragma unroll
        for (int mt = 0; mt < 4; ++mt) {
            #pragma unroll
            for (int r = 0; r < 4; ++r) {
                const int rp_l = wr * 64 + mt * 16 + quad * 4 + r;
                const float d = (sqp[mt][r] + sq_q) - 2.f * acc[mt][nt][r];
                T[rp_l * 128 + (cq_l ^ rp_l)] = d;
            }
        }
    }
    __syncthreads();

    // ---- exact per-tile top-8 per row (2 threads/row, snapshot-merge) ----
    {
        const int row = t >> 1, half = t & 1;

        u64 k8[8];
        #pragma unroll
        for (int j = 0; j < 8; ++j) k8[j] = ~0ull;
        for (int c = 0; c < 64; ++c) {
            const int cc = half * 64 + c;
            const float f = T[row * 128 + (cc ^ row)];
            ins8(k8, ((u64)fkey(f) << 32) | (unsigned)(q0 + cc));
        }
        {
            u64 part[8];
            #pragma unroll
            for (int j = 0; j < 8; ++j) part[j] = __shfl_xor(k8[j], 1, 64);
            #pragma unroll
            for (int j = 0; j < 8; ++j) ins8(k8, part[j]);
        }
        if (half == 0) {
            u64* cp = cand + ((size_t)(cb + p0 + row)) * 32 + tj * 8;
            #pragma unroll
            for (int j = 0; j < 8; ++j) cp[j] = k8[j];
        }

        if (!diag) {                              // mirror side: scan columns
            u64 q8[8];
            #pragma unroll
            for (int j = 0; j < 8; ++j) q8[j] = ~0ull;
            for (int c = 0; c < 64; ++c) {
                const int rr = half * 64 + c;
                const float f = T[rr * 128 + (row ^ rr)];
                ins8(q8, ((u64)fkey(f) << 32) | (unsigned)(p0 + rr));
            }
            {
                u64 part[8];
                #pragma unroll
                for (int j = 0; j < 8; ++j) part[j] = __shfl_xor(q8[j], 1, 64);
                #pragma unroll
                for (int j = 0; j < 8; ++j) ins8(q8, part[j]);
            }
            if (half == 0) {
                u64* cp = cand + ((size_t)(cb + q0 + row)) * 32 + ti * 8;
                #pragma unroll
                for (int j = 0; j < 8; ++j) cp[j] = q8[j];
            }
        }
    }
}

// ---------------------------------------------------------------------------
// Kernel 3: merge 4 per-tile top-8 lists -> global top-8 per point.
// Exact: every global top-8 element is in its tile's top-8; u64 keys are
// (d,idx) lexicographic, matching the reference's stable-top_k tie rule.
// ---------------------------------------------------------------------------
__global__ __launch_bounds__(256)
void k_nidx(const u64* __restrict__ cand, int* __restrict__ nidx)
{
    const int p = blockIdx.x * 256 + threadIdx.x;    // 0..NTOT-1
    const u64* cp = cand + (size_t)p * 32;
    u64 k8[8];
    #pragma unroll
    for (int j = 0; j < 8; ++j) k8[j] = ~0ull;
    #pragma unroll
    for (int i = 0; i < 32; ++i) ins8(k8, cp[i]);
    const int hi = (p >> 9) << 9;
    #pragma unroll
    for (int r = 0; r < 8; ++r)
        nidx[(size_t)p * KNN + r] = hi | (int)(k8[r] & 0x1ffu);
}

// ---------------------------------------------------------------------------
// Kernel 4: u = x@Wd+gb1, v = x@Wb. Single-pass A (hi only), LDS-staged via
// global_load_lds width-16 with XOR chunk-swizzle. B (Wh) direct.
// ---------------------------------------------------------------------------
__global__ __launch_bounds__(256)
void k_uv(const ushort* __restrict__ ehi, const ushort* __restrict__ elo,
          const ushort* __restrict__ Wdh, const ushort* __restrict__ Wbh,
          const float* __restrict__ gb1,
          float* __restrict__ u, float* __restrict__ v)
{
    (void)elo;
    __shared__ __align__(16) ushort lds[2][2048];   // [dbuf][slot*8] hi only, 8 KB

    const int t = threadIdx.x, w = t >> 6, lane = t & 63;
    const int l15 = lane & 15, quad = lane >> 4;
    const int isV = blockIdx.x >> 9;           // 1024 blocks total
    const int m0 = (blockIdx.x & 511) * 64;
    const ushort* Wh = isV ? Wbh : Wdh;
    float* out = isV ? v : u;
    const int mh = w & 1, ch = w >> 1;

    const int sp = w * 64 + lane;
    const int srow = sp >> 2;
    const int scol = ((sp & 3) ^ ((srow >> 1) & 3)) * 8;   // ushort offset

    #define STAGE_UV(S, D)                                                       \
    {                                                                            \
        const size_t ga_ = (size_t)(m0 + srow) * 256 + (S) * 32 + scol;          \
        gload16(ehi + ga_, &lds[D][sp * 8]);                                     \
    }

    const int r0 = mh * 32 + l15, r1 = r0 + 16;
    const int slot0 = 4 * r0 + (quad ^ ((r0 >> 1) & 3));
    const int slot1 = 4 * r1 + (quad ^ ((r1 >> 1) & 3));

    f32x4 acc[2][8];
    #pragma unroll
    for (int mt = 0; mt < 2; ++mt)
        #pragma unroll
        for (int nt = 0; nt < 8; ++nt) acc[mt][nt] = (f32x4){0.f, 0.f, 0.f, 0.f};

    STAGE_UV(0, 0);
    __syncthreads();

    for (int s = 0; s < 8; ++s) {
        const int cur = s & 1;
        if (s < 7) STAGE_UV(s + 1, cur ^ 1);   // prefetch next k-slice

        const s16x8 ah0 = *(const s16x8*)&lds[cur][slot0 * 8];
        const s16x8 ah1 = *(const s16x8*)&lds[cur][slot1 * 8];
        #pragma unroll
        for (int nt = 0; nt < 8; ++nt) {
            const int n = ch * 128 + nt * 16 + l15;
            const size_t bo = (size_t)n * 256 + s * 32 + quad * 8;
            const s16x8 bh = *(const s16x8*)(Wh + bo);
            acc[0][nt] = __builtin_amdgcn_mfma_f32_16x16x32_bf16(ah0, bh, acc[0][nt], 0, 0, 0);
            acc[1][nt] = __builtin_amdgcn_mfma_f32_16x16x32_bf16(ah1, bh, acc[1][nt], 0, 0, 0);
        }
        __syncthreads();                        // drains vmcnt(0) -> buf ready
    }
    #undef STAGE_UV

    #pragma unroll
    for (int mt = 0; mt < 2; ++mt) {
        #pragma unroll
        for (int nt = 0; nt < 8; ++nt) {
            const int col = ch * 128 + nt * 16 + l15;
            const float bias = isV ? 0.f : gb1[col];
            #pragma unroll
            for (int r = 0; r < 4; ++r) {
                const int row = mh * 32 + mt * 16 + quad * 4 + r;
                out[(size_t)(m0 + row) * 256 + col] = acc[mt][nt][r] + bias;
            }
        }
    }
}

// ---------------------------------------------------------------------------
// Kernel 5: edge GEMM + max aggregation. Single-pass RNE A, 512-thread /
// 8-wave structure (occupancy ~80%): wave w owns cols w*32..+31, acc = 2 x
// f32x16 = 32 AGPR. LDS-only inner barrier keeps v loads in flight.
// BYTE-IDENTICAL to the passing R13 version.
// ---------------------------------------------------------------------------
__global__ __launch_bounds__(512)
void k_edge(const float* __restrict__ u, const float* __restrict__ v,
            const int* __restrict__ nidx,
            const ushort* __restrict__ g2h,
            const float* __restrict__ hb,
            float* __restrict__ part)
{
    __shared__ ushort Abuf[2][2304];      // [dbuf][edge*36+k] hi only, 9.2 KB
    __shared__ float ustage[2048];        // 8 pts x 256 k, 8 KB

    const int t = threadIdx.x, w = t >> 6, lane = t & 63;
    const int l31 = lane & 31, kh = lane >> 5;

    const int b = blockIdx.x;
    const int xcd = b & 7, rest = b >> 3;        // rest 0..511
    const int cell = xcd * 8 + (rest >> 6);      // 0..63
    const int pl0 = cell * NP + (rest & 63) * 8;

    // stage u rows once (coalesced, 4 floats per thread x 512 threads)
    {
        const int pt = t >> 6, kk = (t & 63) * 4;
        *(float4*)&ustage[pt * 256 + kk] = *(const float4*)(u + (size_t)(pl0 + pt) * 256 + kk);
    }

    const int se = t >> 3, kq = t & 7;           // edge 0..63, k-quad 0..7 (4 k each)
    const int upt = se >> 3;                     // point within block
    int svrow = nidx[(size_t)(pl0 + upt) * KNN + (se & 7)];
    if ((unsigned)svrow >= (unsigned)NTOT) svrow = 0;

    __syncthreads();                             // ustage visible (one-time)

    float4 vr[2];                                // 2-set v pipeline (4 floats/thread)

    #define VLOAD(S)                                                             \
    {                                                                            \
        const int k0 = (S) * 32 + kq * 4;                                        \
        vr[(S) & 1] = *(const float4*)(v + (size_t)svrow * 256 + k0);            \
    }
    #define SPLITW(S, BUF)                                                       \
    {                                                                            \
        const int k0u = (S) * 32 + kq * 4;                                       \
        const float4 ua = *(const float4*)&ustage[upt * 256 + k0u];              \
        const float4 va = vr[(S) & 1];                                           \
        const float sv[4] = {                                                    \
            fmaxf(ua.x + va.x, 0.f), fmaxf(ua.y + va.y, 0.f),                    \
            fmaxf(ua.z + va.z, 0.f), fmaxf(ua.w + va.w, 0.f)};                   \
        union { uint2 q; ushort us[4]; } th;                                     \
        _Pragma("unroll")                                                        \
        for (int j = 0; j < 4; ++j) { th.us[j] = f2b(sv[j]); }                   \
        *(uint2*)&Abuf[BUF][se * 36 + kq * 4] = th.q;                            \
    }

    #define LDS_BARRIER()                                                        \
    {                                                                            \
        asm volatile("s_waitcnt lgkmcnt(0)" ::: "memory");                       \
        __builtin_amdgcn_s_barrier();                                            \
    }

    f32x16 acc[2];
    acc[0] = (f32x16)(0.0f);
    acc[1] = (f32x16)(0.0f);

    VLOAD(0); VLOAD(1);
    SPLITW(0, 0);

    #pragma unroll
    for (int s = 0; s < 8; ++s) {
        LDS_BARRIER();                        // buf[s&1] visible; buf[(s+1)&1] readers done
        if (s < 7) {
            SPLITW(s + 1, (s + 1) & 1);       // u from LDS, v register-resident
            if (s < 6) VLOAD(s + 2);          // stays in flight across barriers
        }

        s16x8 ah[2][2];
        #pragma unroll
        for (int mt = 0; mt < 2; ++mt) {
            #pragma unroll
            for (int kc = 0; kc < 2; ++kc) {
                const int ao = (mt * 32 + l31) * 36 + kc * 16 + kh * 8;
                union { uint2 q[2]; s16x8 v8; } Th;
                Th.q[0] = *(const uint2*)&Abuf[s & 1][ao];
                Th.q[1] = *(const uint2*)&Abuf[s & 1][ao + 4];
                ah[mt][kc] = Th.v8;
            }
        }

        #pragma unroll
        for (int kc = 0; kc < 2; ++kc) {
            const int n = w * 32 + l31;
            const s16x8 bh = *(const s16x8*)(g2h + (size_t)n * 256 + s * 32 + kc * 16 + kh * 8);
            acc[0] = __builtin_amdgcn_mfma_f32_32x32x16_bf16(ah[0][kc], bh, acc[0], 0, 0, 0);
            acc[1] = __builtin_amdgcn_mfma_f32_32x32x16_bf16(ah[1][kc], bh, acc[1], 0, 0, 0);
        }
    }
    #undef VLOAD
    #undef SPLITW
    #undef LDS_BARRIER

    const int slot = rest & 63;
    {
        float rm = -3.4e38f;
        #pragma unroll
        for (int r = 0; r < 16; ++r)
            rm = fmaxf(rm, fmaxf(acc[0][r], acc[1][r]));
        rm = fmaxf(rm, __shfl_xor(rm, 32, 64));   // merge row-halves (lane>>5)
        if (kh == 0) {
            const int col = w * 32 + l31;
            part[((size_t)cell * 64 + slot) * 256 + col] = rm + hb[col];
        }
    }
}

// ---------------------------------------------------------------------------
// Kernel 6: reduce 64 partial maxes per cell, final MLP (f32), L2 normalize.
// ---------------------------------------------------------------------------
__global__ __launch_bounds__(256)
void k_final(const float* __restrict__ part,
             const float* __restrict__ lW1, const float* __restrict__ lb1,
             const float* __restrict__ lW2, const float* __restrict__ lb2,
             float* __restrict__ out)
{
    __shared__ float pooled[256];
    __shared__ float hid[256];
    __shared__ float red[4];

    const int b = blockIdx.x;
    const int t = threadIdx.x;

    float m = -3.4e38f;
    for (int s = 0; s < 64; ++s)
        m = fmaxf(m, part[((size_t)b * 64 + s) * 256 + t]);
    pooled[t] = m;
    __syncthreads();

    float h = lb1[t];
    for (int k = 0; k < 256; k += 4) {
        #pragma unroll
        for (int kk = 0; kk < 4; ++kk)
            h += pooled[k + kk] * lW1[(k + kk) * 256 + t];
    }
    hid[t] = fmaxf(h, 0.f);
    __syncthreads();

    float o = lb2[t];
    for (int k = 0; k < 256; k += 4) {
        #pragma unroll
        for (int kk = 0; kk < 4; ++kk)
            o += hid[k + kk] * lW2[(k + kk) * 256 + t];
    }

    float ss = o * o;
    #pragma unroll
    for (int s = 32; s > 0; s >>= 1) ss += __shfl_down(ss, s, 64);
    if ((t & 63) == 0) red[t >> 6] = ss;
    __syncthreads();
    const float tot = red[0] + red[1] + red[2] + red[3];
    const float rn = 1.f / fmaxf(sqrtf(tot), 1e-12f);
    out[b * 256 + t] = o * rn;
}

// ---------------------------------------------------------------------------
extern "C" void kernel_launch(void* const* d_in, const int* in_sizes, int n_in,
                              void* d_out, int out_size, void* d_ws, size_t ws_size,
                              hipStream_t stream)
{
    (void)n_in; (void)out_size; (void)ws_size;

    const float* class_table = (const float*)d_in[0];
    const float* cW1 = (const float*)d_in[1];
    const float* cb1 = (const float*)d_in[2];
    const float* cW2 = (const float*)d_in[3];
    const float* cb2 = (const float*)d_in[4];
    const float* pW1 = (const float*)d_in[5];
    const float* pb1 = (const float*)d_in[6];
    const float* pW2 = (const float*)d_in[7];
    const float* pb2 = (const float*)d_in[8];
    const float* mW  = (const float*)d_in[9];
    const float* mb  = (const float*)d_in[10];
    const float* gW1 = (const float*)d_in[11];
    const float* gb1 = (const float*)d_in[12];
    const float* g_gamma = (const float*)d_in[13];
    const float* g_beta  = (const float*)d_in[14];
    const float* gW2 = (const float*)d_in[15];
    const float* gb2 = (const float*)d_in[16];
    const float* lW1 = (const float*)d_in[17];
    const float* lb1 = (const float*)d_in[18];
    const float* lW2 = (const float*)d_in[19];
    const float* lb2 = (const float*)d_in[20];
    const float* positions = (const float*)d_in[21];
    const float* colors    = (const float*)d_in[22];
    const int*  cls        = (const int*)d_in[23];

    const int cstride = (in_sizes[23] == 2 * NTOT) ? 2 : 1;

    // workspace layout (bytes); cand (8 MB) replaces dist (67 MB).
    char* base = (char*)d_ws;
    float*   part   = (float*)(base + 0);               //   4,194,304
    ushort*  Wdh    = (ushort*)(base + 4194304);
    ushort*  Wdl    = (ushort*)(base + 4325376);
    ushort*  Wbh    = (ushort*)(base + 4456448);
    ushort*  Wbl    = (ushort*)(base + 4587520);
    ushort*  g2h    = (ushort*)(base + 4718592);
    ushort*  g2l    = (ushort*)(base + 4849664);
    float*   hb     = (float*)(base + 4980736);
    ushort*  cW2Th  = (ushort*)(base + 4981760);
    ushort*  cW2Tl  = (ushort*)(base + 5014528);
    ushort*  pW2Th  = (ushort*)(base + 5047296);
    ushort*  pW2Tl  = (ushort*)(base + 5080064);
    ushort*  WcTh   = (ushort*)(base + 5112832);
    ushort*  WcTl   = (ushort*)(base + 5145600);
    ushort*  WpTh   = (ushort*)(base + 5178368);
    ushort*  WpTl   = (ushort*)(base + 5211136);
    float*   classMn= (float*)(base + 5243904);
    float*   cbM    = (float*)(base + 5275648);
    float*   pbM    = (float*)(base + 5276672);
    int*     nidx   = (int*)(base + 5277696);           //   1,048,576
    float*   sqn    = (float*)(base + 6326272);         //     131,072
    ushort*  ehi    = (ushort*)(base + 6457344);        //  16,777,216
    ushort*  elo    = (ushort*)(base + 23234560);       //  16,777,216
    u64*     cand   = (u64*)(base + 40011776);          //   8,388,608
    float*   v      = (float*)(base + 107120640);       //  33,554,432
    float*   u      = (float*)(base + 140675072);       //  33,554,432
    float* out = (float*)d_out;

    k_prep<<<1058, 256, 0, stream>>>(gW1, gW2, g_gamma, g_beta, gb2, cW2, pW2,
                                     cb2, pb2, mW, class_table,
                                     Wdh, Wdl, Wbh, Wbl, g2h, g2l, hb,
                                     cW2Th, cW2Tl, pW2Th, pW2Tl,
                                     WcTh, WcTl, WpTh, WpTl, cbM, pbM, classMn);

    k_embed<<<NTOT / 16, 256, 0, stream>>>(classMn, cW1, cb1, cb2, pW1, pb1, pb2,
                                           mb, cW2Th, cW2Tl, pW2Th, pW2Tl,
                                           WcTh, WcTl, WpTh, WpTl, cbM, pbM,
                                           positions, colors, cls, cstride,
                                           ehi, elo, sqn);
    k_gram<<<NB * 10, 256, 0, stream>>>(ehi, elo, sqn, cand);
    k_nidx<<<NTOT / 256, 256, 0, stream>>>(cand, nidx);
    k_uv<<<2 * NTOT / 64, 256, 0, stream>>>(ehi, elo, Wdh, Wbh, gb1, u, v);
    k_edge<<<NTOT / 8, 512, 0, stream>>>(u, v, nidx, g2h, hb, part);
    k_final<<<NB, 256, 0, stream>>>(part, lW1, lb1, lW2, lb2, out);
}

// Round 16
// 391.100 us; speedup vs baseline: 1.1709x; 1.0330x over previous
//
#include <hip/hip_runtime.h>

#define EDIM 256
#define KNN 8
#define NB 64
#define NP 512
#define NTOT (NB * NP)

typedef short s16x8 __attribute__((ext_vector_type(8)));
typedef float f32x4 __attribute__((ext_vector_type(4)));
typedef float f32x16 __attribute__((ext_vector_type(16)));
typedef unsigned short ushort;
typedef unsigned long long u64;

__device__ __forceinline__ ushort f2b(float f) {
    unsigned u = __float_as_uint(f);
    u = (u + 0x7fffu + ((u >> 16) & 1u)) >> 16;   // RNE
    return (ushort)u;
}
__device__ __forceinline__ float b2f(ushort h) {
    return __uint_as_float(((unsigned)h) << 16);
}
__device__ __forceinline__ void split2(float x, ushort& h, ushort& l) {
    h = f2b(x);
    l = f2b(x - b2f(h));
}

// monotone float->uint map: ascending float order == ascending uint order
__device__ __forceinline__ unsigned fkey(float f) {
    const unsigned b = __float_as_uint(f);
    return (b & 0x80000000u) ? ~b : (b | 0x80000000u);
}

// branchless sorted-ascending top-8 insert (k[0] smallest)
__device__ __forceinline__ void ins8(u64* k, u64 x) {
    #pragma unroll
    for (int j = 7; j >= 1; --j)
        k[j] = (x < k[j - 1]) ? k[j - 1] : ((x < k[j]) ? x : k[j]);
    k[0] = (x < k[0]) ? x : k[0];
}

// async global->LDS, 16B per lane; lds dest is wave-uniform base + lane*16
__device__ __forceinline__ void gload16(const ushort* g, ushort* l) {
    __builtin_amdgcn_global_load_lds(
        (const __attribute__((address_space(1))) void*)g,
        (__attribute__((address_space(3))) void*)l, 16, 0, 0);
}

// ---------------------------------------------------------------------------
// Kernel 0: merged prep (cvt + fold + cls).
// ---------------------------------------------------------------------------
__global__ __launch_bounds__(256)
void k_prep(const float* __restrict__ gW1, const float* __restrict__ gW2,
            const float* __restrict__ g_gamma, const float* __restrict__ g_beta,
            const float* __restrict__ gb2,
            const float* __restrict__ cW2, const float* __restrict__ pW2,
            const float* __restrict__ cb2, const float* __restrict__ pb2,
            const float* __restrict__ mW, const float* __restrict__ ct,
            ushort* __restrict__ Wdh, ushort* __restrict__ Wdl,
            ushort* __restrict__ Wbh, ushort* __restrict__ Wbl,
            ushort* __restrict__ g2h, ushort* __restrict__ g2l,
            float* __restrict__ hb,
            ushort* __restrict__ cW2Th, ushort* __restrict__ cW2Tl,
            ushort* __restrict__ pW2Th, ushort* __restrict__ pW2Tl,
            ushort* __restrict__ WcTh, ushort* __restrict__ WcTl,
            ushort* __restrict__ WpTh, ushort* __restrict__ WpTl,
            float* __restrict__ cbM, float* __restrict__ pbM,
            float* __restrict__ classMn)
{
    __shared__ float ctn[256];
    __shared__ float red[4];
    const int bid = blockIdx.x, t = threadIdx.x;
    ushort h, l;

    if (bid < 897) {                              // ---- cvt phase ----
        const int gid = bid * 256 + t;
        if (gid < 65536) {
            const int n = gid >> 8, k = gid & 255;
            split2(gW1[k * 256 + n] - gW1[(k + 256) * 256 + n], h, l);
            Wdh[gid] = h; Wdl[gid] = l;
        } else if (gid < 131072) {
            const int i = gid - 65536, n = i >> 8, k = i & 255;
            split2(gW1[(k + 256) * 256 + n], h, l);
            Wbh[i] = h; Wbl[i] = l;
        } else if (gid < 196608) {
            const int i = gid - 131072, n = i >> 8, k = i & 255;
            split2(g_gamma[k] * gW2[k * 256 + n], h, l);
            g2h[i] = h; g2l[i] = l;
        } else if (gid < 196864) {
            const int n = gid - 196608;
            float s = gb2[n];
            for (int k = 0; k < 256; ++k) s += g_beta[k] * gW2[k * 256 + n];
            hb[n] = s;
        } else if (gid < 213248) {
            const int i = gid - 196864, n = i >> 6, k = i & 63;
            split2(cW2[k * 256 + n], h, l);
            cW2Th[i] = h; cW2Tl[i] = l;
        } else if (gid < 229632) {
            const int i = gid - 213248, n = i >> 6, k = i & 63;
            split2(pW2[k * 256 + n], h, l);
            pW2Th[i] = h; pW2Tl[i] = l;
        }
        return;
    }
    if (bid < 1027) {                             // ---- fold phase ----
        const int gid = (bid - 897) * 256 + t;
        if (gid < 16384) {
            const int j = gid >> 8, n = gid & 255;
            float s = 0.f;
            for (int k = 0; k < 256; ++k) s += cW2[j * 256 + k] * mW[(256 + k) * 256 + n];
            split2(s, h, l);
            WcTh[n * 64 + j] = h; WcTl[n * 64 + j] = l;
        } else if (gid < 32768) {
            const int i = gid - 16384, j = i >> 8, n = i & 255;
            float s = 0.f;
            for (int k = 0; k < 256; ++k) s += pW2[j * 256 + k] * mW[(512 + k) * 256 + n];
            split2(s, h, l);
            WpTh[n * 64 + j] = h; WpTl[n * 64 + j] = l;
        } else if (gid < 33024) {
            const int n = gid - 32768;
            float s = 0.f;
            for (int k = 0; k < 256; ++k) s += cb2[k] * mW[(256 + k) * 256 + n];
            cbM[n] = s;
        } else if (gid < 33280) {
            const int n = gid - 33024;
            float s = 0.f;
            for (int k = 0; k < 256; ++k) s += pb2[k] * mW[(512 + k) * 256 + n];
            pbM[n] = s;
        }
        return;
    }
    {                                             // ---- cls phase ----
        const int c = bid - 1027;
        const float v = ct[c * 256 + t];
        float ss = v * v;
        #pragma unroll
        for (int s = 32; s > 0; s >>= 1) ss += __shfl_down(ss, s, 64);
        if ((t & 63) == 0) red[t >> 6] = ss;
        __syncthreads();
        const float tot = red[0] + red[1] + red[2] + red[3];
        const float r = 1.f / fmaxf(sqrtf(tot), 1e-12f);
        ctn[t] = v * r;
        __syncthreads();
        float s = 0.f;
        for (int k = 0; k < 256; ++k) s += ctn[k] * mW[k * 256 + t];
        classMn[c * 256 + t] = s;
    }
}

// ---------------------------------------------------------------------------
// Kernel 1: embeddings via folded GEMMs. 16 obj/block, full problem (2048).
// ---------------------------------------------------------------------------
__global__ __launch_bounds__(256)
void k_embed(const float* __restrict__ classMn,
             const float* __restrict__ cW1, const float* __restrict__ cb1,
             const float* __restrict__ cb2,
             const float* __restrict__ pW1, const float* __restrict__ pb1,
             const float* __restrict__ pb2,
             const float* __restrict__ mb,
             const ushort* __restrict__ cW2Th, const ushort* __restrict__ cW2Tl,
             const ushort* __restrict__ pW2Th, const ushort* __restrict__ pW2Tl,
             const ushort* __restrict__ WcTh, const ushort* __restrict__ WcTl,
             const ushort* __restrict__ WpTh, const ushort* __restrict__ WpTl,
             const float* __restrict__ cbM, const float* __restrict__ pbM,
             const float* __restrict__ positions, const float* __restrict__ colors,
             const int* __restrict__ cls, const int cstride,
             ushort* __restrict__ ehi, ushort* __restrict__ elo,
             float* __restrict__ sqn)
{
    __shared__ __align__(16) ushort Ahc[16 * 72];
    __shared__ __align__(16) ushort Alc[16 * 72];
    __shared__ __align__(16) ushort Ahp[16 * 72];
    __shared__ __align__(16) ushort Alp[16 * 72];
    __shared__ float sqc[16][4], sqp_[16][4], sqe[16][4];

    const int t = threadIdx.x, w = t >> 6, lane = t & 63;
    const int l15 = lane & 15, quad = lane >> 4;
    const int obase = blockIdx.x * 16;

    {
        const int o = lane >> 4;
        const int objl = w * 4 + o;
        const int gobj = obase + objl;
        const float c0 = colors[gobj * 3], c1 = colors[gobj * 3 + 1], c2 = colors[gobj * 3 + 2];
        const float q0 = positions[gobj * 3], q1 = positions[gobj * 3 + 1], q2 = positions[gobj * 3 + 2];
        const int u0 = (lane & 15) * 4;
        #pragma unroll
        for (int uu = 0; uu < 4; ++uu) {
            const int u = u0 + uu;
            const float hc = fmaxf(cb1[u] + c0 * cW1[u] + c1 * cW1[64 + u] + c2 * cW1[128 + u], 0.f);
            const float hp = fmaxf(pb1[u] + q0 * pW1[u] + q1 * pW1[64 + u] + q2 * pW1[128 + u], 0.f);
            ushort h, l;
            split2(hc, h, l); Ahc[objl * 72 + u] = h; Alc[objl * 72 + u] = l;
            split2(hp, h, l); Ahp[objl * 72 + u] = h; Alp[objl * 72 + u] = l;
        }
    }
    __syncthreads();

    f32x4 aco[4], ape[4];
    #pragma unroll
    for (int nt = 0; nt < 4; ++nt) { aco[nt] = (f32x4){0.f,0.f,0.f,0.f}; ape[nt] = (f32x4){0.f,0.f,0.f,0.f}; }

    #pragma unroll
    for (int kt = 0; kt < 2; ++kt) {
        const int ao = l15 * 72 + kt * 32 + quad * 8;
        const s16x8 ahc = *(const s16x8*)&Ahc[ao];
        const s16x8 alc = *(const s16x8*)&Alc[ao];
        const s16x8 ahp = *(const s16x8*)&Ahp[ao];
        const s16x8 alp = *(const s16x8*)&Alp[ao];
        #pragma unroll
        for (int nt = 0; nt < 4; ++nt) {
            const int n = w * 64 + nt * 16 + l15;
            const size_t bo = (size_t)n * 64 + kt * 32 + quad * 8;
            const s16x8 cbh = *(const s16x8*)(cW2Th + bo);
            const s16x8 cbl = *(const s16x8*)(cW2Tl + bo);
            const s16x8 pbh = *(const s16x8*)(pW2Th + bo);
            const s16x8 pbl = *(const s16x8*)(pW2Tl + bo);
            aco[nt] = __builtin_amdgcn_mfma_f32_16x16x32_bf16(ahc, cbh, aco[nt], 0, 0, 0);
            ape[nt] = __builtin_amdgcn_mfma_f32_16x16x32_bf16(ahp, pbh, ape[nt], 0, 0, 0);
            aco[nt] = __builtin_amdgcn_mfma_f32_16x16x32_bf16(alc, cbh, aco[nt], 0, 0, 0);
            ape[nt] = __builtin_amdgcn_mfma_f32_16x16x32_bf16(alp, pbh, ape[nt], 0, 0, 0);
            aco[nt] = __builtin_amdgcn_mfma_f32_16x16x32_bf16(ahc, cbl, aco[nt], 0, 0, 0);
            ape[nt] = __builtin_amdgcn_mfma_f32_16x16x32_bf16(ahp, pbl, ape[nt], 0, 0, 0);
        }
    }

    float sc[4] = {0.f,0.f,0.f,0.f}, sp[4] = {0.f,0.f,0.f,0.f};
    #pragma unroll
    for (int nt = 0; nt < 4; ++nt) {
        const int col = w * 64 + nt * 16 + l15;
        const float cbv = cb2[col], pbv = pb2[col];
        #pragma unroll
        for (int r = 0; r < 4; ++r) {
            const float co = aco[nt][r] + cbv;
            const float pe = ape[nt][r] + pbv;
            sc[r] += co * co;
            sp[r] += pe * pe;
        }
    }
    #pragma unroll
    for (int s = 8; s > 0; s >>= 1) {
        #pragma unroll
        for (int r = 0; r < 4; ++r) {
            sc[r] += __shfl_xor(sc[r], s, 64);
            sp[r] += __shfl_xor(sp[r], s, 64);
        }
    }
    if (l15 == 0) {
        #pragma unroll
        for (int r = 0; r < 4; ++r) { sqc[quad * 4 + r][w] = sc[r]; sqp_[quad * 4 + r][w] = sp[r]; }
    }
    __syncthreads();

    float rco[4], rpe[4];
    #pragma unroll
    for (int r = 0; r < 4; ++r) {
        const int row = quad * 4 + r;
        rco[r] = 1.f / fmaxf(sqrtf(sqc[row][0] + sqc[row][1] + sqc[row][2] + sqc[row][3]), 1e-12f);
        rpe[r] = 1.f / fmaxf(sqrtf(sqp_[row][0] + sqp_[row][1] + sqp_[row][2] + sqp_[row][3]), 1e-12f);
    }

    f32x4 ac[4], ap[4];
    #pragma unroll
    for (int nt = 0; nt < 4; ++nt) { ac[nt] = (f32x4){0.f,0.f,0.f,0.f}; ap[nt] = (f32x4){0.f,0.f,0.f,0.f}; }

    #pragma unroll
    for (int kt = 0; kt < 2; ++kt) {
        const int ao = l15 * 72 + kt * 32 + quad * 8;
        const s16x8 ahc = *(const s16x8*)&Ahc[ao];
        const s16x8 alc = *(const s16x8*)&Alc[ao];
        const s16x8 ahp = *(const s16x8*)&Ahp[ao];
        const s16x8 alp = *(const s16x8*)&Alp[ao];
        #pragma unroll
        for (int nt = 0; nt < 4; ++nt) {
            const int n = w * 64 + nt * 16 + l15;
            const size_t bo = (size_t)n * 64 + kt * 32 + quad * 8;
            const s16x8 cbh = *(const s16x8*)(WcTh + bo);
            const s16x8 cbl = *(const s16x8*)(WcTl + bo);
            const s16x8 pbh = *(const s16x8*)(WpTh + bo);
            const s16x8 pbl = *(const s16x8*)(WpTl + bo);
            ac[nt] = __builtin_amdgcn_mfma_f32_16x16x32_bf16(ahc, cbh, ac[nt], 0, 0, 0);
            ap[nt] = __builtin_amdgcn_mfma_f32_16x16x32_bf16(ahp, pbh, ap[nt], 0, 0, 0);
            ac[nt] = __builtin_amdgcn_mfma_f32_16x16x32_bf16(alc, cbh, ac[nt], 0, 0, 0);
            ap[nt] = __builtin_amdgcn_mfma_f32_16x16x32_bf16(alp, pbh, ap[nt], 0, 0, 0);
            ac[nt] = __builtin_amdgcn_mfma_f32_16x16x32_bf16(ahc, cbl, ac[nt], 0, 0, 0);
            ap[nt] = __builtin_amdgcn_mfma_f32_16x16x32_bf16(ahp, pbl, ap[nt], 0, 0, 0);
        }
    }

    int ci[4];
    #pragma unroll
    for (int r = 0; r < 4; ++r) {
        const int gobj = obase + quad * 4 + r;
        int c = cls[(size_t)gobj * cstride];
        if ((unsigned)c > 30u) c = 0;
        ci[r] = c;
    }

    float rp[4] = {0.f,0.f,0.f,0.f};
    #pragma unroll
    for (int nt = 0; nt < 4; ++nt) {
        const int col = w * 64 + nt * 16 + l15;
        const float mbv = mb[col], cbMv = cbM[col], pbMv = pbM[col];
        #pragma unroll
        for (int r = 0; r < 4; ++r) {
            const int row = quad * 4 + r;
            const float e = classMn[ci[r] * 256 + col]
                          + rco[r] * (ac[nt][r] + cbMv)
                          + rpe[r] * (ap[nt][r] + pbMv) + mbv;
            ushort h, l;
            split2(e, h, l);
            ehi[(size_t)(obase + row) * 256 + col] = h;
            elo[(size_t)(obase + row) * 256 + col] = l;
            rp[r] += e * e;
        }
    }
    #pragma unroll
    for (int s = 8; s > 0; s >>= 1) {
        #pragma unroll
        for (int r = 0; r < 4; ++r) rp[r] += __shfl_xor(rp[r], s, 64);
    }
    if (l15 == 0) {
        #pragma unroll
        for (int r = 0; r < 4; ++r) sqe[quad * 4 + r][w] = rp[r];
    }
    __syncthreads();
    if (t < 16) sqn[obase + t] = sqe[t][0] + sqe[t][1] + sqe[t][2] + sqe[t][3];
}

// ---------------------------------------------------------------------------
// Kernel 2: Gram + FUSED partial top-8 (R15, unchanged).
// ---------------------------------------------------------------------------
__global__ __launch_bounds__(256)
void k_gram(const ushort* __restrict__ ehi, const ushort* __restrict__ elo,
            const float* __restrict__ sqn, u64* __restrict__ cand)
{
    // [dbuf][Ah,Al,Bh,Bl][128 rows * 32 k], 64 KB; reused as f32[128][128]
    __shared__ __align__(16) ushort lds[2][4][4096];

    const int t = threadIdx.x, w = t >> 6, lane = t & 63;
    const int l15 = lane & 15, quad = lane >> 4;
    const int b = blockIdx.x;
    const int xcd = b & 7, rest = b >> 3;        // rest 0..79
    const int cell = xcd * 8 + rest / 10;        // 0..63
    const int tt = rest % 10;
    // upper-triangle enumeration: (0,0)(0,1)(0,2)(0,3)(1,1)(1,2)(1,3)(2,2)(2,3)(3,3)
    const int ti = (tt < 4) ? 0 : (tt < 7) ? 1 : (tt < 9) ? 2 : 3;
    const int tbase = (ti == 0) ? 0 : (ti == 1) ? 4 : (ti == 2) ? 7 : 9;
    const int tj = ti + (tt - tbase);
    const int p0 = ti * 128, q0 = tj * 128;
    const size_t cb = (size_t)cell * NP;
    const int diag = (ti == tj);
    const int wr = w >> 1, wc = w & 1;           // 2x2 wave grid, 64x64 each

    int srow[2], scol[2];
    #pragma unroll
    for (int i = 0; i < 2; ++i) {
        const int p = (w * 2 + i) * 64 + lane;
        const int row = p >> 2;
        srow[i] = row;
        scol[i] = ((p & 3) ^ ((row >> 1) & 3)) * 8;   // ushort offset of 16B chunk
    }

    #define STAGE(KT, D)                                                         \
    {                                                                            \
        const int kb_ = (KT) * 32;                                               \
        _Pragma("unroll")                                                        \
        for (int i = 0; i < 2; ++i) {                                            \
            const int ls_ = (w * 2 + i) * 512;   /* slot*8 ushorts */            \
            const size_t ga_ = (cb + p0 + srow[i]) * 256 + kb_ + scol[i];        \
            gload16(ehi + ga_, &lds[D][0][ls_]);                                 \
            gload16(elo + ga_, &lds[D][1][ls_]);                                 \
            if (!diag) {                                                         \
                const size_t gq_ = (cb + q0 + srow[i]) * 256 + kb_ + scol[i];    \
                gload16(ehi + gq_, &lds[D][2][ls_]);                             \
                gload16(elo + gq_, &lds[D][3][ls_]);                             \
            }                                                                    \
        }                                                                        \
    }

    f32x4 acc[4][4];
    #pragma unroll
    for (int mt = 0; mt < 4; ++mt)
        #pragma unroll
        for (int nt = 0; nt < 4; ++nt) acc[mt][nt] = (f32x4){0.f, 0.f, 0.f, 0.f};

    const int bB = diag ? 0 : 2;

    STAGE(0, 0);
    __syncthreads();

    for (int kt = 0; kt < 8; ++kt) {
        const int cur = kt & 1;
        if (kt < 7) STAGE(kt + 1, cur ^ 1);      // prefetch next k-slice

        s16x8 ah[4], al[4];
        #pragma unroll
        for (int mt = 0; mt < 4; ++mt) {
            const int r = wr * 64 + mt * 16 + l15;
            const int slot = 4 * r + (quad ^ ((r >> 1) & 3));
            ah[mt] = *(const s16x8*)&lds[cur][0][slot * 8];
            al[mt] = *(const s16x8*)&lds[cur][1][slot * 8];
        }
        #pragma unroll
        for (int nt = 0; nt < 4; ++nt) {
            const int rq = wc * 64 + nt * 16 + l15;
            const int slot = 4 * rq + (quad ^ ((rq >> 1) & 3));
            const s16x8 bh = *(const s16x8*)&lds[cur][bB][slot * 8];
            const s16x8 bl = *(const s16x8*)&lds[cur][bB + 1][slot * 8];
            #pragma unroll
            for (int mt = 0; mt < 4; ++mt) {
                acc[mt][nt] = __builtin_amdgcn_mfma_f32_16x16x32_bf16(ah[mt], bh, acc[mt][nt], 0, 0, 0);
                acc[mt][nt] = __builtin_amdgcn_mfma_f32_16x16x32_bf16(al[mt], bh, acc[mt][nt], 0, 0, 0);
                acc[mt][nt] = __builtin_amdgcn_mfma_f32_16x16x32_bf16(ah[mt], bl, acc[mt][nt], 0, 0, 0);
            }
        }
        __syncthreads();                          // drains vmcnt(0) -> buf ready
    }
    #undef STAGE

    float sqp[4][4];
    #pragma unroll
    for (int mt = 0; mt < 4; ++mt)
        #pragma unroll
        for (int r = 0; r < 4; ++r)
            sqp[mt][r] = sqn[cb + p0 + wr * 64 + mt * 16 + quad * 4 + r];

    float* T = (float*)&lds[0][0][0];            // 128x128 f32, col ^ row swizzle

    #pragma unroll
    for (int nt = 0; nt < 4; ++nt) {
        const int cq_l = wc * 64 + nt * 16 + l15;
        const float sq_q = sqn[cb + q0 + cq_l];
        #pragma unroll
        for (int mt = 0; mt < 4; ++mt) {
            #pragma unroll
            for (int r = 0; r < 4; ++r) {
                const int rp_l = wr * 64 + mt * 16 + quad * 4 + r;
                const float d = (sqp[mt][r] + sq_q) - 2.f * acc[mt][nt][r];
                T[rp_l * 128 + (cq_l ^ rp_l)] = d;
            }
        }
    }
    __syncthreads();

    // ---- exact per-tile top-8 per row (2 threads/row, snapshot-merge) ----
    {
        const int row = t >> 1, half = t & 1;

        u64 k8[8];
        #pragma unroll
        for (int j = 0; j < 8; ++j) k8[j] = ~0ull;
        for (int c = 0; c < 64; ++c) {
            const int cc = half * 64 + c;
            const float f = T[row * 128 + (cc ^ row)];
            ins8(k8, ((u64)fkey(f) << 32) | (unsigned)(q0 + cc));
        }
        {
            u64 part[8];
            #pragma unroll
            for (int j = 0; j < 8; ++j) part[j] = __shfl_xor(k8[j], 1, 64);
            #pragma unroll
            for (int j = 0; j < 8; ++j) ins8(k8, part[j]);
        }
        if (half == 0) {
            u64* cp = cand + ((size_t)(cb + p0 + row)) * 32 + tj * 8;
            #pragma unroll
            for (int j = 0; j < 8; ++j) cp[j] = k8[j];
        }

        if (!diag) {                              // mirror side: scan columns
            u64 q8[8];
            #pragma unroll
            for (int j = 0; j < 8; ++j) q8[j] = ~0ull;
            for (int c = 0; c < 64; ++c) {
                const int rr = half * 64 + c;
                const float f = T[rr * 128 + (row ^ rr)];
                ins8(q8, ((u64)fkey(f) << 32) | (unsigned)(p0 + rr));
            }
            {
                u64 part[8];
                #pragma unroll
                for (int j = 0; j < 8; ++j) part[j] = __shfl_xor(q8[j], 1, 64);
                #pragma unroll
                for (int j = 0; j < 8; ++j) ins8(q8, part[j]);
            }
            if (half == 0) {
                u64* cp = cand + ((size_t)(cb + q0 + row)) * 32 + ti * 8;
                #pragma unroll
                for (int j = 0; j < 8; ++j) cp[j] = q8[j];
            }
        }
    }
}

// ---------------------------------------------------------------------------
// Kernel 3: u = x@Wd+gb1, v = x@Wb (single-pass A, LDS-staged) MERGED with
// the cand->nidx top-8 merge (one fewer launch). bid<1024: uv GEMM path;
// bid>=1024: nidx path (128 blocks x 256 threads = 32768 points).
// ---------------------------------------------------------------------------
__global__ __launch_bounds__(256)
void k_uvnidx(const ushort* __restrict__ ehi,
              const ushort* __restrict__ Wdh, const ushort* __restrict__ Wbh,
              const float* __restrict__ gb1,
              float* __restrict__ u, float* __restrict__ v,
              const u64* __restrict__ cand, int* __restrict__ nidx)
{
    __shared__ __align__(16) ushort lds[2][2048];   // [dbuf][slot*8] hi only, 8 KB

    const int t = threadIdx.x;

    if (blockIdx.x >= 1024) {                    // ---- nidx merge path ----
        const int p = (blockIdx.x - 1024) * 256 + t;   // 0..NTOT-1
        const u64* cp = cand + (size_t)p * 32;
        u64 k8[8];
        #pragma unroll
        for (int j = 0; j < 8; ++j) k8[j] = ~0ull;
        #pragma unroll
        for (int i = 0; i < 32; ++i) ins8(k8, cp[i]);
        const int hi = (p >> 9) << 9;
        #pragma unroll
        for (int r = 0; r < 8; ++r)
            nidx[(size_t)p * KNN + r] = hi | (int)(k8[r] & 0x1ffu);
        return;
    }

    const int w = t >> 6, lane = t & 63;
    const int l15 = lane & 15, quad = lane >> 4;
    const int isV = blockIdx.x >> 9;           // 1024 uv blocks
    const int m0 = (blockIdx.x & 511) * 64;
    const ushort* Wh = isV ? Wbh : Wdh;
    float* out = isV ? v : u;
    const int mh = w & 1, ch = w >> 1;

    const int sp = w * 64 + lane;
    const int srow = sp >> 2;
    const int scol = ((sp & 3) ^ ((srow >> 1) & 3)) * 8;   // ushort offset

    #define STAGE_UV(S, D)                                                       \
    {                                                                            \
        const size_t ga_ = (size_t)(m0 + srow) * 256 + (S) * 32 + scol;          \
        gload16(ehi + ga_, &lds[D][sp * 8]);                                     \
    }

    const int r0 = mh * 32 + l15, r1 = r0 + 16;
    const int slot0 = 4 * r0 + (quad ^ ((r0 >> 1) & 3));
    const int slot1 = 4 * r1 + (quad ^ ((r1 >> 1) & 3));

    f32x4 acc[2][8];
    #pragma unroll
    for (int mt = 0; mt < 2; ++mt)
        #pragma unroll
        for (int nt = 0; nt < 8; ++nt) acc[mt][nt] = (f32x4){0.f, 0.f, 0.f, 0.f};

    STAGE_UV(0, 0);
    __syncthreads();

    for (int s = 0; s < 8; ++s) {
        const int cur = s & 1;
        if (s < 7) STAGE_UV(s + 1, cur ^ 1);   // prefetch next k-slice

        const s16x8 ah0 = *(const s16x8*)&lds[cur][slot0 * 8];
        const s16x8 ah1 = *(const s16x8*)&lds[cur][slot1 * 8];
        #pragma unroll
        for (int nt = 0; nt < 8; ++nt) {
            const int n = ch * 128 + nt * 16 + l15;
            const size_t bo = (size_t)n * 256 + s * 32 + quad * 8;
            const s16x8 bh = *(const s16x8*)(Wh + bo);
            acc[0][nt] = __builtin_amdgcn_mfma_f32_16x16x32_bf16(ah0, bh, acc[0][nt], 0, 0, 0);
            acc[1][nt] = __builtin_amdgcn_mfma_f32_16x16x32_bf16(ah1, bh, acc[1][nt], 0, 0, 0);
        }
        __syncthreads();                        // drains vmcnt(0) -> buf ready
    }
    #undef STAGE_UV

    #pragma unroll
    for (int mt = 0; mt < 2; ++mt) {
        #pragma unroll
        for (int nt = 0; nt < 8; ++nt) {
            const int col = ch * 128 + nt * 16 + l15;
            const float bias = isV ? 0.f : gb1[col];
            #pragma unroll
            for (int r = 0; r < 4; ++r) {
                const int row = mh * 32 + mt * 16 + quad * 4 + r;
                out[(size_t)(m0 + row) * 256 + col] = acc[mt][nt][r] + bias;
            }
        }
    }
}

// ---------------------------------------------------------------------------
// Kernel 5: edge GEMM + max aggregation. BK=64: 4 barrier phases instead of
// 8 (same total MFMA/split work; per-acc MFMA operand order is the same
// ascending k sequence -> bit-identical part). Abuf [2][64*68] = 17.4 KB,
// stride 68 ushorts = 2-way banks (free). Each thread handles 8 k/edge
// (se=t>>3, kq=t&7). Same dbuf barrier protocol; v pipeline 1 phase ahead.
// ---------------------------------------------------------------------------
__global__ __launch_bounds__(512)
void k_edge(const float* __restrict__ u, const float* __restrict__ v,
            const int* __restrict__ nidx,
            const ushort* __restrict__ g2h,
            const float* __restrict__ hb,
            float* __restrict__ part)
{
    __shared__ ushort Abuf[2][4352];      // [dbuf][edge*68+k] hi only, 17.4 KB
    __shared__ float ustage[2048];        // 8 pts x 256 k, 8 KB

    const int t = threadIdx.x, w = t >> 6, lane = t & 63;
    const int l31 = lane & 31, kh = lane >> 5;

    const int b = blockIdx.x;
    const int xcd = b & 7, rest = b >> 3;        // rest 0..511
    const int cell = xcd * 8 + (rest >> 6);      // 0..63
    const int pl0 = cell * NP + (rest & 63) * 8;

    // stage u rows once (coalesced, 4 floats per thread x 512 threads)
    {
        const int pt = t >> 6, kk = (t & 63) * 4;
        *(float4*)&ustage[pt * 256 + kk] = *(const float4*)(u + (size_t)(pl0 + pt) * 256 + kk);
    }

    const int se = t >> 3, kq = t & 7;           // edge 0..63, k-octet 0..7 (8 k each)
    const int upt = se >> 3;                     // point within block
    int svrow = nidx[(size_t)(pl0 + upt) * KNN + (se & 7)];
    if ((unsigned)svrow >= (unsigned)NTOT) svrow = 0;

    __syncthreads();                             // ustage visible (one-time)

    float4 vr[2][2];                             // 2-set v pipeline (8 floats/thread)

    #define VLOAD(S)                                                             \
    {                                                                            \
        const int k0 = (S) * 64 + kq * 8;                                        \
        vr[(S) & 1][0] = *(const float4*)(v + (size_t)svrow * 256 + k0);         \
        vr[(S) & 1][1] = *(const float4*)(v + (size_t)svrow * 256 + k0 + 4);     \
    }
    #define SPLITW(S, BUF)                                                       \
    {                                                                            \
        const int k0u = (S) * 64 + kq * 8;                                       \
        const float4 ua = *(const float4*)&ustage[upt * 256 + k0u];              \
        const float4 ub = *(const float4*)&ustage[upt * 256 + k0u + 4];          \
        const float4 va = vr[(S) & 1][0], vb = vr[(S) & 1][1];                   \
        const float sv[8] = {                                                    \
            fmaxf(ua.x + va.x, 0.f), fmaxf(ua.y + va.y, 0.f),                    \
            fmaxf(ua.z + va.z, 0.f), fmaxf(ua.w + va.w, 0.f),                    \
            fmaxf(ub.x + vb.x, 0.f), fmaxf(ub.y + vb.y, 0.f),                    \
            fmaxf(ub.z + vb.z, 0.f), fmaxf(ub.w + vb.w, 0.f)};                   \
        union { uint2 q[2]; ushort us[8]; } th;                                  \
        _Pragma("unroll")                                                        \
        for (int j = 0; j < 8; ++j) { th.us[j] = f2b(sv[j]); }                   \
        *(uint2*)&Abuf[BUF][se * 68 + kq * 8]     = th.q[0];                     \
        *(uint2*)&Abuf[BUF][se * 68 + kq * 8 + 4] = th.q[1];                     \
    }

    #define LDS_BARRIER()                                                        \
    {                                                                            \
        asm volatile("s_waitcnt lgkmcnt(0)" ::: "memory");                       \
        __builtin_amdgcn_s_barrier();                                            \
    }

    f32x16 acc[2];
    acc[0] = (f32x16)(0.0f);
    acc[1] = (f32x16)(0.0f);

    VLOAD(0); VLOAD(1);
    SPLITW(0, 0);

    #pragma unroll
    for (int S = 0; S < 4; ++S) {
        LDS_BARRIER();                        // buf[S&1] visible; buf[(S+1)&1] readers done
        if (S < 3) {
            SPLITW(S + 1, (S + 1) & 1);       // u from LDS, v register-resident
            if (S < 2) VLOAD(S + 2);          // stays in flight across barriers
        }

        // A fragments: row = mt*32 + l31, k = kc*16 + kh*8 within this BK=64
        s16x8 ah[2][4];
        #pragma unroll
        for (int mt = 0; mt < 2; ++mt) {
            #pragma unroll
            for (int kc = 0; kc < 4; ++kc) {
                const int ao = (mt * 32 + l31) * 68 + kc * 16 + kh * 8;
                union { uint2 q[2]; s16x8 v8; } Th;
                Th.q[0] = *(const uint2*)&Abuf[S & 1][ao];
                Th.q[1] = *(const uint2*)&Abuf[S & 1][ao + 4];
                ah[mt][kc] = Th.v8;
            }
        }

        #pragma unroll
        for (int kc = 0; kc < 4; ++kc) {
            const int n = w * 32 + l31;
            const s16x8 bh = *(const s16x8*)(g2h + (size_t)n * 256 + S * 64 + kc * 16 + kh * 8);
            acc[0] = __builtin_amdgcn_mfma_f32_32x32x16_bf16(ah[0][kc], bh, acc[0], 0, 0, 0);
            acc[1] = __builtin_amdgcn_mfma_f32_32x32x16_bf16(ah[1][kc], bh, acc[1], 0, 0, 0);
        }
    }
    #undef VLOAD
    #undef SPLITW
    #undef LDS_BARRIER

    const int slot = rest & 63;
    {
        float rm = -3.4e38f;
        #pragma unroll
        for (int r = 0; r < 16; ++r)
            rm = fmaxf(rm, fmaxf(acc[0][r], acc[1][r]));
        rm = fmaxf(rm, __shfl_xor(rm, 32, 64));   // merge row-halves (lane>>5)
        if (kh == 0) {
            const int col = w * 32 + l31;
            part[((size_t)cell * 64 + slot) * 256 + col] = rm + hb[col];
        }
    }
}

// ---------------------------------------------------------------------------
// Kernel 6: reduce 64 partial maxes per cell, final MLP (f32), L2 normalize.
// ---------------------------------------------------------------------------
__global__ __launch_bounds__(256)
void k_final(const float* __restrict__ part,
             const float* __restrict__ lW1, const float* __restrict__ lb1,
             const float* __restrict__ lW2, const float* __restrict__ lb2,
             float* __restrict__ out)
{
    __shared__ float pooled[256];
    __shared__ float hid[256];
    __shared__ float red[4];

    const int b = blockIdx.x;
    const int t = threadIdx.x;

    float m = -3.4e38f;
    for (int s = 0; s < 64; ++s)
        m = fmaxf(m, part[((size_t)b * 64 + s) * 256 + t]);
    pooled[t] = m;
    __syncthreads();

    float h = lb1[t];
    for (int k = 0; k < 256; k += 4) {
        #pragma unroll
        for (int kk = 0; kk < 4; ++kk)
            h += pooled[k + kk] * lW1[(k + kk) * 256 + t];
    }
    hid[t] = fmaxf(h, 0.f);
    __syncthreads();

    float o = lb2[t];
    for (int k = 0; k < 256; k += 4) {
        #pragma unroll
        for (int kk = 0; kk < 4; ++kk)
            o += hid[k + kk] * lW2[(k + kk) * 256 + t];
    }

    float ss = o * o;
    #pragma unroll
    for (int s = 32; s > 0; s >>= 1) ss += __shfl_down(ss, s, 64);
    if ((t & 63) == 0) red[t >> 6] = ss;
    __syncthreads();
    const float tot = red[0] + red[1] + red[2] + red[3];
    const float rn = 1.f / fmaxf(sqrtf(tot), 1e-12f);
    out[b * 256 + t] = o * rn;
}

// ---------------------------------------------------------------------------
extern "C" void kernel_launch(void* const* d_in, const int* in_sizes, int n_in,
                              void* d_out, int out_size, void* d_ws, size_t ws_size,
                              hipStream_t stream)
{
    (void)n_in; (void)out_size; (void)ws_size;

    const float* class_table = (const float*)d_in[0];
    const float* cW1 = (const float*)d_in[1];
    const float* cb1 = (const float*)d_in[2];
    const float* cW2 = (const float*)d_in[3];
    const float* cb2 = (const float*)d_in[4];
    const float* pW1 = (const float*)d_in[5];
    const float* pb1 = (const float*)d_in[6];
    const float* pW2 = (const float*)d_in[7];
    const float* pb2 = (const float*)d_in[8];
    const float* mW  = (const float*)d_in[9];
    const float* mb  = (const float*)d_in[10];
    const float* gW1 = (const float*)d_in[11];
    const float* gb1 = (const float*)d_in[12];
    const float* g_gamma = (const float*)d_in[13];
    const float* g_beta  = (const float*)d_in[14];
    const float* gW2 = (const float*)d_in[15];
    const float* gb2 = (const float*)d_in[16];
    const float* lW1 = (const float*)d_in[17];
    const float* lb1 = (const float*)d_in[18];
    const float* lW2 = (const float*)d_in[19];
    const float* lb2 = (const float*)d_in[20];
    const float* positions = (const float*)d_in[21];
    const float* colors    = (const float*)d_in[22];
    const int*  cls        = (const int*)d_in[23];

    const int cstride = (in_sizes[23] == 2 * NTOT) ? 2 : 1;

    // workspace layout (bytes); cand (8 MB) replaces dist (67 MB).
    char* base = (char*)d_ws;
    float*   part   = (float*)(base + 0);               //   4,194,304
    ushort*  Wdh    = (ushort*)(base + 4194304);
    ushort*  Wdl    = (ushort*)(base + 4325376);
    ushort*  Wbh    = (ushort*)(base + 4456448);
    ushort*  Wbl    = (ushort*)(base + 4587520);
    ushort*  g2h    = (ushort*)(base + 4718592);
    ushort*  g2l    = (ushort*)(base + 4849664);
    float*   hb     = (float*)(base + 4980736);
    ushort*  cW2Th  = (ushort*)(base + 4981760);
    ushort*  cW2Tl  = (ushort*)(base + 5014528);
    ushort*  pW2Th  = (ushort*)(base + 5047296);
    ushort*  pW2Tl  = (ushort*)(base + 5080064);
    ushort*  WcTh   = (ushort*)(base + 5112832);
    ushort*  WcTl   = (ushort*)(base + 5145600);
    ushort*  WpTh   = (ushort*)(base + 5178368);
    ushort*  WpTl   = (ushort*)(base + 5211136);
    float*   classMn= (float*)(base + 5243904);
    float*   cbM    = (float*)(base + 5275648);
    float*   pbM    = (float*)(base + 5276672);
    int*     nidx   = (int*)(base + 5277696);           //   1,048,576
    float*   sqn    = (float*)(base + 6326272);         //     131,072
    ushort*  ehi    = (ushort*)(base + 6457344);        //  16,777,216
    ushort*  elo    = (ushort*)(base + 23234560);       //  16,777,216
    u64*     cand   = (u64*)(base + 40011776);          //   8,388,608
    float*   v      = (float*)(base + 107120640);       //  33,554,432
    float*   u      = (float*)(base + 140675072);       //  33,554,432
    float* out = (float*)d_out;

    k_prep<<<1058, 256, 0, stream>>>(gW1, gW2, g_gamma, g_beta, gb2, cW2, pW2,
                                     cb2, pb2, mW, class_table,
                                     Wdh, Wdl, Wbh, Wbl, g2h, g2l, hb,
                                     cW2Th, cW2Tl, pW2Th, pW2Tl,
                                     WcTh, WcTl, WpTh, WpTl, cbM, pbM, classMn);

    k_embed<<<NTOT / 16, 256, 0, stream>>>(classMn, cW1, cb1, cb2, pW1, pb1, pb2,
                                           mb, cW2Th, cW2Tl, pW2Th, pW2Tl,
                                           WcTh, WcTl, WpTh, WpTl, cbM, pbM,
                                           positions, colors, cls, cstride,
                                           ehi, elo, sqn);
    k_gram<<<NB * 10, 256, 0, stream>>>(ehi, elo, sqn, cand);
    k_uvnidx<<<1024 + NTOT / 256, 256, 0, stream>>>(ehi, Wdh, Wbh, gb1, u, v,
                                                    cand, nidx);
    k_edge<<<NTOT / 8, 512, 0, stream>>>(u, v, nidx, g2h, hb, part);
    k_final<<<NB, 256, 0, stream>>>(part, lW1, lb1, lW2, lb2, out);
}